// Round 1
// 1606.977 us; speedup vs baseline: 1.2127x; 1.2127x over previous
//
#include <hip/hip_runtime.h>

// ---------------- problem constants ----------------
#define NN      20000     // nodes per type
#define EE      320000    // edges per relation
#define ETOT    340000    // EE + NN self loops
#define FD      512       // raw feature dim
#define HH_     4         // heads
#define CD      128       // channels per head
#define HHD     512       // H*C
#define BG      64        // batch graphs
#define INNERD  64

typedef __attribute__((ext_vector_type(8))) short bf16x8;
typedef __attribute__((ext_vector_type(4))) float f32x4;

// ---- bf16 <-> f32 via raw bits ----
__device__ __forceinline__ float bf2f(unsigned v) { return __uint_as_float(v << 16); }
__device__ __forceinline__ unsigned short f2bf(float f) {
    unsigned u = __float_as_uint(f);
    unsigned r = 0x7fffu + ((u >> 16) & 1u);
    return (unsigned short)((u + r) >> 16);
}
__device__ __forceinline__ void load8bf(const unsigned short* p, float* f) {
    uint4 u = *reinterpret_cast<const uint4*>(p);
    f[0] = bf2f(u.x & 0xffffu); f[1] = bf2f(u.x >> 16);
    f[2] = bf2f(u.y & 0xffffu); f[3] = bf2f(u.y >> 16);
    f[4] = bf2f(u.z & 0xffffu); f[5] = bf2f(u.z >> 16);
    f[6] = bf2f(u.w & 0xffffu); f[7] = bf2f(u.w >> 16);
}
// fast split f32 -> hi + lo bf16 (truncation; residual ~2^-16 relative)
__device__ __forceinline__ void split_f32(float x, unsigned short& hi, unsigned short& lo) {
    unsigned u = __float_as_uint(x);
    hi = (unsigned short)(u >> 16);
    float r = x - bf2f(hi);
    lo = (unsigned short)(__float_as_uint(r) >> 16);
}
template <typename TA>
__device__ __forceinline__ void splitA(const TA* p, size_t i, unsigned short& hi, unsigned short& lo);
template <>
__device__ __forceinline__ void splitA<float>(const float* p, size_t i, unsigned short& hi, unsigned short& lo) {
    split_f32(p[i], hi, lo);
}
template <>
__device__ __forceinline__ void splitA<unsigned short>(const unsigned short* p, size_t i, unsigned short& hi, unsigned short& lo) {
    hi = p[i]; lo = 0;
}

// ================= CSR build =================
__global__ __launch_bounds__(256) void csr_hist(const int* __restrict__ ei, int* __restrict__ cnt) {
    int e = blockIdx.x * blockDim.x + threadIdx.x;
    if (e < EE) atomicAdd(&cnt[ei[EE + e]], 1);
}

__global__ __launch_bounds__(1024) void csr_scan(const int* __restrict__ cnt,
                                                 int* __restrict__ rowptr,
                                                 int* __restrict__ cursor) {
    __shared__ int part[1024];
    int t = threadIdx.x;
    int base = t * 20;
    int s = 0;
    #pragma unroll
    for (int i = 0; i < 20; ++i) { int n = base + i; if (n < NN) s += cnt[n] + 1; }
    part[t] = s;
    __syncthreads();
    for (int off = 1; off < 1024; off <<= 1) {
        int v = (t >= off) ? part[t - off] : 0;
        __syncthreads();
        part[t] += v;
        __syncthreads();
    }
    int run = (t > 0) ? part[t - 1] : 0;
    #pragma unroll
    for (int i = 0; i < 20; ++i) {
        int n = base + i;
        if (n < NN) { rowptr[n] = run; cursor[n] = run; run += cnt[n] + 1; }
    }
    if (t == 1023) rowptr[NN] = run;
}

// scatter src ids as uint16 (node ids < 65536); self-loop appended per node
__global__ __launch_bounds__(256) void csr_scatter16(const int* __restrict__ ei,
                                                     int* __restrict__ cursor,
                                                     unsigned short* __restrict__ srcs) {
    int idx = blockIdx.x * blockDim.x + threadIdx.x;
    if (idx >= ETOT) return;
    int src, dst;
    if (idx < EE) { src = ei[idx]; dst = ei[EE + idx]; }
    else          { src = dst = idx - EE; }
    int pos = atomicAdd(&cursor[dst], 1);
    srcs[pos] = (unsigned short)src;
}

// ================= split-bf16 MFMA GEMM (near-f32 precision) =================
// C[M,N](bf16) = A[M,K] @ B[K, N cols of ldb](f32). 64x64 tiles, 256 thr.
// D = Ah*Bh + Ah*Bl + (A_EXACT ? 0 : Al*Bh). blockIdx.z batches xl / xr sides.
template <typename TA, bool A_EXACT>
__global__ __launch_bounds__(256) void gemm_mfma(
    const TA* __restrict__ A0, const TA* __restrict__ A1,
    const float* __restrict__ B0, const float* __restrict__ B1, int ldb,
    unsigned short* __restrict__ C0, unsigned short* __restrict__ C1,
    int M, int K, int N)
{
    const TA* A = blockIdx.z ? A1 : A0;
    const float* B = blockIdx.z ? B1 : B0;
    unsigned short* C = blockIdx.z ? C1 : C0;

    __shared__ unsigned short Ah[64][40];   // [m][k] stride 80B; 16B-aligned segs
    __shared__ unsigned short Al[64][40];
    __shared__ unsigned short Bh[64][40];   // [n][k] (B transposed on store)
    __shared__ unsigned short Bl[64][40];
    const int tid = threadIdx.x;
    const int wave = tid >> 6, lane = tid & 63;
    const int quad = lane >> 4, lrow = lane & 15;
    const int tileM = blockIdx.y * 64, tileN = blockIdx.x * 64;
    const int wm = (wave >> 1) * 32, wn = (wave & 1) * 32;

    f32x4 acc[2][2] = {};

    const int am = tid >> 2;            // A loader: row (0..63)
    const int aks = (tid & 3) * 8;      // A loader: k-seg
    const int bn = tid & 63;            // B loader: col
    const int bk0 = (tid >> 6) * 8;     // B loader: k-seg

    for (int k0 = 0; k0 < K; k0 += 32) {
        {   // ---- stage A: 64 x 32, hi/lo split ----
            int gm = tileM + am;
            bf16x8 ph = {}, pl = {};
            if (gm < M) {
                #pragma unroll
                for (int j = 0; j < 8; ++j) {
                    unsigned short h, l;
                    splitA(A, (size_t)gm * K + k0 + aks + j, h, l);
                    ph[j] = (short)h; pl[j] = (short)l;
                }
            }
            *reinterpret_cast<bf16x8*>(&Ah[am][aks]) = ph;
            if (!A_EXACT) *reinterpret_cast<bf16x8*>(&Al[am][aks]) = pl;
        }
        {   // ---- stage B (transposed): Bs[n][k], hi/lo split ----
            bf16x8 ph, pl;
            #pragma unroll
            for (int j = 0; j < 8; ++j) {
                unsigned short h, l;
                split_f32(B[(size_t)(k0 + bk0 + j) * ldb + tileN + bn], h, l);
                ph[j] = (short)h; pl[j] = (short)l;
            }
            *reinterpret_cast<bf16x8*>(&Bh[bn][bk0]) = ph;
            *reinterpret_cast<bf16x8*>(&Bl[bn][bk0]) = pl;
        }
        __syncthreads();
        bf16x8 ah[2], al[2], bh[2], bl[2];
        #pragma unroll
        for (int mi = 0; mi < 2; ++mi) {
            ah[mi] = *reinterpret_cast<const bf16x8*>(&Ah[wm + mi * 16 + lrow][quad * 8]);
            if (!A_EXACT)
                al[mi] = *reinterpret_cast<const bf16x8*>(&Al[wm + mi * 16 + lrow][quad * 8]);
        }
        #pragma unroll
        for (int ni = 0; ni < 2; ++ni) {
            bh[ni] = *reinterpret_cast<const bf16x8*>(&Bh[wn + ni * 16 + lrow][quad * 8]);
            bl[ni] = *reinterpret_cast<const bf16x8*>(&Bl[wn + ni * 16 + lrow][quad * 8]);
        }
        #pragma unroll
        for (int mi = 0; mi < 2; ++mi)
            #pragma unroll
            for (int ni = 0; ni < 2; ++ni) {
                acc[mi][ni] = __builtin_amdgcn_mfma_f32_16x16x32_bf16(
                    ah[mi], bh[ni], acc[mi][ni], 0, 0, 0);
                acc[mi][ni] = __builtin_amdgcn_mfma_f32_16x16x32_bf16(
                    ah[mi], bl[ni], acc[mi][ni], 0, 0, 0);
                if (!A_EXACT)
                    acc[mi][ni] = __builtin_amdgcn_mfma_f32_16x16x32_bf16(
                        al[mi], bh[ni], acc[mi][ni], 0, 0, 0);
            }
        __syncthreads();
    }
    // ---- epilogue: C/D layout col=lane&15, row=quad*4+reg ----
    #pragma unroll
    for (int mi = 0; mi < 2; ++mi) {
        #pragma unroll
        for (int ni = 0; ni < 2; ++ni) {
            int gcol = tileN + wn + ni * 16 + lrow;
            #pragma unroll
            for (int r = 0; r < 4; ++r) {
                int grow = tileM + wm + mi * 16 + quad * 4 + r;
                if (grow < M)
                    C[(size_t)grow * N + gcol] = f2bf(acc[mi][ni][r]);
            }
        }
    }
}

// ================= THIN: fused GATv2 pass, one head (xl/xr [NN,128]) =================
__global__ __launch_bounds__(256) void fused_aggr1(
    const int* __restrict__ rowptr, const unsigned short* __restrict__ srcs,
    const unsigned short* __restrict__ xl, const unsigned short* __restrict__ xr,
    const float* __restrict__ att,
    float* __restrict__ acc, int add_in, int fin_mode,
    const float* __restrict__ bA, const float* __restrict__ bB,
    unsigned short* __restrict__ z,
    const int* __restrict__ batch, float* __restrict__ pool)
{
    int dst = (int)((blockIdx.x * (size_t)blockDim.x + threadIdx.x) >> 6);
    int lane = threadIdx.x & 63;
    if (dst >= NN) return;
    int beg = rowptr[dst], end = rowptr[dst + 1];

    unsigned ub = *reinterpret_cast<const unsigned*>(xr + (size_t)dst * CD + lane * 2);
    float br0 = bf2f(ub & 0xffffu), br1 = bf2f(ub >> 16);
    float ta0 = att[lane * 2], ta1 = att[lane * 2 + 1];

    float n0 = 0.f, n1 = 0.f, den = 0.f;
    for (int k = beg; k < end; ++k) {
        int src = srcs[k];
        unsigned ua = *reinterpret_cast<const unsigned*>(xl + (size_t)src * CD + lane * 2);
        float a0 = bf2f(ua & 0xffffu), a1 = bf2f(ua >> 16);
        float v0 = a0 + br0, v1 = a1 + br1;
        v0 = (v0 > 0.f) ? v0 : 0.2f * v0;
        v1 = (v1 > 0.f) ? v1 : 0.2f * v1;
        float d = v0 * ta0 + v1 * ta1;
        #pragma unroll
        for (int off = 1; off < 64; off <<= 1)
            d += __shfl_xor(d, off);
        float p = expf(d);
        n0 += p * a0; n1 += p * a1; den += p;
    }
    float o0 = n0 / den, o1 = n1 / den;
    size_t ai = (size_t)dst * CD + lane * 2;
    if (add_in) { o0 += acc[ai]; o1 += acc[ai + 1]; }
    if (fin_mode == 0) {
        acc[ai] = o0; acc[ai + 1] = o1;
    } else {
        int c0 = lane * 2;
        float bb0 = 0.f, bb1 = 0.f;
        #pragma unroll
        for (int h = 0; h < HH_; ++h) {
            bb0 += bA[h * CD + c0]     + bB[h * CD + c0];
            bb1 += bA[h * CD + c0 + 1] + bB[h * CD + c0 + 1];
        }
        o0 = tanhf(o0 + bb0);
        o1 = tanhf(o1 + bb1);
        if (fin_mode == 1) {
            z[ai] = f2bf(o0); z[ai + 1] = f2bf(o1);
        } else {
            int b = batch[dst];
            atomicAdd(&pool[(size_t)b * CD + c0],     o0);
            atomicAdd(&pool[(size_t)b * CD + c0 + 1], o1);
        }
    }
}

// ================= FAT: fused GATv2 pass, ALL 4 heads (R7-proven structure) =========
// one 64-lane wave per dst; 16-lane group per head; lane holds 8 channels (16B gathers).
// Per-edge reduce: xor 1/2/4/8 only; head-sum xor16/32 once per dst. No LDS, no syncs.
// fin_mode: 0 = store partial acc (f32); 1 = bias+tanh -> z (bf16);
//           2 = bias+tanh -> acc (f32), later reduced by pool_reduce (NO atomics —
//               2.56M contended pool atomics cost ~190us/pass in R-prev profile).
__global__ __launch_bounds__(256) void fused_aggr4(
    const int* __restrict__ rowptr, const unsigned short* __restrict__ srcs,
    const unsigned short* __restrict__ xl, const unsigned short* __restrict__ xr,
    const float* __restrict__ att,          // [512] f32 this relation (all heads)
    float* __restrict__ acc, int add_in, int fin_mode,
    const float* __restrict__ bA, const float* __restrict__ bB,
    unsigned short* __restrict__ z,
    const int* __restrict__ batch, float* __restrict__ pool)
{
    int dst = (int)((blockIdx.x * (size_t)blockDim.x + threadIdx.x) >> 6);
    int lane = threadIdx.x & 63;
    if (dst >= NN) return;
    int beg = rowptr[dst], end = rowptr[dst + 1];

    float br[8], ta[8];
    load8bf(xr + (size_t)dst * HHD + lane * 8, br);
    #pragma unroll
    for (int j = 0; j < 8; ++j) ta[j] = att[lane * 8 + j];

    float n[8] = {}; float den = 0.f;
    for (int k = beg; k < end; ++k) {
        int src = srcs[k];
        float a[8];
        load8bf(xl + (size_t)src * HHD + lane * 8, a);
        float d = 0.f;
        #pragma unroll
        for (int j = 0; j < 8; ++j) {
            float v = a[j] + br[j];
            v = (v > 0.f) ? v : 0.2f * v;
            d += v * ta[j];
        }
        d += __shfl_xor(d, 1);
        d += __shfl_xor(d, 2);
        d += __shfl_xor(d, 4);
        d += __shfl_xor(d, 8);
        float p = expf(d);
        den += p;
        #pragma unroll
        for (int j = 0; j < 8; ++j) n[j] += p * a[j];
    }
    float inv = 1.f / den;
    float o[8];
    #pragma unroll
    for (int j = 0; j < 8; ++j) {
        o[j] = n[j] * inv;
        o[j] += __shfl_xor(o[j], 16);   // head-sum (once per dst)
        o[j] += __shfl_xor(o[j], 32);
    }
    if (lane < 16) {
        size_t ai = (size_t)dst * CD + lane * 8;
        if (add_in) {
            #pragma unroll
            for (int j = 0; j < 8; ++j) o[j] += acc[ai + j];
        }
        if (fin_mode == 0) {
            #pragma unroll
            for (int j = 0; j < 8; ++j) acc[ai + j] = o[j];
        } else {
            int c0 = lane * 8;
            #pragma unroll
            for (int j = 0; j < 8; ++j) {
                float bb = 0.f;
                #pragma unroll
                for (int h = 0; h < HH_; ++h)
                    bb += bA[h * CD + c0 + j] + bB[h * CD + c0 + j];
                o[j] = tanhf(o[j] + bb);
            }
            if (fin_mode == 1) {
                #pragma unroll
                for (int j = 0; j < 8; ++j) z[ai + j] = f2bf(o[j]);
            } else {
                // contention-free: store finalized f32 row; pool_reduce sums per graph
                #pragma unroll
                for (int j = 0; j < 8; ++j) acc[ai + j] = o[j];
            }
        }
    }
}

// ================= pool_reduce: segmented sum over sorted batch (no atomics) ========
// one block per graph b; 4 waves split the node range; LDS combine. ~10MB read total.
__global__ __launch_bounds__(512) void pool_reduce(
    const float* __restrict__ acc, const int* __restrict__ batch,
    float* __restrict__ pool)
{
    int b = blockIdx.x;
    int t = threadIdx.x & (CD - 1);
    int q = threadIdx.x >> 7;          // 0..3 (wave id; CD==128 => 2 waves/q? no: 128 thr per q)
    // binary search: first index with batch[i] >= b, first with batch[i] > b
    int lo, hi;
    { int l = 0, r = NN; while (l < r) { int m = (l + r) >> 1; if (batch[m] < b) l = m + 1; else r = m; } lo = l; }
    { int l = lo, r = NN; while (l < r) { int m = (l + r) >> 1; if (batch[m] <= b) l = m + 1; else r = m; } hi = l; }
    float s = 0.f;
    for (int nrow = lo + q; nrow < hi; nrow += 4)
        s += acc[(size_t)nrow * CD + t];
    __shared__ float red[4][CD];
    red[q][t] = s;
    __syncthreads();
    if (q == 0)
        pool[(size_t)b * CD + t] = red[0][t] + red[1][t] + red[2][t] + red[3][t];
}

// ================= head: tanh(pool), small GEMVs, sigmoid; f32 out =================
__global__ __launch_bounds__(128) void head_kernel(
    const float* __restrict__ pool_i, const float* __restrict__ pool_j,
    const float* __restrict__ W_out, const float* __restrict__ b_out,
    const float* __restrict__ W_i, const float* __restrict__ b_i,
    const float* __restrict__ W_j, const float* __restrict__ b_j,
    float* __restrict__ out)
{
    int b = blockIdx.x;
    int t = threadIdx.x;
    __shared__ float pi[CD], pj[CD];
    pi[t] = tanhf(pool_i[(size_t)b * CD + t]);
    pj[t] = tanhf(pool_j[(size_t)b * CD + t]);
    __syncthreads();
    if (t < INNERD) {
        float a = b_i[t];
        for (int c = 0; c < CD; ++c) a += pi[c] * W_i[c * INNERD + t];
        out[BG + (size_t)b * INNERD + t] = a;
    } else {
        int k = t - INNERD;
        float a = b_j[k];
        for (int c = 0; c < CD; ++c) a += pj[c] * W_j[c * INNERD + k];
        out[BG + BG * INNERD + (size_t)b * INNERD + k] = a;
    }
    if (t == 0) {
        float a = b_out[0];
        for (int c = 0; c < CD; ++c) a += (pi[c] + pj[c]) * W_out[c];
        out[b] = 1.f / (1.f + expf(-a));
    }
}

// ================= host-side drivers =================
struct Ws {
    unsigned short *xl, *xr, *z_i, *z_j;
    float* acc;
    int *rowptr[4];                // per-relation rowptr (FAT2) or slot 0 only
    unsigned short *srcs[4];
    int *cnt, *cursor;
    float *pool_i, *pool_j;
};

static void build_csr(const int* ei, int* rowptr, unsigned short* srcs,
                      int* cnt, int* cursor, hipStream_t stream) {
    hipMemsetAsync(cnt, 0, NN * sizeof(int), stream);
    csr_hist<<<(EE + 255) / 256, 256, 0, stream>>>(ei, cnt);
    csr_scan<<<1, 1024, 0, stream>>>(cnt, rowptr, cursor);
    csr_scatter16<<<(ETOT + 255) / 256, 256, 0, stream>>>(ei, cursor, srcs);
}

// ---- FAT group pass: CSR slots provided (prebuilt); all-heads aggr ----
template <typename TA, bool A_EXACT>
static void run_group_fat(const TA* srcA[2], const TA* dstA[2],
                          const int* rp[2], const unsigned short* sr[2],
                          const int rids[2], int K,
                          const float* Wl, const float* Wr, const float* att,
                          const float* bias, int fin_mode,
                          unsigned short* zout, const int* batch, float* pool,
                          const Ws& w, hipStream_t stream)
{
    dim3 gg(HHD / 64, (NN + 63) / 64, 2);
    const int ablocks = NN / 4;   // 4 dst per block, 1 wave each (R7-proven)
    for (int q = 0; q < 2; ++q) {
        int r = rids[q];
        gemm_mfma<TA, A_EXACT><<<gg, 256, 0, stream>>>(
            srcA[q], dstA[q],
            Wl + (size_t)r * K * HHD, Wr + (size_t)r * K * HHD, HHD,
            w.xl, w.xr, NN, K, HHD);
        int fm = (q == 1) ? fin_mode : 0;
        fused_aggr4<<<ablocks, 256, 0, stream>>>(
            rp[q], sr[q], w.xl, w.xr,
            att + (size_t)r * HHD,
            w.acc, q > 0 ? 1 : 0, fm,
            bias + (size_t)rids[0] * HHD, bias + (size_t)rids[1] * HHD,
            zout, batch, pool);
    }
}

// ---- THIN group pass: per-head, rebuilds CSR slot 0 per relation ----
template <typename TA, bool A_EXACT>
static void run_group_thin(const TA* srcA[2], const TA* dstA[2],
                           const int* eis[2], const int rids[2], int K,
                           const float* Wl, const float* Wr, const float* att,
                           const float* bias, int fin_mode,
                           unsigned short* zout, const int* batch, float* pool,
                           const Ws& w, hipStream_t stream)
{
    dim3 gg(2, (NN + 63) / 64, 2);
    const int ablocks = NN / 4;
    for (int q = 0; q < 2; ++q) {
        int r = rids[q];
        build_csr(eis[q], w.rowptr[0], w.srcs[0], w.cnt, w.cursor, stream);
        for (int h = 0; h < HH_; ++h) {
            const float* WlS = Wl + (size_t)r * K * HHD + h * CD;
            const float* WrS = Wr + (size_t)r * K * HHD + h * CD;
            gemm_mfma<TA, A_EXACT><<<gg, 256, 0, stream>>>(
                srcA[q], dstA[q], WlS, WrS, HHD, w.xl, w.xr, NN, K, CD);
            int pass = q * HH_ + h;
            int fm = (pass == 2 * HH_ - 1) ? fin_mode : 0;
            fused_aggr1<<<ablocks, 256, 0, stream>>>(
                w.rowptr[0], w.srcs[0], w.xl, w.xr,
                att + (size_t)r * HHD + h * CD,
                w.acc, pass > 0 ? 1 : 0, fm,
                bias + (size_t)rids[0] * HHD, bias + (size_t)rids[1] * HHD,
                zout, batch, pool);
        }
    }
}

extern "C" void kernel_launch(void* const* d_in, const int* in_sizes, int n_in,
                              void* d_out, int out_size, void* d_ws, size_t ws_size,
                              hipStream_t stream)
{
    const float* x_i   = (const float*)d_in[0];
    const float* x_j   = (const float*)d_in[1];
    const int* ei_ii   = (const int*)d_in[2];
    const int* ei_jj   = (const int*)d_in[3];
    const int* ei_ij   = (const int*)d_in[4];
    const int* ei_ji   = (const int*)d_in[5];
    const int* batch_i = (const int*)d_in[6];
    const int* batch_j = (const int*)d_in[7];
    const float* Wl0   = (const float*)d_in[8];
    const float* Wr0   = (const float*)d_in[9];
    const float* att0  = (const float*)d_in[10];
    const float* b0    = (const float*)d_in[11];
    const float* Wl1   = (const float*)d_in[12];
    const float* Wr1   = (const float*)d_in[13];
    const float* att1  = (const float*)d_in[14];
    const float* b1    = (const float*)d_in[15];
    const float* W_out = (const float*)d_in[16];
    const float* b_out = (const float*)d_in[17];
    const float* W_i   = (const float*)d_in[18];
    const float* b_i   = (const float*)d_in[19];
    const float* W_j   = (const float*)d_in[20];
    const float* b_j   = (const float*)d_in[21];
    float* out = (float*)d_out;

    // FAT2: 4 prebuilt CSRs (uint16 srcs). 40.96 + 10.24 + 10.24 + 2.72 + 0.32 + 0.16 + 0.065 = 64.71 MB
    const size_t FAT2_BYTES = (size_t)NN * HHD * 2 * 2 + (size_t)NN * CD * 4
                            + (size_t)NN * CD * 2 * 2 + 4 * (size_t)ETOT * 2
                            + 4 * (size_t)(NN + 4) * 4 + (size_t)NN * 4 * 2
                            + (size_t)BG * CD * 4 * 2;
    // FAT1: 1 CSR slot rebuilt per relation-group (R7-equivalent, smaller)
    const size_t FAT1_BYTES = (size_t)NN * HHD * 2 * 2 + (size_t)NN * CD * 4
                            + (size_t)NN * CD * 2 * 2 + (size_t)ETOT * 2
                            + (size_t)(NN + 4) * 4 + (size_t)NN * 4 * 2
                            + (size_t)BG * CD * 4 * 2;
    const int ncsr = (ws_size >= FAT2_BYTES) ? 4 : 1;
    const bool fat = (ws_size >= FAT1_BYTES);

    Ws w;
    char* p = (char*)d_ws;
    size_t xbytes = fat ? (size_t)NN * HHD * 2 : (size_t)NN * CD * 2;
    w.xl     = (unsigned short*)p; p += xbytes;
    w.xr     = (unsigned short*)p; p += xbytes;
    w.acc    = (float*)p;          p += (size_t)NN * CD * 4;
    w.z_i    = (unsigned short*)p; p += (size_t)NN * CD * 2;
    w.z_j    = (unsigned short*)p; p += (size_t)NN * CD * 2;
    for (int r = 0; r < 4; ++r) {
        int rr = (r < ncsr) ? r : 0;
        if (r < ncsr) {
            w.rowptr[r] = (int*)p;            p += (size_t)(NN + 4) * 4;
            w.srcs[r]   = (unsigned short*)p; p += (size_t)ETOT * 2;
        } else {
            w.rowptr[r] = w.rowptr[rr]; w.srcs[r] = w.srcs[rr];
        }
    }
    w.cnt    = (int*)p;            p += (size_t)NN * 4;
    w.cursor = (int*)p;            p += (size_t)NN * 4;
    w.pool_i = (float*)p;          p += (size_t)BG * CD * 4;
    w.pool_j = (float*)p;          p += (size_t)BG * CD * 4;

    hipMemsetAsync(w.pool_i, 0, (size_t)BG * CD * sizeof(float), stream);
    hipMemsetAsync(w.pool_j, 0, (size_t)BG * CD * sizeof(float), stream);

    // relation ids: 0=ii, 1=jj, 2=ij, 3=ji
    const int* eis_all[4] = { ei_ii, ei_jj, ei_ij, ei_ji };
    const float* srcA0_i[2] = { x_i, x_j };  const float* dstA0_i[2] = { x_i, x_i };
    const float* srcA0_j[2] = { x_j, x_i };  const float* dstA0_j[2] = { x_j, x_j };
    const int rids_i[2] = { 0, 3 };
    const int rids_j[2] = { 1, 2 };
    const unsigned short* srcA1_i[2] = { w.z_i, w.z_j };
    const unsigned short* dstA1_i[2] = { w.z_i, w.z_i };
    const unsigned short* srcA1_j[2] = { w.z_j, w.z_i };
    const unsigned short* dstA1_j[2] = { w.z_j, w.z_j };

    if (fat) {
        if (ncsr == 4) {
            // build all 4 CSRs once, reuse across both layers
            for (int r = 0; r < 4; ++r)
                build_csr(eis_all[r], w.rowptr[r], w.srcs[r], w.cnt, w.cursor, stream);
            const int* rp_i[2] = { w.rowptr[0], w.rowptr[3] };
            const unsigned short* sr_i[2] = { w.srcs[0], w.srcs[3] };
            const int* rp_j[2] = { w.rowptr[1], w.rowptr[2] };
            const unsigned short* sr_j[2] = { w.srcs[1], w.srcs[2] };
            run_group_fat<float, false>(srcA0_i, dstA0_i, rp_i, sr_i, rids_i, FD,
                                        Wl0, Wr0, att0, b0, 1, w.z_i, nullptr, nullptr, w, stream);
            run_group_fat<float, false>(srcA0_j, dstA0_j, rp_j, sr_j, rids_j, FD,
                                        Wl0, Wr0, att0, b0, 1, w.z_j, nullptr, nullptr, w, stream);
            run_group_fat<unsigned short, true>(srcA1_i, dstA1_i, rp_i, sr_i, rids_i, CD,
                                                Wl1, Wr1, att1, b1, 2, nullptr, batch_i, w.pool_i, w, stream);
            pool_reduce<<<BG, 512, 0, stream>>>(w.acc, batch_i, w.pool_i);
            run_group_fat<unsigned short, true>(srcA1_j, dstA1_j, rp_j, sr_j, rids_j, CD,
                                                Wl1, Wr1, att1, b1, 2, nullptr, batch_j, w.pool_j, w, stream);
            pool_reduce<<<BG, 512, 0, stream>>>(w.acc, batch_j, w.pool_j);
        } else {
            // 1 CSR slot: rebuild per relation (8 builds) — R7-equivalent
            for (int pass = 0; pass < 4; ++pass) {
                // pass 0: L0 gi; 1: L0 gj; 2: L1 gi; 3: L1 gj
                const int* rids = (pass & 1) ? rids_j : rids_i;
                for (int q = 0; q < 2; ++q) {
                    int r = rids[q];
                    build_csr(eis_all[r], w.rowptr[0], w.srcs[0], w.cnt, w.cursor, stream);
                    dim3 gg(HHD / 64, (NN + 63) / 64, 2);
                    if (pass < 2) {
                        const float* sa = (pass == 0) ? srcA0_i[q] : srcA0_j[q];
                        const float* da = (pass == 0) ? dstA0_i[q] : dstA0_j[q];
                        gemm_mfma<float, false><<<gg, 256, 0, stream>>>(
                            sa, da, Wl0 + (size_t)r * FD * HHD, Wr0 + (size_t)r * FD * HHD,
                            HHD, w.xl, w.xr, NN, FD, HHD);
                        fused_aggr4<<<NN / 4, 256, 0, stream>>>(
                            w.rowptr[0], w.srcs[0], w.xl, w.xr, att0 + (size_t)r * HHD,
                            w.acc, q, (q == 1) ? 1 : 0,
                            b0 + (size_t)rids[0] * HHD, b0 + (size_t)rids[1] * HHD,
                            (pass == 0) ? w.z_i : w.z_j, nullptr, nullptr);
                    } else {
                        const unsigned short* sa = (pass == 2) ? srcA1_i[q] : srcA1_j[q];
                        const unsigned short* da = (pass == 2) ? dstA1_i[q] : dstA1_j[q];
                        gemm_mfma<unsigned short, true><<<gg, 256, 0, stream>>>(
                            sa, da, Wl1 + (size_t)r * CD * HHD, Wr1 + (size_t)r * CD * HHD,
                            HHD, w.xl, w.xr, NN, CD, HHD);
                        fused_aggr4<<<NN / 4, 256, 0, stream>>>(
                            w.rowptr[0], w.srcs[0], w.xl, w.xr, att1 + (size_t)r * HHD,
                            w.acc, q, (q == 1) ? 2 : 0,
                            b1 + (size_t)rids[0] * HHD, b1 + (size_t)rids[1] * HHD,
                            nullptr, (pass == 2) ? batch_i : batch_j,
                            (pass == 2) ? w.pool_i : w.pool_j);
                    }
                }
                if (pass == 2)
                    pool_reduce<<<BG, 512, 0, stream>>>(w.acc, batch_i, w.pool_i);
                else if (pass == 3)
                    pool_reduce<<<BG, 512, 0, stream>>>(w.acc, batch_j, w.pool_j);
            }
        }
    } else {
        const int* eis_i[2] = { ei_ii, ei_ji };
        const int* eis_j[2] = { ei_jj, ei_ij };
        run_group_thin<float, false>(srcA0_i, dstA0_i, eis_i, rids_i, FD, Wl0, Wr0, att0, b0,
                                     1, w.z_i, nullptr, nullptr, w, stream);
        run_group_thin<float, false>(srcA0_j, dstA0_j, eis_j, rids_j, FD, Wl0, Wr0, att0, b0,
                                     1, w.z_j, nullptr, nullptr, w, stream);
        run_group_thin<unsigned short, true>(srcA1_i, dstA1_i, eis_i, rids_i, CD, Wl1, Wr1, att1, b1,
                                             2, nullptr, batch_i, w.pool_i, w, stream);
        run_group_thin<unsigned short, true>(srcA1_j, dstA1_j, eis_j, rids_j, CD, Wl1, Wr1, att1, b1,
                                             2, nullptr, batch_j, w.pool_j, w, stream);
    }

    head_kernel<<<BG, 128, 0, stream>>>(w.pool_i, w.pool_j, W_out, b_out,
                                        W_i, b_i, W_j, b_j, out);
}

// Round 2
// 1482.137 us; speedup vs baseline: 1.3148x; 1.0842x over previous
//
#include <hip/hip_runtime.h>

// ---------------- problem constants ----------------
#define NN      20000     // nodes per type
#define EE      320000    // edges per relation
#define ETOT    340000    // EE + NN self loops
#define FD      512       // raw feature dim
#define HH_     4         // heads
#define CD      128       // channels per head
#define HHD     512       // H*C
#define BG      64        // batch graphs
#define INNERD  64

typedef __attribute__((ext_vector_type(8))) short bf16x8;
typedef __attribute__((ext_vector_type(4))) float f32x4;

// ---- bf16 <-> f32 via raw bits ----
__device__ __forceinline__ float bf2f(unsigned v) { return __uint_as_float(v << 16); }
__device__ __forceinline__ unsigned short f2bf(float f) {
    unsigned u = __float_as_uint(f);
    unsigned r = 0x7fffu + ((u >> 16) & 1u);
    return (unsigned short)((u + r) >> 16);
}
__device__ __forceinline__ void load8bf(const unsigned short* p, float* f) {
    uint4 u = *reinterpret_cast<const uint4*>(p);
    f[0] = bf2f(u.x & 0xffffu); f[1] = bf2f(u.x >> 16);
    f[2] = bf2f(u.y & 0xffffu); f[3] = bf2f(u.y >> 16);
    f[4] = bf2f(u.z & 0xffffu); f[5] = bf2f(u.z >> 16);
    f[6] = bf2f(u.w & 0xffffu); f[7] = bf2f(u.w >> 16);
}
// fast split f32 -> hi + lo bf16 (truncation; residual ~2^-16 relative)
__device__ __forceinline__ void split_f32(float x, unsigned short& hi, unsigned short& lo) {
    unsigned u = __float_as_uint(x);
    hi = (unsigned short)(u >> 16);
    float r = x - bf2f(hi);
    lo = (unsigned short)(__float_as_uint(r) >> 16);
}
template <typename TA>
__device__ __forceinline__ void splitA(const TA* p, size_t i, unsigned short& hi, unsigned short& lo);
template <>
__device__ __forceinline__ void splitA<float>(const float* p, size_t i, unsigned short& hi, unsigned short& lo) {
    split_f32(p[i], hi, lo);
}
template <>
__device__ __forceinline__ void splitA<unsigned short>(const unsigned short* p, size_t i, unsigned short& hi, unsigned short& lo) {
    hi = p[i]; lo = 0;
}

// ================= CSR build =================
__global__ __launch_bounds__(256) void csr_hist(const int* __restrict__ ei, int* __restrict__ cnt) {
    int e = blockIdx.x * blockDim.x + threadIdx.x;
    if (e < EE) atomicAdd(&cnt[ei[EE + e]], 1);
}

__global__ __launch_bounds__(1024) void csr_scan(const int* __restrict__ cnt,
                                                 int* __restrict__ rowptr,
                                                 int* __restrict__ cursor) {
    __shared__ int part[1024];
    int t = threadIdx.x;
    int base = t * 20;
    int s = 0;
    #pragma unroll
    for (int i = 0; i < 20; ++i) { int n = base + i; if (n < NN) s += cnt[n] + 1; }
    part[t] = s;
    __syncthreads();
    for (int off = 1; off < 1024; off <<= 1) {
        int v = (t >= off) ? part[t - off] : 0;
        __syncthreads();
        part[t] += v;
        __syncthreads();
    }
    int run = (t > 0) ? part[t - 1] : 0;
    #pragma unroll
    for (int i = 0; i < 20; ++i) {
        int n = base + i;
        if (n < NN) { rowptr[n] = run; cursor[n] = run; run += cnt[n] + 1; }
    }
    if (t == 1023) rowptr[NN] = run;
}

// scatter src ids as uint16 (node ids < 65536); self-loop appended per node
__global__ __launch_bounds__(256) void csr_scatter16(const int* __restrict__ ei,
                                                     int* __restrict__ cursor,
                                                     unsigned short* __restrict__ srcs) {
    int idx = blockIdx.x * blockDim.x + threadIdx.x;
    if (idx >= ETOT) return;
    int src, dst;
    if (idx < EE) { src = ei[idx]; dst = ei[EE + idx]; }
    else          { src = dst = idx - EE; }
    int pos = atomicAdd(&cursor[dst], 1);
    srcs[pos] = (unsigned short)src;
}

// ================= W pre-split: [R][K][512] f32 -> hi/lo [R][512][K] bf16 ============
// LDS-transposed so both read and write are coalesced. Done ONCE — removes the
// per-M-tile redundant split VALU (157x) from the GEMM inner loop.
__global__ __launch_bounds__(256) void wsplit_t(const float* __restrict__ W,
                                                unsigned short* __restrict__ Whi,
                                                unsigned short* __restrict__ Wlo,
                                                int K)
{
    __shared__ float tile[64][65];
    const int nt = 512 / 64;
    const int kt = K / 64;
    int bid = blockIdx.x;
    int in = bid % nt; int ik = (bid / nt) % kt; int r = bid / (nt * kt);
    int t = threadIdx.x;
    const float* Wr_ = W + (size_t)r * K * 512;
    #pragma unroll
    for (int rep = 0; rep < 16; ++rep) {
        int idx = rep * 256 + t;
        int kk = idx >> 6, nn = idx & 63;
        tile[kk][nn] = Wr_[(size_t)(ik * 64 + kk) * 512 + in * 64 + nn];
    }
    __syncthreads();
    #pragma unroll
    for (int rep = 0; rep < 16; ++rep) {
        int idx = rep * 256 + t;
        int nn = idx >> 6, kk = idx & 63;
        unsigned short h, l; split_f32(tile[kk][nn], h, l);
        size_t o = ((size_t)r * 512 + in * 64 + nn) * K + ik * 64 + kk;
        Whi[o] = h; Wlo[o] = l;
    }
}

// ================= 128x128 split-bf16 MFMA GEMM (pre-split transposed B) =============
// C[M,N](bf16) = A[M,K] @ B; B given as hi/lo bf16 [N][K] (pre-transposed).
// 256 thr, 4 waves (2x2 of 64x64). blockIdx.z batches xl/xr. XCD-chunk swizzled.
template <typename TA, bool A_EXACT>
__global__ __launch_bounds__(256, 3) void gemm_mfma_t(
    const TA* __restrict__ A0, const TA* __restrict__ A1,
    const unsigned short* __restrict__ B0h, const unsigned short* __restrict__ B0l,
    const unsigned short* __restrict__ B1h, const unsigned short* __restrict__ B1l,
    unsigned short* __restrict__ C0, unsigned short* __restrict__ C1,
    int M, int K, int N)
{
    // bijective XCD-chunk swizzle (m204): same-A blocks land on the same XCD L2
    const int gx = gridDim.x, gy = gridDim.y;
    const int nwg = gx * gy * (int)gridDim.z;
    int b = ((int)blockIdx.z * gy + blockIdx.y) * gx + blockIdx.x;
    int xcd = b & 7, q8 = nwg >> 3, r8 = nwg & 7;
    int work = (xcd < r8 ? xcd * (q8 + 1) : r8 * (q8 + 1) + (xcd - r8) * q8) + (b >> 3);
    int bx = work % gx; int t2 = work / gx; int by = t2 % gy; int bz = t2 / gy;

    const TA* A = bz ? A1 : A0;
    const unsigned short* Bhg = bz ? B1h : B0h;
    const unsigned short* Blg = bz ? B1l : B0l;
    unsigned short* C = bz ? C1 : C0;

    __shared__ unsigned short Ah[128][40];
    __shared__ unsigned short Al[A_EXACT ? 1 : 128][40];
    __shared__ unsigned short Bh[128][40];
    __shared__ unsigned short Bl[128][40];

    const int tid = threadIdx.x;
    const int wave = tid >> 6, lane = tid & 63;
    const int quad = lane >> 4, lrow = lane & 15;
    const int wr = (wave >> 1) * 64, wc = (wave & 1) * 64;
    const int tileM = by * 128, tileN = bx * 128;

    const int srow = tid >> 1;            // staging row/col (0..127)
    const int sks  = (tid & 1) * 16;      // staging k-offset (0 or 16)
    const int sgm  = tileM + srow;

    f32x4 acc[4][4] = {};

    for (int k0 = 0; k0 < K; k0 += 32) {
        // ---- stage A: 128 x 32 ----
        if constexpr (!A_EXACT) {
            bf16x8 ph[2] = {{}, {}}, pl[2] = {{}, {}};
            if (sgm < M) {
                const float* Ap = (const float*)A + (size_t)sgm * K + k0 + sks;
                #pragma unroll
                for (int s = 0; s < 2; ++s) {
                    float4 f0 = reinterpret_cast<const float4*>(Ap)[2 * s];
                    float4 f1 = reinterpret_cast<const float4*>(Ap)[2 * s + 1];
                    float xv[8] = {f0.x, f0.y, f0.z, f0.w, f1.x, f1.y, f1.z, f1.w};
                    #pragma unroll
                    for (int pp = 0; pp < 4; ++pp) {
                        unsigned u0 = __float_as_uint(xv[2 * pp]);
                        unsigned u1 = __float_as_uint(xv[2 * pp + 1]);
                        // pack top16(u0),top16(u1) in one v_perm
                        reinterpret_cast<unsigned*>(&ph[s])[pp] =
                            __builtin_amdgcn_perm(u1, u0, 0x07060302u);
                        float r0 = xv[2 * pp]     - __uint_as_float(u0 & 0xffff0000u);
                        float r1 = xv[2 * pp + 1] - __uint_as_float(u1 & 0xffff0000u);
                        reinterpret_cast<unsigned*>(&pl[s])[pp] =
                            __builtin_amdgcn_perm(__float_as_uint(r1), __float_as_uint(r0), 0x07060302u);
                    }
                }
            }
            *reinterpret_cast<bf16x8*>(&Ah[srow][sks])     = ph[0];
            *reinterpret_cast<bf16x8*>(&Ah[srow][sks + 8]) = ph[1];
            *reinterpret_cast<bf16x8*>(&Al[srow][sks])     = pl[0];
            *reinterpret_cast<bf16x8*>(&Al[srow][sks + 8]) = pl[1];
        } else {
            bf16x8 v0 = {}, v1 = {};
            if (sgm < M) {
                const unsigned short* Ap = (const unsigned short*)A + (size_t)sgm * K + k0 + sks;
                v0 = reinterpret_cast<const bf16x8*>(Ap)[0];
                v1 = reinterpret_cast<const bf16x8*>(Ap)[1];
            }
            *reinterpret_cast<bf16x8*>(&Ah[srow][sks])     = v0;
            *reinterpret_cast<bf16x8*>(&Ah[srow][sks + 8]) = v1;
        }
        // ---- stage B: pure bf16 copies (pre-split, pre-transposed [N][K]) ----
        {
            const unsigned short* Bp = Bhg + (size_t)(tileN + srow) * K + k0 + sks;
            const unsigned short* Bq = Blg + (size_t)(tileN + srow) * K + k0 + sks;
            bf16x8 h0 = reinterpret_cast<const bf16x8*>(Bp)[0];
            bf16x8 h1 = reinterpret_cast<const bf16x8*>(Bp)[1];
            bf16x8 l0 = reinterpret_cast<const bf16x8*>(Bq)[0];
            bf16x8 l1 = reinterpret_cast<const bf16x8*>(Bq)[1];
            *reinterpret_cast<bf16x8*>(&Bh[srow][sks])     = h0;
            *reinterpret_cast<bf16x8*>(&Bh[srow][sks + 8]) = h1;
            *reinterpret_cast<bf16x8*>(&Bl[srow][sks])     = l0;
            *reinterpret_cast<bf16x8*>(&Bl[srow][sks + 8]) = l1;
        }
        __syncthreads();
        bf16x8 ah[4], al[4], bh[4], bl[4];
        #pragma unroll
        for (int mi = 0; mi < 4; ++mi) {
            ah[mi] = *reinterpret_cast<const bf16x8*>(&Ah[wr + mi * 16 + lrow][quad * 8]);
            if constexpr (!A_EXACT)
                al[mi] = *reinterpret_cast<const bf16x8*>(&Al[wr + mi * 16 + lrow][quad * 8]);
        }
        #pragma unroll
        for (int ni = 0; ni < 4; ++ni) {
            bh[ni] = *reinterpret_cast<const bf16x8*>(&Bh[wc + ni * 16 + lrow][quad * 8]);
            bl[ni] = *reinterpret_cast<const bf16x8*>(&Bl[wc + ni * 16 + lrow][quad * 8]);
        }
        #pragma unroll
        for (int mi = 0; mi < 4; ++mi)
            #pragma unroll
            for (int ni = 0; ni < 4; ++ni) {
                acc[mi][ni] = __builtin_amdgcn_mfma_f32_16x16x32_bf16(
                    ah[mi], bh[ni], acc[mi][ni], 0, 0, 0);
                acc[mi][ni] = __builtin_amdgcn_mfma_f32_16x16x32_bf16(
                    ah[mi], bl[ni], acc[mi][ni], 0, 0, 0);
                if constexpr (!A_EXACT)
                    acc[mi][ni] = __builtin_amdgcn_mfma_f32_16x16x32_bf16(
                        al[mi], bh[ni], acc[mi][ni], 0, 0, 0);
            }
        __syncthreads();
    }
    // ---- epilogue: C/D layout col=lane&15, row=quad*4+reg ----
    #pragma unroll
    for (int mi = 0; mi < 4; ++mi) {
        #pragma unroll
        for (int ni = 0; ni < 4; ++ni) {
            int gcol = tileN + wc + ni * 16 + lrow;
            #pragma unroll
            for (int r = 0; r < 4; ++r) {
                int grow = tileM + wr + mi * 16 + quad * 4 + r;
                if (grow < M)
                    C[(size_t)grow * N + gcol] = f2bf(acc[mi][ni][r]);
            }
        }
    }
}

// ================= OLD 64x64 split-bf16 GEMM (fallback paths) =================
template <typename TA, bool A_EXACT>
__global__ __launch_bounds__(256) void gemm_mfma(
    const TA* __restrict__ A0, const TA* __restrict__ A1,
    const float* __restrict__ B0, const float* __restrict__ B1, int ldb,
    unsigned short* __restrict__ C0, unsigned short* __restrict__ C1,
    int M, int K, int N)
{
    const TA* A = blockIdx.z ? A1 : A0;
    const float* B = blockIdx.z ? B1 : B0;
    unsigned short* C = blockIdx.z ? C1 : C0;

    __shared__ unsigned short Ah[64][40];
    __shared__ unsigned short Al[64][40];
    __shared__ unsigned short Bh[64][40];
    __shared__ unsigned short Bl[64][40];
    const int tid = threadIdx.x;
    const int wave = tid >> 6, lane = tid & 63;
    const int quad = lane >> 4, lrow = lane & 15;
    const int tileM = blockIdx.y * 64, tileN = blockIdx.x * 64;
    const int wm = (wave >> 1) * 32, wn = (wave & 1) * 32;

    f32x4 acc[2][2] = {};

    const int am = tid >> 2;
    const int aks = (tid & 3) * 8;
    const int bn = tid & 63;
    const int bk0 = (tid >> 6) * 8;

    for (int k0 = 0; k0 < K; k0 += 32) {
        {
            int gm = tileM + am;
            bf16x8 ph = {}, pl = {};
            if (gm < M) {
                #pragma unroll
                for (int j = 0; j < 8; ++j) {
                    unsigned short h, l;
                    splitA(A, (size_t)gm * K + k0 + aks + j, h, l);
                    ph[j] = (short)h; pl[j] = (short)l;
                }
            }
            *reinterpret_cast<bf16x8*>(&Ah[am][aks]) = ph;
            if (!A_EXACT) *reinterpret_cast<bf16x8*>(&Al[am][aks]) = pl;
        }
        {
            bf16x8 ph, pl;
            #pragma unroll
            for (int j = 0; j < 8; ++j) {
                unsigned short h, l;
                split_f32(B[(size_t)(k0 + bk0 + j) * ldb + tileN + bn], h, l);
                ph[j] = (short)h; pl[j] = (short)l;
            }
            *reinterpret_cast<bf16x8*>(&Bh[bn][bk0]) = ph;
            *reinterpret_cast<bf16x8*>(&Bl[bn][bk0]) = pl;
        }
        __syncthreads();
        bf16x8 ah[2], al[2], bh[2], bl[2];
        #pragma unroll
        for (int mi = 0; mi < 2; ++mi) {
            ah[mi] = *reinterpret_cast<const bf16x8*>(&Ah[wm + mi * 16 + lrow][quad * 8]);
            if (!A_EXACT)
                al[mi] = *reinterpret_cast<const bf16x8*>(&Al[wm + mi * 16 + lrow][quad * 8]);
        }
        #pragma unroll
        for (int ni = 0; ni < 2; ++ni) {
            bh[ni] = *reinterpret_cast<const bf16x8*>(&Bh[wn + ni * 16 + lrow][quad * 8]);
            bl[ni] = *reinterpret_cast<const bf16x8*>(&Bl[wn + ni * 16 + lrow][quad * 8]);
        }
        #pragma unroll
        for (int mi = 0; mi < 2; ++mi)
            #pragma unroll
            for (int ni = 0; ni < 2; ++ni) {
                acc[mi][ni] = __builtin_amdgcn_mfma_f32_16x16x32_bf16(
                    ah[mi], bh[ni], acc[mi][ni], 0, 0, 0);
                acc[mi][ni] = __builtin_amdgcn_mfma_f32_16x16x32_bf16(
                    ah[mi], bl[ni], acc[mi][ni], 0, 0, 0);
                if (!A_EXACT)
                    acc[mi][ni] = __builtin_amdgcn_mfma_f32_16x16x32_bf16(
                        al[mi], bh[ni], acc[mi][ni], 0, 0, 0);
            }
        __syncthreads();
    }
    #pragma unroll
    for (int mi = 0; mi < 2; ++mi) {
        #pragma unroll
        for (int ni = 0; ni < 2; ++ni) {
            int gcol = tileN + wn + ni * 16 + lrow;
            #pragma unroll
            for (int r = 0; r < 4; ++r) {
                int grow = tileM + wm + mi * 16 + quad * 4 + r;
                if (grow < M)
                    C[(size_t)grow * N + gcol] = f2bf(acc[mi][ni][r]);
            }
        }
    }
}

// ================= THIN: fused GATv2 pass, one head (xl/xr [NN,128]) =================
__global__ __launch_bounds__(256) void fused_aggr1(
    const int* __restrict__ rowptr, const unsigned short* __restrict__ srcs,
    const unsigned short* __restrict__ xl, const unsigned short* __restrict__ xr,
    const float* __restrict__ att,
    float* __restrict__ acc, int add_in, int fin_mode,
    const float* __restrict__ bA, const float* __restrict__ bB,
    unsigned short* __restrict__ z,
    const int* __restrict__ batch, float* __restrict__ pool)
{
    int dst = (int)((blockIdx.x * (size_t)blockDim.x + threadIdx.x) >> 6);
    int lane = threadIdx.x & 63;
    if (dst >= NN) return;
    int beg = rowptr[dst], end = rowptr[dst + 1];

    unsigned ub = *reinterpret_cast<const unsigned*>(xr + (size_t)dst * CD + lane * 2);
    float br0 = bf2f(ub & 0xffffu), br1 = bf2f(ub >> 16);
    float ta0 = att[lane * 2], ta1 = att[lane * 2 + 1];

    float n0 = 0.f, n1 = 0.f, den = 0.f;
    for (int k = beg; k < end; ++k) {
        int src = srcs[k];
        unsigned ua = *reinterpret_cast<const unsigned*>(xl + (size_t)src * CD + lane * 2);
        float a0 = bf2f(ua & 0xffffu), a1 = bf2f(ua >> 16);
        float v0 = a0 + br0, v1 = a1 + br1;
        v0 = (v0 > 0.f) ? v0 : 0.2f * v0;
        v1 = (v1 > 0.f) ? v1 : 0.2f * v1;
        float d = v0 * ta0 + v1 * ta1;
        #pragma unroll
        for (int off = 1; off < 64; off <<= 1)
            d += __shfl_xor(d, off);
        float p = expf(d);
        n0 += p * a0; n1 += p * a1; den += p;
    }
    float o0 = n0 / den, o1 = n1 / den;
    size_t ai = (size_t)dst * CD + lane * 2;
    if (add_in) { o0 += acc[ai]; o1 += acc[ai + 1]; }
    if (fin_mode == 0) {
        acc[ai] = o0; acc[ai + 1] = o1;
    } else {
        int c0 = lane * 2;
        float bb0 = 0.f, bb1 = 0.f;
        #pragma unroll
        for (int h = 0; h < HH_; ++h) {
            bb0 += bA[h * CD + c0]     + bB[h * CD + c0];
            bb1 += bA[h * CD + c0 + 1] + bB[h * CD + c0 + 1];
        }
        o0 = tanhf(o0 + bb0);
        o1 = tanhf(o1 + bb1);
        if (fin_mode == 1) {
            z[ai] = f2bf(o0); z[ai + 1] = f2bf(o1);
        } else {
            int b = batch[dst];
            atomicAdd(&pool[(size_t)b * CD + c0],     o0);
            atomicAdd(&pool[(size_t)b * CD + c0 + 1], o1);
        }
    }
}

// ================= FAT: fused GATv2 pass, ALL 4 heads =================
// fin_mode: 0 = store partial acc (f32); 1 = bias+tanh -> z (bf16);
//           2 = bias+tanh -> acc (f32), later reduced by pool_reduce (NO atomics)
__global__ __launch_bounds__(256) void fused_aggr4(
    const int* __restrict__ rowptr, const unsigned short* __restrict__ srcs,
    const unsigned short* __restrict__ xl, const unsigned short* __restrict__ xr,
    const float* __restrict__ att,
    float* __restrict__ acc, int add_in, int fin_mode,
    const float* __restrict__ bA, const float* __restrict__ bB,
    unsigned short* __restrict__ z,
    const int* __restrict__ batch, float* __restrict__ pool)
{
    int dst = (int)((blockIdx.x * (size_t)blockDim.x + threadIdx.x) >> 6);
    int lane = threadIdx.x & 63;
    if (dst >= NN) return;
    int beg = rowptr[dst], end = rowptr[dst + 1];

    float br[8], ta[8];
    load8bf(xr + (size_t)dst * HHD + lane * 8, br);
    #pragma unroll
    for (int j = 0; j < 8; ++j) ta[j] = att[lane * 8 + j];

    float n[8] = {}; float den = 0.f;
    for (int k = beg; k < end; ++k) {
        int src = srcs[k];
        float a[8];
        load8bf(xl + (size_t)src * HHD + lane * 8, a);
        float d = 0.f;
        #pragma unroll
        for (int j = 0; j < 8; ++j) {
            float v = a[j] + br[j];
            v = (v > 0.f) ? v : 0.2f * v;
            d += v * ta[j];
        }
        d += __shfl_xor(d, 1);
        d += __shfl_xor(d, 2);
        d += __shfl_xor(d, 4);
        d += __shfl_xor(d, 8);
        float p = expf(d);
        den += p;
        #pragma unroll
        for (int j = 0; j < 8; ++j) n[j] += p * a[j];
    }
    float inv = 1.f / den;
    float o[8];
    #pragma unroll
    for (int j = 0; j < 8; ++j) {
        o[j] = n[j] * inv;
        o[j] += __shfl_xor(o[j], 16);
        o[j] += __shfl_xor(o[j], 32);
    }
    if (lane < 16) {
        size_t ai = (size_t)dst * CD + lane * 8;
        if (add_in) {
            #pragma unroll
            for (int j = 0; j < 8; ++j) o[j] += acc[ai + j];
        }
        if (fin_mode == 0) {
            #pragma unroll
            for (int j = 0; j < 8; ++j) acc[ai + j] = o[j];
        } else {
            int c0 = lane * 8;
            #pragma unroll
            for (int j = 0; j < 8; ++j) {
                float bb = 0.f;
                #pragma unroll
                for (int h = 0; h < HH_; ++h)
                    bb += bA[h * CD + c0 + j] + bB[h * CD + c0 + j];
                o[j] = tanhf(o[j] + bb);
            }
            if (fin_mode == 1) {
                #pragma unroll
                for (int j = 0; j < 8; ++j) z[ai + j] = f2bf(o[j]);
            } else {
                #pragma unroll
                for (int j = 0; j < 8; ++j) acc[ai + j] = o[j];
            }
        }
    }
}

// ================= pool_reduce: segmented sum over sorted batch (no atomics) ========
__global__ __launch_bounds__(512) void pool_reduce(
    const float* __restrict__ acc, const int* __restrict__ batch,
    float* __restrict__ pool)
{
    int b = blockIdx.x;
    int t = threadIdx.x & (CD - 1);
    int q = threadIdx.x >> 7;
    int lo, hi;
    { int l = 0, r = NN; while (l < r) { int m = (l + r) >> 1; if (batch[m] < b) l = m + 1; else r = m; } lo = l; }
    { int l = lo, r = NN; while (l < r) { int m = (l + r) >> 1; if (batch[m] <= b) l = m + 1; else r = m; } hi = l; }
    float s = 0.f;
    for (int nrow = lo + q; nrow < hi; nrow += 4)
        s += acc[(size_t)nrow * CD + t];
    __shared__ float red[4][CD];
    red[q][t] = s;
    __syncthreads();
    if (q == 0)
        pool[(size_t)b * CD + t] = red[0][t] + red[1][t] + red[2][t] + red[3][t];
}

// ================= head =================
__global__ __launch_bounds__(128) void head_kernel(
    const float* __restrict__ pool_i, const float* __restrict__ pool_j,
    const float* __restrict__ W_out, const float* __restrict__ b_out,
    const float* __restrict__ W_i, const float* __restrict__ b_i,
    const float* __restrict__ W_j, const float* __restrict__ b_j,
    float* __restrict__ out)
{
    int b = blockIdx.x;
    int t = threadIdx.x;
    __shared__ float pi[CD], pj[CD];
    pi[t] = tanhf(pool_i[(size_t)b * CD + t]);
    pj[t] = tanhf(pool_j[(size_t)b * CD + t]);
    __syncthreads();
    if (t < INNERD) {
        float a = b_i[t];
        for (int c = 0; c < CD; ++c) a += pi[c] * W_i[c * INNERD + t];
        out[BG + (size_t)b * INNERD + t] = a;
    } else {
        int k = t - INNERD;
        float a = b_j[k];
        for (int c = 0; c < CD; ++c) a += pj[c] * W_j[c * INNERD + k];
        out[BG + BG * INNERD + (size_t)b * INNERD + k] = a;
    }
    if (t == 0) {
        float a = b_out[0];
        for (int c = 0; c < CD; ++c) a += (pi[c] + pj[c]) * W_out[c];
        out[b] = 1.f / (1.f + expf(-a));
    }
}

// ================= host-side drivers =================
struct Ws {
    unsigned short *xl, *xr, *z_i, *z_j;
    float* acc;
    int *rowptr[4];
    unsigned short *srcs[4];
    int *cnt, *cursor;
    float *pool_i, *pool_j;
    // pre-split transposed weights (new path)
    unsigned short *wt0l_h, *wt0l_l, *wt0r_h, *wt0r_l;
    unsigned short *wt1l_h, *wt1l_l, *wt1r_h, *wt1r_l;
};

static void build_csr(const int* ei, int* rowptr, unsigned short* srcs,
                      int* cnt, int* cursor, hipStream_t stream) {
    hipMemsetAsync(cnt, 0, NN * sizeof(int), stream);
    csr_hist<<<(EE + 255) / 256, 256, 0, stream>>>(ei, cnt);
    csr_scan<<<1, 1024, 0, stream>>>(cnt, rowptr, cursor);
    csr_scatter16<<<(ETOT + 255) / 256, 256, 0, stream>>>(ei, cursor, srcs);
}

// ---- NEW FAT group pass: 128x128 GEMM with pre-split transposed weights ----
template <typename TA, bool A_EXACT>
static void run_group_fat_t(const TA* srcA[2], const TA* dstA[2],
                            const int* rp[2], const unsigned short* sr[2],
                            const int rids[2], int K,
                            const unsigned short* WTl_h, const unsigned short* WTl_l,
                            const unsigned short* WTr_h, const unsigned short* WTr_l,
                            const float* att, const float* bias, int fin_mode,
                            unsigned short* zout, const int* batch, float* pool,
                            const Ws& w, hipStream_t stream)
{
    dim3 gg(HHD / 128, (NN + 127) / 128, 2);
    const int ablocks = NN / 4;
    for (int q = 0; q < 2; ++q) {
        int r = rids[q];
        size_t off = (size_t)r * HHD * K;      // [r][512][K]
        gemm_mfma_t<TA, A_EXACT><<<gg, 256, 0, stream>>>(
            srcA[q], dstA[q],
            WTl_h + off, WTl_l + off, WTr_h + off, WTr_l + off,
            w.xl, w.xr, NN, K, HHD);
        int fm = (q == 1) ? fin_mode : 0;
        fused_aggr4<<<ablocks, 256, 0, stream>>>(
            rp[q], sr[q], w.xl, w.xr,
            att + (size_t)r * HHD,
            w.acc, q > 0 ? 1 : 0, fm,
            bias + (size_t)rids[0] * HHD, bias + (size_t)rids[1] * HHD,
            zout, batch, pool);
    }
}

// ---- OLD FAT group pass (fallback) ----
template <typename TA, bool A_EXACT>
static void run_group_fat(const TA* srcA[2], const TA* dstA[2],
                          const int* rp[2], const unsigned short* sr[2],
                          const int rids[2], int K,
                          const float* Wl, const float* Wr, const float* att,
                          const float* bias, int fin_mode,
                          unsigned short* zout, const int* batch, float* pool,
                          const Ws& w, hipStream_t stream)
{
    dim3 gg(HHD / 64, (NN + 63) / 64, 2);
    const int ablocks = NN / 4;
    for (int q = 0; q < 2; ++q) {
        int r = rids[q];
        gemm_mfma<TA, A_EXACT><<<gg, 256, 0, stream>>>(
            srcA[q], dstA[q],
            Wl + (size_t)r * K * HHD, Wr + (size_t)r * K * HHD, HHD,
            w.xl, w.xr, NN, K, HHD);
        int fm = (q == 1) ? fin_mode : 0;
        fused_aggr4<<<ablocks, 256, 0, stream>>>(
            rp[q], sr[q], w.xl, w.xr,
            att + (size_t)r * HHD,
            w.acc, q > 0 ? 1 : 0, fm,
            bias + (size_t)rids[0] * HHD, bias + (size_t)rids[1] * HHD,
            zout, batch, pool);
    }
}

// ---- THIN group pass (fallback) ----
template <typename TA, bool A_EXACT>
static void run_group_thin(const TA* srcA[2], const TA* dstA[2],
                           const int* eis[2], const int rids[2], int K,
                           const float* Wl, const float* Wr, const float* att,
                           const float* bias, int fin_mode,
                           unsigned short* zout, const int* batch, float* pool,
                           const Ws& w, hipStream_t stream)
{
    dim3 gg(2, (NN + 63) / 64, 2);
    const int ablocks = NN / 4;
    for (int q = 0; q < 2; ++q) {
        int r = rids[q];
        build_csr(eis[q], w.rowptr[0], w.srcs[0], w.cnt, w.cursor, stream);
        for (int h = 0; h < HH_; ++h) {
            const float* WlS = Wl + (size_t)r * K * HHD + h * CD;
            const float* WrS = Wr + (size_t)r * K * HHD + h * CD;
            gemm_mfma<TA, A_EXACT><<<gg, 256, 0, stream>>>(
                srcA[q], dstA[q], WlS, WrS, HHD, w.xl, w.xr, NN, K, CD);
            int pass = q * HH_ + h;
            int fm = (pass == 2 * HH_ - 1) ? fin_mode : 0;
            fused_aggr1<<<ablocks, 256, 0, stream>>>(
                w.rowptr[0], w.srcs[0], w.xl, w.xr,
                att + (size_t)r * HHD + h * CD,
                w.acc, pass > 0 ? 1 : 0, fm,
                bias + (size_t)rids[0] * HHD, bias + (size_t)rids[1] * HHD,
                zout, batch, pool);
        }
    }
}

extern "C" void kernel_launch(void* const* d_in, const int* in_sizes, int n_in,
                              void* d_out, int out_size, void* d_ws, size_t ws_size,
                              hipStream_t stream)
{
    const float* x_i   = (const float*)d_in[0];
    const float* x_j   = (const float*)d_in[1];
    const int* ei_ii   = (const int*)d_in[2];
    const int* ei_jj   = (const int*)d_in[3];
    const int* ei_ij   = (const int*)d_in[4];
    const int* ei_ji   = (const int*)d_in[5];
    const int* batch_i = (const int*)d_in[6];
    const int* batch_j = (const int*)d_in[7];
    const float* Wl0   = (const float*)d_in[8];
    const float* Wr0   = (const float*)d_in[9];
    const float* att0  = (const float*)d_in[10];
    const float* b0    = (const float*)d_in[11];
    const float* Wl1   = (const float*)d_in[12];
    const float* Wr1   = (const float*)d_in[13];
    const float* att1  = (const float*)d_in[14];
    const float* b1    = (const float*)d_in[15];
    const float* W_out = (const float*)d_in[16];
    const float* b_out = (const float*)d_in[17];
    const float* W_i   = (const float*)d_in[18];
    const float* b_i   = (const float*)d_in[19];
    const float* W_j   = (const float*)d_in[20];
    const float* b_j   = (const float*)d_in[21];
    float* out = (float*)d_out;

    const size_t FAT2_BYTES = (size_t)NN * HHD * 2 * 2 + (size_t)NN * CD * 4
                            + (size_t)NN * CD * 2 * 2 + 4 * (size_t)ETOT * 2
                            + 4 * (size_t)(NN + 4) * 4 + (size_t)NN * 4 * 2
                            + (size_t)BG * CD * 4 * 2;
    const size_t FAT1_BYTES = (size_t)NN * HHD * 2 * 2 + (size_t)NN * CD * 4
                            + (size_t)NN * CD * 2 * 2 + (size_t)ETOT * 2
                            + (size_t)(NN + 4) * 4 + (size_t)NN * 4 * 2
                            + (size_t)BG * CD * 4 * 2;
    // pre-split transposed weights: L0 4x(4*512*512*2B)=8MB, L1 4x(4*512*128*2B)=2MB
    const size_t WT0_ONE = (size_t)4 * 512 * 512 * 2;
    const size_t WT1_ONE = (size_t)4 * 512 * 128 * 2;
    const size_t WT_BYTES = 4 * WT0_ONE + 4 * WT1_ONE;

    const int ncsr = (ws_size >= FAT2_BYTES) ? 4 : 1;
    const bool fat = (ws_size >= FAT1_BYTES);
    const bool fat_t = (ws_size >= FAT2_BYTES + WT_BYTES);   // new path

    Ws w;
    char* p = (char*)d_ws;
    size_t xbytes = fat ? (size_t)NN * HHD * 2 : (size_t)NN * CD * 2;
    w.xl     = (unsigned short*)p; p += xbytes;
    w.xr     = (unsigned short*)p; p += xbytes;
    w.acc    = (float*)p;          p += (size_t)NN * CD * 4;
    w.z_i    = (unsigned short*)p; p += (size_t)NN * CD * 2;
    w.z_j    = (unsigned short*)p; p += (size_t)NN * CD * 2;
    for (int r = 0; r < 4; ++r) {
        int rr = (r < ncsr) ? r : 0;
        if (r < ncsr) {
            w.rowptr[r] = (int*)p;            p += (size_t)(NN + 4) * 4;
            w.srcs[r]   = (unsigned short*)p; p += (size_t)ETOT * 2;
        } else {
            w.rowptr[r] = w.rowptr[rr]; w.srcs[r] = w.srcs[rr];
        }
    }
    w.cnt    = (int*)p;            p += (size_t)NN * 4;
    w.cursor = (int*)p;            p += (size_t)NN * 4;
    w.pool_i = (float*)p;          p += (size_t)BG * CD * 4;
    w.pool_j = (float*)p;          p += (size_t)BG * CD * 4;
    if (fat_t) {
        w.wt0l_h = (unsigned short*)p; p += WT0_ONE;
        w.wt0l_l = (unsigned short*)p; p += WT0_ONE;
        w.wt0r_h = (unsigned short*)p; p += WT0_ONE;
        w.wt0r_l = (unsigned short*)p; p += WT0_ONE;
        w.wt1l_h = (unsigned short*)p; p += WT1_ONE;
        w.wt1l_l = (unsigned short*)p; p += WT1_ONE;
        w.wt1r_h = (unsigned short*)p; p += WT1_ONE;
        w.wt1r_l = (unsigned short*)p; p += WT1_ONE;
    }

    hipMemsetAsync(w.pool_i, 0, (size_t)BG * CD * sizeof(float), stream);
    hipMemsetAsync(w.pool_j, 0, (size_t)BG * CD * sizeof(float), stream);

    const int* eis_all[4] = { ei_ii, ei_jj, ei_ij, ei_ji };
    const float* srcA0_i[2] = { x_i, x_j };  const float* dstA0_i[2] = { x_i, x_i };
    const float* srcA0_j[2] = { x_j, x_i };  const float* dstA0_j[2] = { x_j, x_j };
    const int rids_i[2] = { 0, 3 };
    const int rids_j[2] = { 1, 2 };
    const unsigned short* srcA1_i[2] = { w.z_i, w.z_j };
    const unsigned short* dstA1_i[2] = { w.z_i, w.z_i };
    const unsigned short* srcA1_j[2] = { w.z_j, w.z_i };
    const unsigned short* dstA1_j[2] = { w.z_j, w.z_j };

    if (fat_t) {
        // build all 4 CSRs once; pre-split+transpose all weights once
        for (int r = 0; r < 4; ++r)
            build_csr(eis_all[r], w.rowptr[r], w.srcs[r], w.cnt, w.cursor, stream);
        wsplit_t<<<4 * (FD / 64) * 8, 256, 0, stream>>>(Wl0, w.wt0l_h, w.wt0l_l, FD);
        wsplit_t<<<4 * (FD / 64) * 8, 256, 0, stream>>>(Wr0, w.wt0r_h, w.wt0r_l, FD);
        wsplit_t<<<4 * (CD / 64) * 8, 256, 0, stream>>>(Wl1, w.wt1l_h, w.wt1l_l, CD);
        wsplit_t<<<4 * (CD / 64) * 8, 256, 0, stream>>>(Wr1, w.wt1r_h, w.wt1r_l, CD);

        const int* rp_i[2] = { w.rowptr[0], w.rowptr[3] };
        const unsigned short* sr_i[2] = { w.srcs[0], w.srcs[3] };
        const int* rp_j[2] = { w.rowptr[1], w.rowptr[2] };
        const unsigned short* sr_j[2] = { w.srcs[1], w.srcs[2] };
        run_group_fat_t<float, false>(srcA0_i, dstA0_i, rp_i, sr_i, rids_i, FD,
                                      w.wt0l_h, w.wt0l_l, w.wt0r_h, w.wt0r_l,
                                      att0, b0, 1, w.z_i, nullptr, nullptr, w, stream);
        run_group_fat_t<float, false>(srcA0_j, dstA0_j, rp_j, sr_j, rids_j, FD,
                                      w.wt0l_h, w.wt0l_l, w.wt0r_h, w.wt0r_l,
                                      att0, b0, 1, w.z_j, nullptr, nullptr, w, stream);
        run_group_fat_t<unsigned short, true>(srcA1_i, dstA1_i, rp_i, sr_i, rids_i, CD,
                                              w.wt1l_h, w.wt1l_l, w.wt1r_h, w.wt1r_l,
                                              att1, b1, 2, nullptr, batch_i, w.pool_i, w, stream);
        pool_reduce<<<BG, 512, 0, stream>>>(w.acc, batch_i, w.pool_i);
        run_group_fat_t<unsigned short, true>(srcA1_j, dstA1_j, rp_j, sr_j, rids_j, CD,
                                              w.wt1l_h, w.wt1l_l, w.wt1r_h, w.wt1r_l,
                                              att1, b1, 2, nullptr, batch_j, w.pool_j, w, stream);
        pool_reduce<<<BG, 512, 0, stream>>>(w.acc, batch_j, w.pool_j);
    } else if (fat) {
        if (ncsr == 4) {
            for (int r = 0; r < 4; ++r)
                build_csr(eis_all[r], w.rowptr[r], w.srcs[r], w.cnt, w.cursor, stream);
            const int* rp_i[2] = { w.rowptr[0], w.rowptr[3] };
            const unsigned short* sr_i[2] = { w.srcs[0], w.srcs[3] };
            const int* rp_j[2] = { w.rowptr[1], w.rowptr[2] };
            const unsigned short* sr_j[2] = { w.srcs[1], w.srcs[2] };
            run_group_fat<float, false>(srcA0_i, dstA0_i, rp_i, sr_i, rids_i, FD,
                                        Wl0, Wr0, att0, b0, 1, w.z_i, nullptr, nullptr, w, stream);
            run_group_fat<float, false>(srcA0_j, dstA0_j, rp_j, sr_j, rids_j, FD,
                                        Wl0, Wr0, att0, b0, 1, w.z_j, nullptr, nullptr, w, stream);
            run_group_fat<unsigned short, true>(srcA1_i, dstA1_i, rp_i, sr_i, rids_i, CD,
                                                Wl1, Wr1, att1, b1, 2, nullptr, batch_i, w.pool_i, w, stream);
            pool_reduce<<<BG, 512, 0, stream>>>(w.acc, batch_i, w.pool_i);
            run_group_fat<unsigned short, true>(srcA1_j, dstA1_j, rp_j, sr_j, rids_j, CD,
                                                Wl1, Wr1, att1, b1, 2, nullptr, batch_j, w.pool_j, w, stream);
            pool_reduce<<<BG, 512, 0, stream>>>(w.acc, batch_j, w.pool_j);
        } else {
            for (int pass = 0; pass < 4; ++pass) {
                const int* rids = (pass & 1) ? rids_j : rids_i;
                for (int q = 0; q < 2; ++q) {
                    int r = rids[q];
                    build_csr(eis_all[r], w.rowptr[0], w.srcs[0], w.cnt, w.cursor, stream);
                    dim3 gg(HHD / 64, (NN + 63) / 64, 2);
                    if (pass < 2) {
                        const float* sa = (pass == 0) ? srcA0_i[q] : srcA0_j[q];
                        const float* da = (pass == 0) ? dstA0_i[q] : dstA0_j[q];
                        gemm_mfma<float, false><<<gg, 256, 0, stream>>>(
                            sa, da, Wl0 + (size_t)r * FD * HHD, Wr0 + (size_t)r * FD * HHD,
                            HHD, w.xl, w.xr, NN, FD, HHD);
                        fused_aggr4<<<NN / 4, 256, 0, stream>>>(
                            w.rowptr[0], w.srcs[0], w.xl, w.xr, att0 + (size_t)r * HHD,
                            w.acc, q, (q == 1) ? 1 : 0,
                            b0 + (size_t)rids[0] * HHD, b0 + (size_t)rids[1] * HHD,
                            (pass == 0) ? w.z_i : w.z_j, nullptr, nullptr);
                    } else {
                        const unsigned short* sa = (pass == 2) ? srcA1_i[q] : srcA1_j[q];
                        const unsigned short* da = (pass == 2) ? dstA1_i[q] : dstA1_j[q];
                        gemm_mfma<unsigned short, true><<<gg, 256, 0, stream>>>(
                            sa, da, Wl1 + (size_t)r * CD * HHD, Wr1 + (size_t)r * CD * HHD,
                            HHD, w.xl, w.xr, NN, CD, HHD);
                        fused_aggr4<<<NN / 4, 256, 0, stream>>>(
                            w.rowptr[0], w.srcs[0], w.xl, w.xr, att1 + (size_t)r * HHD,
                            w.acc, q, (q == 1) ? 2 : 0,
                            b1 + (size_t)rids[0] * HHD, b1 + (size_t)rids[1] * HHD,
                            nullptr, (pass == 2) ? batch_i : batch_j,
                            (pass == 2) ? w.pool_i : w.pool_j);
                    }
                }
                if (pass == 2)
                    pool_reduce<<<BG, 512, 0, stream>>>(w.acc, batch_i, w.pool_i);
                else if (pass == 3)
                    pool_reduce<<<BG, 512, 0, stream>>>(w.acc, batch_j, w.pool_j);
            }
        }
    } else {
        const int* eis_i[2] = { ei_ii, ei_ji };
        const int* eis_j[2] = { ei_jj, ei_ij };
        run_group_thin<float, false>(srcA0_i, dstA0_i, eis_i, rids_i, FD, Wl0, Wr0, att0, b0,
                                     1, w.z_i, nullptr, nullptr, w, stream);
        run_group_thin<float, false>(srcA0_j, dstA0_j, eis_j, rids_j, FD, Wl0, Wr0, att0, b0,
                                     1, w.z_j, nullptr, nullptr, w, stream);
        run_group_thin<unsigned short, true>(srcA1_i, dstA1_i, eis_i, rids_i, CD, Wl1, Wr1, att1, b1,
                                             2, nullptr, batch_i, w.pool_i, w, stream);
        run_group_thin<unsigned short, true>(srcA1_j, dstA1_j, eis_j, rids_j, CD, Wl1, Wr1, att1, b1,
                                             2, nullptr, batch_j, w.pool_j, w, stream);
    }

    head_kernel<<<BG, 128, 0, stream>>>(w.pool_i, w.pool_j, W_out, b_out,
                                        W_i, b_i, W_j, b_j, out);
}

// Round 3
// 1441.281 us; speedup vs baseline: 1.3521x; 1.0283x over previous
//
#include <hip/hip_runtime.h>

// ---------------- problem constants ----------------
#define NN      20000     // nodes per type
#define EE      320000    // edges per relation
#define ETOT    340000    // EE + NN self loops
#define FD      512       // raw feature dim
#define HH_     4         // heads
#define CD      128       // channels per head
#define HHD     512       // H*C
#define BG      64        // batch graphs
#define INNERD  64

typedef __attribute__((ext_vector_type(8))) short bf16x8;
typedef __attribute__((ext_vector_type(4))) float f32x4;

// ---- bf16 <-> f32 via raw bits ----
__device__ __forceinline__ float bf2f(unsigned v) { return __uint_as_float(v << 16); }
__device__ __forceinline__ unsigned short f2bf(float f) {
    unsigned u = __float_as_uint(f);
    unsigned r = 0x7fffu + ((u >> 16) & 1u);
    return (unsigned short)((u + r) >> 16);
}
__device__ __forceinline__ void load8bf(const unsigned short* p, float* f) {
    uint4 u = *reinterpret_cast<const uint4*>(p);
    f[0] = bf2f(u.x & 0xffffu); f[1] = bf2f(u.x >> 16);
    f[2] = bf2f(u.y & 0xffffu); f[3] = bf2f(u.y >> 16);
    f[4] = bf2f(u.z & 0xffffu); f[5] = bf2f(u.z >> 16);
    f[6] = bf2f(u.w & 0xffffu); f[7] = bf2f(u.w >> 16);
}
// fast split f32 -> hi + lo bf16 (truncation; residual ~2^-16 relative)
__device__ __forceinline__ void split_f32(float x, unsigned short& hi, unsigned short& lo) {
    unsigned u = __float_as_uint(x);
    hi = (unsigned short)(u >> 16);
    float r = x - bf2f(hi);
    lo = (unsigned short)(__float_as_uint(r) >> 16);
}
template <typename TA>
__device__ __forceinline__ void splitA(const TA* p, size_t i, unsigned short& hi, unsigned short& lo);
template <>
__device__ __forceinline__ void splitA<float>(const float* p, size_t i, unsigned short& hi, unsigned short& lo) {
    split_f32(p[i], hi, lo);
}
template <>
__device__ __forceinline__ void splitA<unsigned short>(const unsigned short* p, size_t i, unsigned short& hi, unsigned short& lo) {
    hi = p[i]; lo = 0;
}

// ================= CSR build =================
__global__ __launch_bounds__(256) void csr_hist(const int* __restrict__ ei, int* __restrict__ cnt) {
    int e = blockIdx.x * blockDim.x + threadIdx.x;
    if (e < EE) atomicAdd(&cnt[ei[EE + e]], 1);
}

__global__ __launch_bounds__(1024) void csr_scan(const int* __restrict__ cnt,
                                                 int* __restrict__ rowptr,
                                                 int* __restrict__ cursor) {
    __shared__ int part[1024];
    int t = threadIdx.x;
    int base = t * 20;
    int s = 0;
    #pragma unroll
    for (int i = 0; i < 20; ++i) { int n = base + i; if (n < NN) s += cnt[n] + 1; }
    part[t] = s;
    __syncthreads();
    for (int off = 1; off < 1024; off <<= 1) {
        int v = (t >= off) ? part[t - off] : 0;
        __syncthreads();
        part[t] += v;
        __syncthreads();
    }
    int run = (t > 0) ? part[t - 1] : 0;
    #pragma unroll
    for (int i = 0; i < 20; ++i) {
        int n = base + i;
        if (n < NN) { rowptr[n] = run; cursor[n] = run; run += cnt[n] + 1; }
    }
    if (t == 1023) rowptr[NN] = run;
}

// scatter src ids as uint16 (node ids < 65536); self-loop appended per node
__global__ __launch_bounds__(256) void csr_scatter16(const int* __restrict__ ei,
                                                     int* __restrict__ cursor,
                                                     unsigned short* __restrict__ srcs) {
    int idx = blockIdx.x * blockDim.x + threadIdx.x;
    if (idx >= ETOT) return;
    int src, dst;
    if (idx < EE) { src = ei[idx]; dst = ei[EE + idx]; }
    else          { src = dst = idx - EE; }
    int pos = atomicAdd(&cursor[dst], 1);
    srcs[pos] = (unsigned short)src;
}

// ================= W pre-split: [R][K][512] f32 -> hi/lo [R][512][K] bf16 ============
__global__ __launch_bounds__(256) void wsplit_t(const float* __restrict__ W,
                                                unsigned short* __restrict__ Whi,
                                                unsigned short* __restrict__ Wlo,
                                                int K)
{
    __shared__ float tile[64][65];
    const int nt = 512 / 64;
    const int kt = K / 64;
    int bid = blockIdx.x;
    int in = bid % nt; int ik = (bid / nt) % kt; int r = bid / (nt * kt);
    int t = threadIdx.x;
    const float* Wr_ = W + (size_t)r * K * 512;
    #pragma unroll
    for (int rep = 0; rep < 16; ++rep) {
        int idx = rep * 256 + t;
        int kk = idx >> 6, nn = idx & 63;
        tile[kk][nn] = Wr_[(size_t)(ik * 64 + kk) * 512 + in * 64 + nn];
    }
    __syncthreads();
    #pragma unroll
    for (int rep = 0; rep < 16; ++rep) {
        int idx = rep * 256 + t;
        int nn = idx >> 6, kk = idx & 63;
        unsigned short h, l; split_f32(tile[kk][nn], h, l);
        size_t o = ((size_t)r * 512 + in * 64 + nn) * K + ik * 64 + kk;
        Whi[o] = h; Wlo[o] = l;
    }
}

// ================= 128x128 split-bf16 MFMA GEMM core (shared by z2 / z4) ============
template <typename TA, bool A_EXACT>
__device__ __forceinline__ void gemm_body(
    const TA* __restrict__ A, const unsigned short* __restrict__ Bhg,
    const unsigned short* __restrict__ Blg, unsigned short* __restrict__ C,
    int bx, int by, int M, int K, int N)
{
    __shared__ unsigned short Ah[128][40];
    __shared__ unsigned short Al[A_EXACT ? 1 : 128][40];
    __shared__ unsigned short Bh[128][40];
    __shared__ unsigned short Bl[128][40];

    const int tid = threadIdx.x;
    const int wave = tid >> 6, lane = tid & 63;
    const int quad = lane >> 4, lrow = lane & 15;
    const int wr = (wave >> 1) * 64, wc = (wave & 1) * 64;
    const int tileM = by * 128, tileN = bx * 128;

    const int srow = tid >> 1;
    const int sks  = (tid & 1) * 16;
    const int sgm  = tileM + srow;

    f32x4 acc[4][4] = {};

    for (int k0 = 0; k0 < K; k0 += 32) {
        if constexpr (!A_EXACT) {
            bf16x8 ph[2] = {{}, {}}, pl[2] = {{}, {}};
            if (sgm < M) {
                const float* Ap = (const float*)A + (size_t)sgm * K + k0 + sks;
                #pragma unroll
                for (int s = 0; s < 2; ++s) {
                    float4 f0 = reinterpret_cast<const float4*>(Ap)[2 * s];
                    float4 f1 = reinterpret_cast<const float4*>(Ap)[2 * s + 1];
                    float xv[8] = {f0.x, f0.y, f0.z, f0.w, f1.x, f1.y, f1.z, f1.w};
                    #pragma unroll
                    for (int pp = 0; pp < 4; ++pp) {
                        unsigned u0 = __float_as_uint(xv[2 * pp]);
                        unsigned u1 = __float_as_uint(xv[2 * pp + 1]);
                        reinterpret_cast<unsigned*>(&ph[s])[pp] =
                            __builtin_amdgcn_perm(u1, u0, 0x07060302u);
                        float r0 = xv[2 * pp]     - __uint_as_float(u0 & 0xffff0000u);
                        float r1 = xv[2 * pp + 1] - __uint_as_float(u1 & 0xffff0000u);
                        reinterpret_cast<unsigned*>(&pl[s])[pp] =
                            __builtin_amdgcn_perm(__float_as_uint(r1), __float_as_uint(r0), 0x07060302u);
                    }
                }
            }
            *reinterpret_cast<bf16x8*>(&Ah[srow][sks])     = ph[0];
            *reinterpret_cast<bf16x8*>(&Ah[srow][sks + 8]) = ph[1];
            *reinterpret_cast<bf16x8*>(&Al[srow][sks])     = pl[0];
            *reinterpret_cast<bf16x8*>(&Al[srow][sks + 8]) = pl[1];
        } else {
            bf16x8 v0 = {}, v1 = {};
            if (sgm < M) {
                const unsigned short* Ap = (const unsigned short*)A + (size_t)sgm * K + k0 + sks;
                v0 = reinterpret_cast<const bf16x8*>(Ap)[0];
                v1 = reinterpret_cast<const bf16x8*>(Ap)[1];
            }
            *reinterpret_cast<bf16x8*>(&Ah[srow][sks])     = v0;
            *reinterpret_cast<bf16x8*>(&Ah[srow][sks + 8]) = v1;
        }
        {
            const unsigned short* Bp = Bhg + (size_t)(tileN + srow) * K + k0 + sks;
            const unsigned short* Bq = Blg + (size_t)(tileN + srow) * K + k0 + sks;
            bf16x8 h0 = reinterpret_cast<const bf16x8*>(Bp)[0];
            bf16x8 h1 = reinterpret_cast<const bf16x8*>(Bp)[1];
            bf16x8 l0 = reinterpret_cast<const bf16x8*>(Bq)[0];
            bf16x8 l1 = reinterpret_cast<const bf16x8*>(Bq)[1];
            *reinterpret_cast<bf16x8*>(&Bh[srow][sks])     = h0;
            *reinterpret_cast<bf16x8*>(&Bh[srow][sks + 8]) = h1;
            *reinterpret_cast<bf16x8*>(&Bl[srow][sks])     = l0;
            *reinterpret_cast<bf16x8*>(&Bl[srow][sks + 8]) = l1;
        }
        __syncthreads();
        bf16x8 ah[4], al[4], bh[4], bl[4];
        #pragma unroll
        for (int mi = 0; mi < 4; ++mi) {
            ah[mi] = *reinterpret_cast<const bf16x8*>(&Ah[wr + mi * 16 + lrow][quad * 8]);
            if constexpr (!A_EXACT)
                al[mi] = *reinterpret_cast<const bf16x8*>(&Al[wr + mi * 16 + lrow][quad * 8]);
        }
        #pragma unroll
        for (int ni = 0; ni < 4; ++ni) {
            bh[ni] = *reinterpret_cast<const bf16x8*>(&Bh[wc + ni * 16 + lrow][quad * 8]);
            bl[ni] = *reinterpret_cast<const bf16x8*>(&Bl[wc + ni * 16 + lrow][quad * 8]);
        }
        #pragma unroll
        for (int mi = 0; mi < 4; ++mi)
            #pragma unroll
            for (int ni = 0; ni < 4; ++ni) {
                acc[mi][ni] = __builtin_amdgcn_mfma_f32_16x16x32_bf16(
                    ah[mi], bh[ni], acc[mi][ni], 0, 0, 0);
                acc[mi][ni] = __builtin_amdgcn_mfma_f32_16x16x32_bf16(
                    ah[mi], bl[ni], acc[mi][ni], 0, 0, 0);
                if constexpr (!A_EXACT)
                    acc[mi][ni] = __builtin_amdgcn_mfma_f32_16x16x32_bf16(
                        al[mi], bh[ni], acc[mi][ni], 0, 0, 0);
            }
        __syncthreads();
    }
    #pragma unroll
    for (int mi = 0; mi < 4; ++mi) {
        #pragma unroll
        for (int ni = 0; ni < 4; ++ni) {
            int gcol = tileN + wc + ni * 16 + lrow;
            #pragma unroll
            for (int r = 0; r < 4; ++r) {
                int grow = tileM + wr + mi * 16 + quad * 4 + r;
                if (grow < M)
                    C[(size_t)grow * N + gcol] = f2bf(acc[mi][ni][r]);
            }
        }
    }
}

// z=2 variant (fat_t fallback path)
template <typename TA, bool A_EXACT>
__global__ __launch_bounds__(256, 3) void gemm_mfma_t(
    const TA* __restrict__ A0, const TA* __restrict__ A1,
    const unsigned short* __restrict__ B0h, const unsigned short* __restrict__ B0l,
    const unsigned short* __restrict__ B1h, const unsigned short* __restrict__ B1l,
    unsigned short* __restrict__ C0, unsigned short* __restrict__ C1,
    int M, int K, int N)
{
    const int gx = gridDim.x, gy = gridDim.y;
    const int nwg = gx * gy * (int)gridDim.z;
    int b = ((int)blockIdx.z * gy + blockIdx.y) * gx + blockIdx.x;
    int xcd = b & 7, q8 = nwg >> 3, r8 = nwg & 7;
    int work = (xcd < r8 ? xcd * (q8 + 1) : r8 * (q8 + 1) + (xcd - r8) * q8) + (b >> 3);
    int bx = work % gx; int t2 = work / gx; int by = t2 % gy; int bz = t2 / gy;

    const TA* A = bz ? A1 : A0;
    const unsigned short* Bhg = bz ? B1h : B0h;
    const unsigned short* Blg = bz ? B1l : B0l;
    unsigned short* C = bz ? C1 : C0;
    gemm_body<TA, A_EXACT>(A, Bhg, Blg, C, bx, by, M, K, N);
}

// z=4 variant (merged path: one dispatch covers both relations of a group)
template <typename TA, bool A_EXACT>
__global__ __launch_bounds__(256, 3) void gemm_mfma_t4(
    const TA* __restrict__ A0, const TA* __restrict__ A1,
    const TA* __restrict__ A2, const TA* __restrict__ A3,
    const unsigned short* __restrict__ B0h, const unsigned short* __restrict__ B0l,
    const unsigned short* __restrict__ B1h, const unsigned short* __restrict__ B1l,
    const unsigned short* __restrict__ B2h, const unsigned short* __restrict__ B2l,
    const unsigned short* __restrict__ B3h, const unsigned short* __restrict__ B3l,
    unsigned short* __restrict__ C0, unsigned short* __restrict__ C1,
    unsigned short* __restrict__ C2, unsigned short* __restrict__ C3,
    int M, int K, int N)
{
    const int gx = gridDim.x, gy = gridDim.y;
    const int nwg = gx * gy * (int)gridDim.z;
    int b = ((int)blockIdx.z * gy + blockIdx.y) * gx + blockIdx.x;
    int xcd = b & 7, q8 = nwg >> 3, r8 = nwg & 7;
    int work = (xcd < r8 ? xcd * (q8 + 1) : r8 * (q8 + 1) + (xcd - r8) * q8) + (b >> 3);
    int bx = work % gx; int t2 = work / gx; int by = t2 % gy; int bz = t2 / gy;

    // explicit select chains (no runtime-indexed pointer array -> no scratch)
    const TA* A = bz == 0 ? A0 : bz == 1 ? A1 : bz == 2 ? A2 : A3;
    const unsigned short* Bhg = bz == 0 ? B0h : bz == 1 ? B1h : bz == 2 ? B2h : B3h;
    const unsigned short* Blg = bz == 0 ? B0l : bz == 1 ? B1l : bz == 2 ? B2l : B3l;
    unsigned short* C = bz == 0 ? C0 : bz == 1 ? C1 : bz == 2 ? C2 : C3;
    gemm_body<TA, A_EXACT>(A, Bhg, Blg, C, bx, by, M, K, N);
}

// ================= OLD 64x64 split-bf16 GEMM (deep fallback) =================
template <typename TA, bool A_EXACT>
__global__ __launch_bounds__(256) void gemm_mfma(
    const TA* __restrict__ A0, const TA* __restrict__ A1,
    const float* __restrict__ B0, const float* __restrict__ B1, int ldb,
    unsigned short* __restrict__ C0, unsigned short* __restrict__ C1,
    int M, int K, int N)
{
    const TA* A = blockIdx.z ? A1 : A0;
    const float* B = blockIdx.z ? B1 : B0;
    unsigned short* C = blockIdx.z ? C1 : C0;

    __shared__ unsigned short Ah[64][40];
    __shared__ unsigned short Al[64][40];
    __shared__ unsigned short Bh[64][40];
    __shared__ unsigned short Bl[64][40];
    const int tid = threadIdx.x;
    const int wave = tid >> 6, lane = tid & 63;
    const int quad = lane >> 4, lrow = lane & 15;
    const int tileM = blockIdx.y * 64, tileN = blockIdx.x * 64;
    const int wm = (wave >> 1) * 32, wn = (wave & 1) * 32;

    f32x4 acc[2][2] = {};

    const int am = tid >> 2;
    const int aks = (tid & 3) * 8;
    const int bn = tid & 63;
    const int bk0 = (tid >> 6) * 8;

    for (int k0 = 0; k0 < K; k0 += 32) {
        {
            int gm = tileM + am;
            bf16x8 ph = {}, pl = {};
            if (gm < M) {
                #pragma unroll
                for (int j = 0; j < 8; ++j) {
                    unsigned short h, l;
                    splitA(A, (size_t)gm * K + k0 + aks + j, h, l);
                    ph[j] = (short)h; pl[j] = (short)l;
                }
            }
            *reinterpret_cast<bf16x8*>(&Ah[am][aks]) = ph;
            if (!A_EXACT) *reinterpret_cast<bf16x8*>(&Al[am][aks]) = pl;
        }
        {
            bf16x8 ph, pl;
            #pragma unroll
            for (int j = 0; j < 8; ++j) {
                unsigned short h, l;
                split_f32(B[(size_t)(k0 + bk0 + j) * ldb + tileN + bn], h, l);
                ph[j] = (short)h; pl[j] = (short)l;
            }
            *reinterpret_cast<bf16x8*>(&Bh[bn][bk0]) = ph;
            *reinterpret_cast<bf16x8*>(&Bl[bn][bk0]) = pl;
        }
        __syncthreads();
        bf16x8 ah[2], al[2], bh[2], bl[2];
        #pragma unroll
        for (int mi = 0; mi < 2; ++mi) {
            ah[mi] = *reinterpret_cast<const bf16x8*>(&Ah[wm + mi * 16 + lrow][quad * 8]);
            if (!A_EXACT)
                al[mi] = *reinterpret_cast<const bf16x8*>(&Al[wm + mi * 16 + lrow][quad * 8]);
        }
        #pragma unroll
        for (int ni = 0; ni < 2; ++ni) {
            bh[ni] = *reinterpret_cast<const bf16x8*>(&Bh[wn + ni * 16 + lrow][quad * 8]);
            bl[ni] = *reinterpret_cast<const bf16x8*>(&Bl[wn + ni * 16 + lrow][quad * 8]);
        }
        #pragma unroll
        for (int mi = 0; mi < 2; ++mi)
            #pragma unroll
            for (int ni = 0; ni < 2; ++ni) {
                acc[mi][ni] = __builtin_amdgcn_mfma_f32_16x16x32_bf16(
                    ah[mi], bh[ni], acc[mi][ni], 0, 0, 0);
                acc[mi][ni] = __builtin_amdgcn_mfma_f32_16x16x32_bf16(
                    ah[mi], bl[ni], acc[mi][ni], 0, 0, 0);
                if (!A_EXACT)
                    acc[mi][ni] = __builtin_amdgcn_mfma_f32_16x16x32_bf16(
                        al[mi], bh[ni], acc[mi][ni], 0, 0, 0);
            }
        __syncthreads();
    }
    #pragma unroll
    for (int mi = 0; mi < 2; ++mi) {
        #pragma unroll
        for (int ni = 0; ni < 2; ++ni) {
            int gcol = tileN + wn + ni * 16 + lrow;
            #pragma unroll
            for (int r = 0; r < 4; ++r) {
                int grow = tileM + wm + mi * 16 + quad * 4 + r;
                if (grow < M)
                    C[(size_t)grow * N + gcol] = f2bf(acc[mi][ni][r]);
            }
        }
    }
}

// ================= THIN: fused GATv2 pass, one head (deep fallback) =================
__global__ __launch_bounds__(256) void fused_aggr1(
    const int* __restrict__ rowptr, const unsigned short* __restrict__ srcs,
    const unsigned short* __restrict__ xl, const unsigned short* __restrict__ xr,
    const float* __restrict__ att,
    float* __restrict__ acc, int add_in, int fin_mode,
    const float* __restrict__ bA, const float* __restrict__ bB,
    unsigned short* __restrict__ z,
    const int* __restrict__ batch, float* __restrict__ pool)
{
    int dst = (int)((blockIdx.x * (size_t)blockDim.x + threadIdx.x) >> 6);
    int lane = threadIdx.x & 63;
    if (dst >= NN) return;
    int beg = rowptr[dst], end = rowptr[dst + 1];

    unsigned ub = *reinterpret_cast<const unsigned*>(xr + (size_t)dst * CD + lane * 2);
    float br0 = bf2f(ub & 0xffffu), br1 = bf2f(ub >> 16);
    float ta0 = att[lane * 2], ta1 = att[lane * 2 + 1];

    float n0 = 0.f, n1 = 0.f, den = 0.f;
    for (int k = beg; k < end; ++k) {
        int src = srcs[k];
        unsigned ua = *reinterpret_cast<const unsigned*>(xl + (size_t)src * CD + lane * 2);
        float a0 = bf2f(ua & 0xffffu), a1 = bf2f(ua >> 16);
        float v0 = a0 + br0, v1 = a1 + br1;
        v0 = (v0 > 0.f) ? v0 : 0.2f * v0;
        v1 = (v1 > 0.f) ? v1 : 0.2f * v1;
        float d = v0 * ta0 + v1 * ta1;
        #pragma unroll
        for (int off = 1; off < 64; off <<= 1)
            d += __shfl_xor(d, off);
        float p = expf(d);
        n0 += p * a0; n1 += p * a1; den += p;
    }
    float o0 = n0 / den, o1 = n1 / den;
    size_t ai = (size_t)dst * CD + lane * 2;
    if (add_in) { o0 += acc[ai]; o1 += acc[ai + 1]; }
    if (fin_mode == 0) {
        acc[ai] = o0; acc[ai + 1] = o1;
    } else {
        int c0 = lane * 2;
        float bb0 = 0.f, bb1 = 0.f;
        #pragma unroll
        for (int h = 0; h < HH_; ++h) {
            bb0 += bA[h * CD + c0]     + bB[h * CD + c0];
            bb1 += bA[h * CD + c0 + 1] + bB[h * CD + c0 + 1];
        }
        o0 = tanhf(o0 + bb0);
        o1 = tanhf(o1 + bb1);
        if (fin_mode == 1) {
            z[ai] = f2bf(o0); z[ai + 1] = f2bf(o1);
        } else {
            int b = batch[dst];
            atomicAdd(&pool[(size_t)b * CD + c0],     o0);
            atomicAdd(&pool[(size_t)b * CD + c0 + 1], o1);
        }
    }
}

// ================= GATv2 relation pass: 2x-unrolled edge loop =================
// one 64-lane wave, all 4 heads; lane holds 8 channels. Edge gathers are the
// latency bottleneck (random 1KB rows from L3) — pair loads issue back-to-back
// to halve exposed latency. Summation order is IDENTICAL to the serial loop.
__device__ __forceinline__ void gat_rel(
    const int* __restrict__ rp, const unsigned short* __restrict__ sr,
    const unsigned short* __restrict__ xl, const unsigned short* __restrict__ xr,
    const float* __restrict__ att, int dst, int lane, float* o)
{
    int beg = rp[dst], end = rp[dst + 1];
    float br[8], ta[8];
    load8bf(xr + (size_t)dst * HHD + lane * 8, br);
    #pragma unroll
    for (int j = 0; j < 8; ++j) ta[j] = att[lane * 8 + j];

    float n[8] = {}; float den = 0.f;
    int k = beg;
    for (; k + 2 <= end; k += 2) {
        int s0 = sr[k], s1 = sr[k + 1];
        float a0[8], a1[8];
        load8bf(xl + (size_t)s0 * HHD + lane * 8, a0);
        load8bf(xl + (size_t)s1 * HHD + lane * 8, a1);
        float d0 = 0.f, d1 = 0.f;
        #pragma unroll
        for (int j = 0; j < 8; ++j) {
            float v0 = a0[j] + br[j];
            v0 = (v0 > 0.f) ? v0 : 0.2f * v0;
            d0 += v0 * ta[j];
            float v1 = a1[j] + br[j];
            v1 = (v1 > 0.f) ? v1 : 0.2f * v1;
            d1 += v1 * ta[j];
        }
        d0 += __shfl_xor(d0, 1);  d1 += __shfl_xor(d1, 1);
        d0 += __shfl_xor(d0, 2);  d1 += __shfl_xor(d1, 2);
        d0 += __shfl_xor(d0, 4);  d1 += __shfl_xor(d1, 4);
        d0 += __shfl_xor(d0, 8);  d1 += __shfl_xor(d1, 8);
        float p0 = expf(d0), p1 = expf(d1);
        den += p0;
        #pragma unroll
        for (int j = 0; j < 8; ++j) n[j] += p0 * a0[j];
        den += p1;
        #pragma unroll
        for (int j = 0; j < 8; ++j) n[j] += p1 * a1[j];
    }
    if (k < end) {
        int s0 = sr[k];
        float a0[8];
        load8bf(xl + (size_t)s0 * HHD + lane * 8, a0);
        float d0 = 0.f;
        #pragma unroll
        for (int j = 0; j < 8; ++j) {
            float v0 = a0[j] + br[j];
            v0 = (v0 > 0.f) ? v0 : 0.2f * v0;
            d0 += v0 * ta[j];
        }
        d0 += __shfl_xor(d0, 1);
        d0 += __shfl_xor(d0, 2);
        d0 += __shfl_xor(d0, 4);
        d0 += __shfl_xor(d0, 8);
        float p0 = expf(d0);
        den += p0;
        #pragma unroll
        for (int j = 0; j < 8; ++j) n[j] += p0 * a0[j];
    }
    float inv = 1.f / den;
    #pragma unroll
    for (int j = 0; j < 8; ++j) {
        o[j] = n[j] * inv;
        o[j] += __shfl_xor(o[j], 16);   // head-sum (once per dst)
        o[j] += __shfl_xor(o[j], 32);
    }
}

// ================= FAT: single-relation pass (fat_t fallback; now unrolled) =========
__global__ __launch_bounds__(256) void fused_aggr4(
    const int* __restrict__ rowptr, const unsigned short* __restrict__ srcs,
    const unsigned short* __restrict__ xl, const unsigned short* __restrict__ xr,
    const float* __restrict__ att,
    float* __restrict__ acc, int add_in, int fin_mode,
    const float* __restrict__ bA, const float* __restrict__ bB,
    unsigned short* __restrict__ z,
    const int* __restrict__ batch, float* __restrict__ pool)
{
    int dst = (int)((blockIdx.x * (size_t)blockDim.x + threadIdx.x) >> 6);
    int lane = threadIdx.x & 63;
    if (dst >= NN) return;

    float o[8];
    gat_rel(rowptr, srcs, xl, xr, att, dst, lane, o);

    if (lane < 16) {
        size_t ai = (size_t)dst * CD + lane * 8;
        if (add_in) {
            #pragma unroll
            for (int j = 0; j < 8; ++j) o[j] += acc[ai + j];
        }
        if (fin_mode == 0) {
            #pragma unroll
            for (int j = 0; j < 8; ++j) acc[ai + j] = o[j];
        } else {
            int c0 = lane * 8;
            #pragma unroll
            for (int j = 0; j < 8; ++j) {
                float bb = 0.f;
                #pragma unroll
                for (int h = 0; h < HH_; ++h)
                    bb += bA[h * CD + c0 + j] + bB[h * CD + c0 + j];
                o[j] = tanhf(o[j] + bb);
            }
            if (fin_mode == 1) {
                #pragma unroll
                for (int j = 0; j < 8; ++j) z[ai + j] = f2bf(o[j]);
            } else {
                #pragma unroll
                for (int j = 0; j < 8; ++j) acc[ai + j] = o[j];
            }
        }
    }
}

// ================= FAT merged: BOTH relations of a group in one dispatch ============
// o = o_rel1 + o_rel0 (same order as the old acc round-trip). fin_mode 1: z out;
// fin_mode 2: finalized f32 -> acc, reduced by pool_reduce.
__global__ __launch_bounds__(256) void fused_aggr4d(
    const int* __restrict__ rp0, const unsigned short* __restrict__ sr0,
    const unsigned short* __restrict__ xl0, const unsigned short* __restrict__ xr0,
    const float* __restrict__ attA,
    const int* __restrict__ rp1, const unsigned short* __restrict__ sr1,
    const unsigned short* __restrict__ xl1, const unsigned short* __restrict__ xr1,
    const float* __restrict__ attB,
    float* __restrict__ acc, int fin_mode,
    const float* __restrict__ bA, const float* __restrict__ bB,
    unsigned short* __restrict__ z,
    const int* __restrict__ batch, float* __restrict__ pool)
{
    int dst = (int)((blockIdx.x * (size_t)blockDim.x + threadIdx.x) >> 6);
    int lane = threadIdx.x & 63;
    if (dst >= NN) return;

    float o0[8], o1[8];
    gat_rel(rp0, sr0, xl0, xr0, attA, dst, lane, o0);
    gat_rel(rp1, sr1, xl1, xr1, attB, dst, lane, o1);
    #pragma unroll
    for (int j = 0; j < 8; ++j) o1[j] += o0[j];

    if (lane < 16) {
        size_t ai = (size_t)dst * CD + lane * 8;
        int c0 = lane * 8;
        #pragma unroll
        for (int j = 0; j < 8; ++j) {
            float bb = 0.f;
            #pragma unroll
            for (int h = 0; h < HH_; ++h)
                bb += bA[h * CD + c0 + j] + bB[h * CD + c0 + j];
            o1[j] = tanhf(o1[j] + bb);
        }
        if (fin_mode == 1) {
            #pragma unroll
            for (int j = 0; j < 8; ++j) z[ai + j] = f2bf(o1[j]);
        } else {
            #pragma unroll
            for (int j = 0; j < 8; ++j) acc[ai + j] = o1[j];
        }
    }
}

// ================= pool_reduce: segmented sum over sorted batch (no atomics) ========
__global__ __launch_bounds__(512) void pool_reduce(
    const float* __restrict__ acc, const int* __restrict__ batch,
    float* __restrict__ pool)
{
    int b = blockIdx.x;
    int t = threadIdx.x & (CD - 1);
    int q = threadIdx.x >> 7;
    int lo, hi;
    { int l = 0, r = NN; while (l < r) { int m = (l + r) >> 1; if (batch[m] < b) l = m + 1; else r = m; } lo = l; }
    { int l = lo, r = NN; while (l < r) { int m = (l + r) >> 1; if (batch[m] <= b) l = m + 1; else r = m; } hi = l; }
    float s = 0.f;
    for (int nrow = lo + q; nrow < hi; nrow += 4)
        s += acc[(size_t)nrow * CD + t];
    __shared__ float red[4][CD];
    red[q][t] = s;
    __syncthreads();
    if (q == 0)
        pool[(size_t)b * CD + t] = red[0][t] + red[1][t] + red[2][t] + red[3][t];
}

// ================= head =================
__global__ __launch_bounds__(128) void head_kernel(
    const float* __restrict__ pool_i, const float* __restrict__ pool_j,
    const float* __restrict__ W_out, const float* __restrict__ b_out,
    const float* __restrict__ W_i, const float* __restrict__ b_i,
    const float* __restrict__ W_j, const float* __restrict__ b_j,
    float* __restrict__ out)
{
    int b = blockIdx.x;
    int t = threadIdx.x;
    __shared__ float pi[CD], pj[CD];
    pi[t] = tanhf(pool_i[(size_t)b * CD + t]);
    pj[t] = tanhf(pool_j[(size_t)b * CD + t]);
    __syncthreads();
    if (t < INNERD) {
        float a = b_i[t];
        for (int c = 0; c < CD; ++c) a += pi[c] * W_i[c * INNERD + t];
        out[BG + (size_t)b * INNERD + t] = a;
    } else {
        int k = t - INNERD;
        float a = b_j[k];
        for (int c = 0; c < CD; ++c) a += pj[c] * W_j[c * INNERD + k];
        out[BG + BG * INNERD + (size_t)b * INNERD + k] = a;
    }
    if (t == 0) {
        float a = b_out[0];
        for (int c = 0; c < CD; ++c) a += (pi[c] + pj[c]) * W_out[c];
        out[b] = 1.f / (1.f + expf(-a));
    }
}

// ================= host-side drivers =================
struct Ws {
    unsigned short *xl, *xr, *xl2, *xr2, *z_i, *z_j;
    float* acc;
    int *rowptr[4];
    unsigned short *srcs[4];
    int *cnt, *cursor;
    float *pool_i, *pool_j;
    unsigned short *wt0l_h, *wt0l_l, *wt0r_h, *wt0r_l;
    unsigned short *wt1l_h, *wt1l_l, *wt1r_h, *wt1r_l;
};

static void build_csr(const int* ei, int* rowptr, unsigned short* srcs,
                      int* cnt, int* cursor, hipStream_t stream) {
    hipMemsetAsync(cnt, 0, NN * sizeof(int), stream);
    csr_hist<<<(EE + 255) / 256, 256, 0, stream>>>(ei, cnt);
    csr_scan<<<1, 1024, 0, stream>>>(cnt, rowptr, cursor);
    csr_scatter16<<<(ETOT + 255) / 256, 256, 0, stream>>>(ei, cursor, srcs);
}

// ---- MERGED group pass: z=4 GEMM then one dual-relation aggr ----
template <typename TA, bool A_EXACT>
static void run_group_fat_m(const TA* srcA[2], const TA* dstA[2],
                            const int* rp[2], const unsigned short* sr[2],
                            const int rids[2], int K,
                            const unsigned short* WTl_h, const unsigned short* WTl_l,
                            const unsigned short* WTr_h, const unsigned short* WTr_l,
                            const float* att, const float* bias, int fin_mode,
                            unsigned short* zout, const int* batch, float* pool,
                            const Ws& w, hipStream_t stream)
{
    dim3 gg(HHD / 128, (NN + 127) / 128, 4);
    size_t off0 = (size_t)rids[0] * HHD * K;
    size_t off1 = (size_t)rids[1] * HHD * K;
    gemm_mfma_t4<TA, A_EXACT><<<gg, 256, 0, stream>>>(
        srcA[0], dstA[0], srcA[1], dstA[1],
        WTl_h + off0, WTl_l + off0, WTr_h + off0, WTr_l + off0,
        WTl_h + off1, WTl_l + off1, WTr_h + off1, WTr_l + off1,
        w.xl, w.xr, w.xl2, w.xr2, NN, K, HHD);
    fused_aggr4d<<<NN / 4, 256, 0, stream>>>(
        rp[0], sr[0], w.xl, w.xr, att + (size_t)rids[0] * HHD,
        rp[1], sr[1], w.xl2, w.xr2, att + (size_t)rids[1] * HHD,
        w.acc, fin_mode,
        bias + (size_t)rids[0] * HHD, bias + (size_t)rids[1] * HHD,
        zout, batch, pool);
}

// ---- fat_t group pass (fallback, z=2 GEMM + 2 aggr) ----
template <typename TA, bool A_EXACT>
static void run_group_fat_t(const TA* srcA[2], const TA* dstA[2],
                            const int* rp[2], const unsigned short* sr[2],
                            const int rids[2], int K,
                            const unsigned short* WTl_h, const unsigned short* WTl_l,
                            const unsigned short* WTr_h, const unsigned short* WTr_l,
                            const float* att, const float* bias, int fin_mode,
                            unsigned short* zout, const int* batch, float* pool,
                            const Ws& w, hipStream_t stream)
{
    dim3 gg(HHD / 128, (NN + 127) / 128, 2);
    const int ablocks = NN / 4;
    for (int q = 0; q < 2; ++q) {
        int r = rids[q];
        size_t off = (size_t)r * HHD * K;
        gemm_mfma_t<TA, A_EXACT><<<gg, 256, 0, stream>>>(
            srcA[q], dstA[q],
            WTl_h + off, WTl_l + off, WTr_h + off, WTr_l + off,
            w.xl, w.xr, NN, K, HHD);
        int fm = (q == 1) ? fin_mode : 0;
        fused_aggr4<<<ablocks, 256, 0, stream>>>(
            rp[q], sr[q], w.xl, w.xr,
            att + (size_t)r * HHD,
            w.acc, q > 0 ? 1 : 0, fm,
            bias + (size_t)rids[0] * HHD, bias + (size_t)rids[1] * HHD,
            zout, batch, pool);
    }
}

// ---- OLD FAT group pass (fallback) ----
template <typename TA, bool A_EXACT>
static void run_group_fat(const TA* srcA[2], const TA* dstA[2],
                          const int* rp[2], const unsigned short* sr[2],
                          const int rids[2], int K,
                          const float* Wl, const float* Wr, const float* att,
                          const float* bias, int fin_mode,
                          unsigned short* zout, const int* batch, float* pool,
                          const Ws& w, hipStream_t stream)
{
    dim3 gg(HHD / 64, (NN + 63) / 64, 2);
    const int ablocks = NN / 4;
    for (int q = 0; q < 2; ++q) {
        int r = rids[q];
        gemm_mfma<TA, A_EXACT><<<gg, 256, 0, stream>>>(
            srcA[q], dstA[q],
            Wl + (size_t)r * K * HHD, Wr + (size_t)r * K * HHD, HHD,
            w.xl, w.xr, NN, K, HHD);
        int fm = (q == 1) ? fin_mode : 0;
        fused_aggr4<<<ablocks, 256, 0, stream>>>(
            rp[q], sr[q], w.xl, w.xr,
            att + (size_t)r * HHD,
            w.acc, q > 0 ? 1 : 0, fm,
            bias + (size_t)rids[0] * HHD, bias + (size_t)rids[1] * HHD,
            zout, batch, pool);
    }
}

// ---- THIN group pass (deep fallback) ----
template <typename TA, bool A_EXACT>
static void run_group_thin(const TA* srcA[2], const TA* dstA[2],
                           const int* eis[2], const int rids[2], int K,
                           const float* Wl, const float* Wr, const float* att,
                           const float* bias, int fin_mode,
                           unsigned short* zout, const int* batch, float* pool,
                           const Ws& w, hipStream_t stream)
{
    dim3 gg(2, (NN + 63) / 64, 2);
    const int ablocks = NN / 4;
    for (int q = 0; q < 2; ++q) {
        int r = rids[q];
        build_csr(eis[q], w.rowptr[0], w.srcs[0], w.cnt, w.cursor, stream);
        for (int h = 0; h < HH_; ++h) {
            const float* WlS = Wl + (size_t)r * K * HHD + h * CD;
            const float* WrS = Wr + (size_t)r * K * HHD + h * CD;
            gemm_mfma<TA, A_EXACT><<<gg, 256, 0, stream>>>(
                srcA[q], dstA[q], WlS, WrS, HHD, w.xl, w.xr, NN, K, CD);
            int pass = q * HH_ + h;
            int fm = (pass == 2 * HH_ - 1) ? fin_mode : 0;
            fused_aggr1<<<ablocks, 256, 0, stream>>>(
                w.rowptr[0], w.srcs[0], w.xl, w.xr,
                att + (size_t)r * HHD + h * CD,
                w.acc, pass > 0 ? 1 : 0, fm,
                bias + (size_t)rids[0] * HHD, bias + (size_t)rids[1] * HHD,
                zout, batch, pool);
        }
    }
}

extern "C" void kernel_launch(void* const* d_in, const int* in_sizes, int n_in,
                              void* d_out, int out_size, void* d_ws, size_t ws_size,
                              hipStream_t stream)
{
    const float* x_i   = (const float*)d_in[0];
    const float* x_j   = (const float*)d_in[1];
    const int* ei_ii   = (const int*)d_in[2];
    const int* ei_jj   = (const int*)d_in[3];
    const int* ei_ij   = (const int*)d_in[4];
    const int* ei_ji   = (const int*)d_in[5];
    const int* batch_i = (const int*)d_in[6];
    const int* batch_j = (const int*)d_in[7];
    const float* Wl0   = (const float*)d_in[8];
    const float* Wr0   = (const float*)d_in[9];
    const float* att0  = (const float*)d_in[10];
    const float* b0    = (const float*)d_in[11];
    const float* Wl1   = (const float*)d_in[12];
    const float* Wr1   = (const float*)d_in[13];
    const float* att1  = (const float*)d_in[14];
    const float* b1    = (const float*)d_in[15];
    const float* W_out = (const float*)d_in[16];
    const float* b_out = (const float*)d_in[17];
    const float* W_i   = (const float*)d_in[18];
    const float* b_i   = (const float*)d_in[19];
    const float* W_j   = (const float*)d_in[20];
    const float* b_j   = (const float*)d_in[21];
    float* out = (float*)d_out;

    const size_t FAT2_BYTES = (size_t)NN * HHD * 2 * 2 + (size_t)NN * CD * 4
                            + (size_t)NN * CD * 2 * 2 + 4 * (size_t)ETOT * 2
                            + 4 * (size_t)(NN + 4) * 4 + (size_t)NN * 4 * 2
                            + (size_t)BG * CD * 4 * 2;
    const size_t FAT1_BYTES = (size_t)NN * HHD * 2 * 2 + (size_t)NN * CD * 4
                            + (size_t)NN * CD * 2 * 2 + (size_t)ETOT * 2
                            + (size_t)(NN + 4) * 4 + (size_t)NN * 4 * 2
                            + (size_t)BG * CD * 4 * 2;
    const size_t WT0_ONE = (size_t)4 * 512 * 512 * 2;
    const size_t WT1_ONE = (size_t)4 * 512 * 128 * 2;
    const size_t WT_BYTES = 4 * WT0_ONE + 4 * WT1_ONE;
    const size_t X2_BYTES = 2 * (size_t)NN * HHD * 2;   // second xl/xr pair (merged)

    const int ncsr = (ws_size >= FAT2_BYTES) ? 4 : 1;
    const bool fat = (ws_size >= FAT1_BYTES);
    const bool fat_t = (ws_size >= FAT2_BYTES + WT_BYTES);
    const bool fat_m = (ws_size >= FAT2_BYTES + WT_BYTES + X2_BYTES);   // merged path

    Ws w;
    char* p = (char*)d_ws;
    size_t xbytes = fat ? (size_t)NN * HHD * 2 : (size_t)NN * CD * 2;
    w.xl     = (unsigned short*)p; p += xbytes;
    w.xr     = (unsigned short*)p; p += xbytes;
    w.acc    = (float*)p;          p += (size_t)NN * CD * 4;
    w.z_i    = (unsigned short*)p; p += (size_t)NN * CD * 2;
    w.z_j    = (unsigned short*)p; p += (size_t)NN * CD * 2;
    for (int r = 0; r < 4; ++r) {
        int rr = (r < ncsr) ? r : 0;
        if (r < ncsr) {
            w.rowptr[r] = (int*)p;            p += (size_t)(NN + 4) * 4;
            w.srcs[r]   = (unsigned short*)p; p += (size_t)ETOT * 2;
        } else {
            w.rowptr[r] = w.rowptr[rr]; w.srcs[r] = w.srcs[rr];
        }
    }
    w.cnt    = (int*)p;            p += (size_t)NN * 4;
    w.cursor = (int*)p;            p += (size_t)NN * 4;
    w.pool_i = (float*)p;          p += (size_t)BG * CD * 4;
    w.pool_j = (float*)p;          p += (size_t)BG * CD * 4;
    if (fat_t) {
        w.wt0l_h = (unsigned short*)p; p += WT0_ONE;
        w.wt0l_l = (unsigned short*)p; p += WT0_ONE;
        w.wt0r_h = (unsigned short*)p; p += WT0_ONE;
        w.wt0r_l = (unsigned short*)p; p += WT0_ONE;
        w.wt1l_h = (unsigned short*)p; p += WT1_ONE;
        w.wt1l_l = (unsigned short*)p; p += WT1_ONE;
        w.wt1r_h = (unsigned short*)p; p += WT1_ONE;
        w.wt1r_l = (unsigned short*)p; p += WT1_ONE;
    }
    if (fat_m) {
        w.xl2 = (unsigned short*)p; p += (size_t)NN * HHD * 2;
        w.xr2 = (unsigned short*)p; p += (size_t)NN * HHD * 2;
    }

    hipMemsetAsync(w.pool_i, 0, (size_t)BG * CD * sizeof(float), stream);
    hipMemsetAsync(w.pool_j, 0, (size_t)BG * CD * sizeof(float), stream);

    const int* eis_all[4] = { ei_ii, ei_jj, ei_ij, ei_ji };
    const float* srcA0_i[2] = { x_i, x_j };  const float* dstA0_i[2] = { x_i, x_i };
    const float* srcA0_j[2] = { x_j, x_i };  const float* dstA0_j[2] = { x_j, x_j };
    const int rids_i[2] = { 0, 3 };
    const int rids_j[2] = { 1, 2 };
    const unsigned short* srcA1_i[2] = { w.z_i, w.z_j };
    const unsigned short* dstA1_i[2] = { w.z_i, w.z_i };
    const unsigned short* srcA1_j[2] = { w.z_j, w.z_i };
    const unsigned short* dstA1_j[2] = { w.z_j, w.z_j };

    if (fat_t) {
        // build all 4 CSRs once; pre-split+transpose all weights once
        for (int r = 0; r < 4; ++r)
            build_csr(eis_all[r], w.rowptr[r], w.srcs[r], w.cnt, w.cursor, stream);
        wsplit_t<<<4 * (FD / 64) * 8, 256, 0, stream>>>(Wl0, w.wt0l_h, w.wt0l_l, FD);
        wsplit_t<<<4 * (FD / 64) * 8, 256, 0, stream>>>(Wr0, w.wt0r_h, w.wt0r_l, FD);
        wsplit_t<<<4 * (CD / 64) * 8, 256, 0, stream>>>(Wl1, w.wt1l_h, w.wt1l_l, CD);
        wsplit_t<<<4 * (CD / 64) * 8, 256, 0, stream>>>(Wr1, w.wt1r_h, w.wt1r_l, CD);

        const int* rp_i[2] = { w.rowptr[0], w.rowptr[3] };
        const unsigned short* sr_i[2] = { w.srcs[0], w.srcs[3] };
        const int* rp_j[2] = { w.rowptr[1], w.rowptr[2] };
        const unsigned short* sr_j[2] = { w.srcs[1], w.srcs[2] };

        if (fat_m) {
            run_group_fat_m<float, false>(srcA0_i, dstA0_i, rp_i, sr_i, rids_i, FD,
                                          w.wt0l_h, w.wt0l_l, w.wt0r_h, w.wt0r_l,
                                          att0, b0, 1, w.z_i, nullptr, nullptr, w, stream);
            run_group_fat_m<float, false>(srcA0_j, dstA0_j, rp_j, sr_j, rids_j, FD,
                                          w.wt0l_h, w.wt0l_l, w.wt0r_h, w.wt0r_l,
                                          att0, b0, 1, w.z_j, nullptr, nullptr, w, stream);
            run_group_fat_m<unsigned short, true>(srcA1_i, dstA1_i, rp_i, sr_i, rids_i, CD,
                                                  w.wt1l_h, w.wt1l_l, w.wt1r_h, w.wt1r_l,
                                                  att1, b1, 2, nullptr, batch_i, w.pool_i, w, stream);
            pool_reduce<<<BG, 512, 0, stream>>>(w.acc, batch_i, w.pool_i);
            run_group_fat_m<unsigned short, true>(srcA1_j, dstA1_j, rp_j, sr_j, rids_j, CD,
                                                  w.wt1l_h, w.wt1l_l, w.wt1r_h, w.wt1r_l,
                                                  att1, b1, 2, nullptr, batch_j, w.pool_j, w, stream);
            pool_reduce<<<BG, 512, 0, stream>>>(w.acc, batch_j, w.pool_j);
        } else {
            run_group_fat_t<float, false>(srcA0_i, dstA0_i, rp_i, sr_i, rids_i, FD,
                                          w.wt0l_h, w.wt0l_l, w.wt0r_h, w.wt0r_l,
                                          att0, b0, 1, w.z_i, nullptr, nullptr, w, stream);
            run_group_fat_t<float, false>(srcA0_j, dstA0_j, rp_j, sr_j, rids_j, FD,
                                          w.wt0l_h, w.wt0l_l, w.wt0r_h, w.wt0r_l,
                                          att0, b0, 1, w.z_j, nullptr, nullptr, w, stream);
            run_group_fat_t<unsigned short, true>(srcA1_i, dstA1_i, rp_i, sr_i, rids_i, CD,
                                                  w.wt1l_h, w.wt1l_l, w.wt1r_h, w.wt1r_l,
                                                  att1, b1, 2, nullptr, batch_i, w.pool_i, w, stream);
            pool_reduce<<<BG, 512, 0, stream>>>(w.acc, batch_i, w.pool_i);
            run_group_fat_t<unsigned short, true>(srcA1_j, dstA1_j, rp_j, sr_j, rids_j, CD,
                                                  w.wt1l_h, w.wt1l_l, w.wt1r_h, w.wt1r_l,
                                                  att1, b1, 2, nullptr, batch_j, w.pool_j, w, stream);
            pool_reduce<<<BG, 512, 0, stream>>>(w.acc, batch_j, w.pool_j);
        }
    } else if (fat) {
        if (ncsr == 4) {
            for (int r = 0; r < 4; ++r)
                build_csr(eis_all[r], w.rowptr[r], w.srcs[r], w.cnt, w.cursor, stream);
            const int* rp_i[2] = { w.rowptr[0], w.rowptr[3] };
            const unsigned short* sr_i[2] = { w.srcs[0], w.srcs[3] };
            const int* rp_j[2] = { w.rowptr[1], w.rowptr[2] };
            const unsigned short* sr_j[2] = { w.srcs[1], w.srcs[2] };
            run_group_fat<float, false>(srcA0_i, dstA0_i, rp_i, sr_i, rids_i, FD,
                                        Wl0, Wr0, att0, b0, 1, w.z_i, nullptr, nullptr, w, stream);
            run_group_fat<float, false>(srcA0_j, dstA0_j, rp_j, sr_j, rids_j, FD,
                                        Wl0, Wr0, att0, b0, 1, w.z_j, nullptr, nullptr, w, stream);
            run_group_fat<unsigned short, true>(srcA1_i, dstA1_i, rp_i, sr_i, rids_i, CD,
                                                Wl1, Wr1, att1, b1, 2, nullptr, batch_i, w.pool_i, w, stream);
            pool_reduce<<<BG, 512, 0, stream>>>(w.acc, batch_i, w.pool_i);
            run_group_fat<unsigned short, true>(srcA1_j, dstA1_j, rp_j, sr_j, rids_j, CD,
                                                Wl1, Wr1, att1, b1, 2, nullptr, batch_j, w.pool_j, w, stream);
            pool_reduce<<<BG, 512, 0, stream>>>(w.acc, batch_j, w.pool_j);
        } else {
            for (int pass = 0; pass < 4; ++pass) {
                const int* rids = (pass & 1) ? rids_j : rids_i;
                for (int q = 0; q < 2; ++q) {
                    int r = rids[q];
                    build_csr(eis_all[r], w.rowptr[0], w.srcs[0], w.cnt, w.cursor, stream);
                    dim3 gg(HHD / 64, (NN + 63) / 64, 2);
                    if (pass < 2) {
                        const float* sa = (pass == 0) ? srcA0_i[q] : srcA0_j[q];
                        const float* da = (pass == 0) ? dstA0_i[q] : dstA0_j[q];
                        gemm_mfma<float, false><<<gg, 256, 0, stream>>>(
                            sa, da, Wl0 + (size_t)r * FD * HHD, Wr0 + (size_t)r * FD * HHD,
                            HHD, w.xl, w.xr, NN, FD, HHD);
                        fused_aggr4<<<NN / 4, 256, 0, stream>>>(
                            w.rowptr[0], w.srcs[0], w.xl, w.xr, att0 + (size_t)r * HHD,
                            w.acc, q, (q == 1) ? 1 : 0,
                            b0 + (size_t)rids[0] * HHD, b0 + (size_t)rids[1] * HHD,
                            (pass == 0) ? w.z_i : w.z_j, nullptr, nullptr);
                    } else {
                        const unsigned short* sa = (pass == 2) ? srcA1_i[q] : srcA1_j[q];
                        const unsigned short* da = (pass == 2) ? dstA1_i[q] : dstA1_j[q];
                        gemm_mfma<unsigned short, true><<<gg, 256, 0, stream>>>(
                            sa, da, Wl1 + (size_t)r * CD * HHD, Wr1 + (size_t)r * CD * HHD,
                            HHD, w.xl, w.xr, NN, CD, HHD);
                        fused_aggr4<<<NN / 4, 256, 0, stream>>>(
                            w.rowptr[0], w.srcs[0], w.xl, w.xr, att1 + (size_t)r * HHD,
                            w.acc, q, (q == 1) ? 2 : 0,
                            b1 + (size_t)rids[0] * HHD, b1 + (size_t)rids[1] * HHD,
                            nullptr, (pass == 2) ? batch_i : batch_j,
                            (pass == 2) ? w.pool_i : w.pool_j);
                    }
                }
                if (pass == 2)
                    pool_reduce<<<BG, 512, 0, stream>>>(w.acc, batch_i, w.pool_i);
                else if (pass == 3)
                    pool_reduce<<<BG, 512, 0, stream>>>(w.acc, batch_j, w.pool_j);
            }
        }
    } else {
        const int* eis_i[2] = { ei_ii, ei_ji };
        const int* eis_j[2] = { ei_jj, ei_ij };
        run_group_thin<float, false>(srcA0_i, dstA0_i, eis_i, rids_i, FD, Wl0, Wr0, att0, b0,
                                     1, w.z_i, nullptr, nullptr, w, stream);
        run_group_thin<float, false>(srcA0_j, dstA0_j, eis_j, rids_j, FD, Wl0, Wr0, att0, b0,
                                     1, w.z_j, nullptr, nullptr, w, stream);
        run_group_thin<unsigned short, true>(srcA1_i, dstA1_i, eis_i, rids_i, CD, Wl1, Wr1, att1, b1,
                                             2, nullptr, batch_i, w.pool_i, w, stream);
        run_group_thin<unsigned short, true>(srcA1_j, dstA1_j, eis_j, rids_j, CD, Wl1, Wr1, att1, b1,
                                             2, nullptr, batch_j, w.pool_j, w, stream);
    }

    head_kernel<<<BG, 128, 0, stream>>>(w.pool_i, w.pool_j, W_out, b_out,
                                        W_i, b_i, W_j, b_j, out);
}

// Round 4
// 1413.994 us; speedup vs baseline: 1.3782x; 1.0193x over previous
//
#include <hip/hip_runtime.h>

// ---------------- problem constants ----------------
#define NN      20000     // nodes per type
#define EE      320000    // edges per relation
#define ETOT    340000    // EE + NN self loops
#define FD      512       // raw feature dim
#define HH_     4         // heads
#define CD      128       // channels per head
#define HHD     512       // H*C
#define BG      64        // batch graphs
#define INNERD  64

typedef __attribute__((ext_vector_type(8))) short bf16x8;
typedef __attribute__((ext_vector_type(4))) float f32x4;

// ---- bf16 <-> f32 via raw bits ----
__device__ __forceinline__ float bf2f(unsigned v) { return __uint_as_float(v << 16); }
__device__ __forceinline__ unsigned short f2bf(float f) {
    unsigned u = __float_as_uint(f);
    unsigned r = 0x7fffu + ((u >> 16) & 1u);
    return (unsigned short)((u + r) >> 16);
}
__device__ __forceinline__ void load8bf(const unsigned short* p, float* f) {
    uint4 u = *reinterpret_cast<const uint4*>(p);
    f[0] = bf2f(u.x & 0xffffu); f[1] = bf2f(u.x >> 16);
    f[2] = bf2f(u.y & 0xffffu); f[3] = bf2f(u.y >> 16);
    f[4] = bf2f(u.z & 0xffffu); f[5] = bf2f(u.z >> 16);
    f[6] = bf2f(u.w & 0xffffu); f[7] = bf2f(u.w >> 16);
}
// fast split f32 -> hi + lo bf16 (truncation; residual ~2^-16 relative)
__device__ __forceinline__ void split_f32(float x, unsigned short& hi, unsigned short& lo) {
    unsigned u = __float_as_uint(x);
    hi = (unsigned short)(u >> 16);
    float r = x - bf2f(hi);
    lo = (unsigned short)(__float_as_uint(r) >> 16);
}
template <typename TA>
__device__ __forceinline__ void splitA(const TA* p, size_t i, unsigned short& hi, unsigned short& lo);
template <>
__device__ __forceinline__ void splitA<float>(const float* p, size_t i, unsigned short& hi, unsigned short& lo) {
    split_f32(p[i], hi, lo);
}
template <>
__device__ __forceinline__ void splitA<unsigned short>(const unsigned short* p, size_t i, unsigned short& hi, unsigned short& lo) {
    hi = p[i]; lo = 0;
}

// ================= CSR build =================
__global__ __launch_bounds__(256) void csr_hist(const int* __restrict__ ei, int* __restrict__ cnt) {
    int e = blockIdx.x * blockDim.x + threadIdx.x;
    if (e < EE) atomicAdd(&cnt[ei[EE + e]], 1);
}

__global__ __launch_bounds__(1024) void csr_scan(const int* __restrict__ cnt,
                                                 int* __restrict__ rowptr,
                                                 int* __restrict__ cursor) {
    __shared__ int part[1024];
    int t = threadIdx.x;
    int base = t * 20;
    int s = 0;
    #pragma unroll
    for (int i = 0; i < 20; ++i) { int n = base + i; if (n < NN) s += cnt[n] + 1; }
    part[t] = s;
    __syncthreads();
    for (int off = 1; off < 1024; off <<= 1) {
        int v = (t >= off) ? part[t - off] : 0;
        __syncthreads();
        part[t] += v;
        __syncthreads();
    }
    int run = (t > 0) ? part[t - 1] : 0;
    #pragma unroll
    for (int i = 0; i < 20; ++i) {
        int n = base + i;
        if (n < NN) { rowptr[n] = run; cursor[n] = run; run += cnt[n] + 1; }
    }
    if (t == 1023) rowptr[NN] = run;
}

// scatter src ids as uint16 (node ids < 65536); self-loop appended per node
__global__ __launch_bounds__(256) void csr_scatter16(const int* __restrict__ ei,
                                                     int* __restrict__ cursor,
                                                     unsigned short* __restrict__ srcs) {
    int idx = blockIdx.x * blockDim.x + threadIdx.x;
    if (idx >= ETOT) return;
    int src, dst;
    if (idx < EE) { src = ei[idx]; dst = ei[EE + idx]; }
    else          { src = dst = idx - EE; }
    int pos = atomicAdd(&cursor[dst], 1);
    srcs[pos] = (unsigned short)src;
}

// ================= W pre-split: [R][K][512] f32 -> hi/lo FRAGMENT-TILED bf16 =========
// Output layout per relation: [K/32][N=512][32] — the exact per-lane MFMA B-fragment
// order, so the GEMM reads B directly from L2 (dense 1KB/wave/instr), no LDS staging.
__global__ __launch_bounds__(256) void wsplit_t(const float* __restrict__ W,
                                                unsigned short* __restrict__ Whi,
                                                unsigned short* __restrict__ Wlo,
                                                int K)
{
    __shared__ float tile[64][65];
    const int nt = 512 / 64;
    const int kt = K / 64;
    int bid = blockIdx.x;
    int in = bid % nt; int ik = (bid / nt) % kt; int r = bid / (nt * kt);
    int t = threadIdx.x;
    const float* Wr_ = W + (size_t)r * K * 512;
    #pragma unroll
    for (int rep = 0; rep < 16; ++rep) {
        int idx = rep * 256 + t;
        int kk = idx >> 6, nn = idx & 63;
        tile[kk][nn] = Wr_[(size_t)(ik * 64 + kk) * 512 + in * 64 + nn];
    }
    __syncthreads();
    #pragma unroll
    for (int rep = 0; rep < 16; ++rep) {
        int idx = rep * 256 + t;
        int nn = idx >> 6, kk = idx & 63;
        unsigned short h, l; split_f32(tile[kk][nn], h, l);
        int n = in * 64 + nn;
        int k = ik * 64 + kk;
        size_t o = (size_t)r * 512 * K + ((size_t)(k >> 5) * 512 + n) * 32 + (k & 31);
        Whi[o] = h; Wlo[o] = l;
    }
}

// ================= 128x128 split-bf16 MFMA GEMM core (B direct-from-L2) =============
// A staged+split in LDS; B read per-wave from fragment-tiled global (L2-resident,
// reused across all 157 M-tiles). LDS traffic per K-step: 96KB -> 48KB.
template <typename TA, bool A_EXACT>
__device__ __forceinline__ void gemm_body(
    const TA* __restrict__ A, const unsigned short* __restrict__ Bhg,
    const unsigned short* __restrict__ Blg, unsigned short* __restrict__ C,
    int bx, int by, int M, int K, int N)
{
    __shared__ unsigned short Ah[128][40];
    __shared__ unsigned short Al[A_EXACT ? 1 : 128][40];

    const int tid = threadIdx.x;
    const int wave = tid >> 6, lane = tid & 63;
    const int quad = lane >> 4, lrow = lane & 15;
    const int wr = (wave >> 1) * 64, wc = (wave & 1) * 64;
    const int tileM = by * 128, tileN = bx * 128;

    const int srow = tid >> 1;
    const int sks  = (tid & 1) * 16;
    const int sgm  = tileM + srow;

    // per-lane B fragment offset within one k-block: row (tileN+wc+lrow), elems quad*8
    const size_t bfrag = ((size_t)(tileN + wc + lrow) << 5) + quad * 8;
    const size_t kblk  = (size_t)N << 5;   // elements per k-block of the frag layout

    f32x4 acc[4][4] = {};

    for (int k0 = 0; k0 < K; k0 += 32) {
        // ---- stage A: 128 x 32 (hi/lo split in LDS) ----
        if constexpr (!A_EXACT) {
            bf16x8 ph[2] = {{}, {}}, pl[2] = {{}, {}};
            if (sgm < M) {
                const float* Ap = (const float*)A + (size_t)sgm * K + k0 + sks;
                #pragma unroll
                for (int s = 0; s < 2; ++s) {
                    float4 f0 = reinterpret_cast<const float4*>(Ap)[2 * s];
                    float4 f1 = reinterpret_cast<const float4*>(Ap)[2 * s + 1];
                    float xv[8] = {f0.x, f0.y, f0.z, f0.w, f1.x, f1.y, f1.z, f1.w};
                    #pragma unroll
                    for (int pp = 0; pp < 4; ++pp) {
                        unsigned u0 = __float_as_uint(xv[2 * pp]);
                        unsigned u1 = __float_as_uint(xv[2 * pp + 1]);
                        reinterpret_cast<unsigned*>(&ph[s])[pp] =
                            __builtin_amdgcn_perm(u1, u0, 0x07060302u);
                        float r0 = xv[2 * pp]     - __uint_as_float(u0 & 0xffff0000u);
                        float r1 = xv[2 * pp + 1] - __uint_as_float(u1 & 0xffff0000u);
                        reinterpret_cast<unsigned*>(&pl[s])[pp] =
                            __builtin_amdgcn_perm(__float_as_uint(r1), __float_as_uint(r0), 0x07060302u);
                    }
                }
            }
            *reinterpret_cast<bf16x8*>(&Ah[srow][sks])     = ph[0];
            *reinterpret_cast<bf16x8*>(&Ah[srow][sks + 8]) = ph[1];
            *reinterpret_cast<bf16x8*>(&Al[srow][sks])     = pl[0];
            *reinterpret_cast<bf16x8*>(&Al[srow][sks + 8]) = pl[1];
        } else {
            bf16x8 v0 = {}, v1 = {};
            if (sgm < M) {
                const unsigned short* Ap = (const unsigned short*)A + (size_t)sgm * K + k0 + sks;
                v0 = reinterpret_cast<const bf16x8*>(Ap)[0];
                v1 = reinterpret_cast<const bf16x8*>(Ap)[1];
            }
            *reinterpret_cast<bf16x8*>(&Ah[srow][sks])     = v0;
            *reinterpret_cast<bf16x8*>(&Ah[srow][sks + 8]) = v1;
        }
        // ---- issue B fragment loads (global, L2-hot) BEFORE the barrier ----
        bf16x8 bh[4], bl[4];
        {
            const unsigned short* Bb = Bhg + (size_t)(k0 >> 5) * kblk + bfrag;
            const unsigned short* Bc = Blg + (size_t)(k0 >> 5) * kblk + bfrag;
            #pragma unroll
            for (int ni = 0; ni < 4; ++ni) {
                bh[ni] = *reinterpret_cast<const bf16x8*>(Bb + ((size_t)ni << 9));
                bl[ni] = *reinterpret_cast<const bf16x8*>(Bc + ((size_t)ni << 9));
            }
        }
        __syncthreads();
        bf16x8 ah[4], al[4];
        #pragma unroll
        for (int mi = 0; mi < 4; ++mi) {
            ah[mi] = *reinterpret_cast<const bf16x8*>(&Ah[wr + mi * 16 + lrow][quad * 8]);
            if constexpr (!A_EXACT)
                al[mi] = *reinterpret_cast<const bf16x8*>(&Al[wr + mi * 16 + lrow][quad * 8]);
        }
        #pragma unroll
        for (int mi = 0; mi < 4; ++mi)
            #pragma unroll
            for (int ni = 0; ni < 4; ++ni) {
                acc[mi][ni] = __builtin_amdgcn_mfma_f32_16x16x32_bf16(
                    ah[mi], bh[ni], acc[mi][ni], 0, 0, 0);
                acc[mi][ni] = __builtin_amdgcn_mfma_f32_16x16x32_bf16(
                    ah[mi], bl[ni], acc[mi][ni], 0, 0, 0);
                if constexpr (!A_EXACT)
                    acc[mi][ni] = __builtin_amdgcn_mfma_f32_16x16x32_bf16(
                        al[mi], bh[ni], acc[mi][ni], 0, 0, 0);
            }
        __syncthreads();
    }
    #pragma unroll
    for (int mi = 0; mi < 4; ++mi) {
        #pragma unroll
        for (int ni = 0; ni < 4; ++ni) {
            int gcol = tileN + wc + ni * 16 + lrow;
            #pragma unroll
            for (int r = 0; r < 4; ++r) {
                int grow = tileM + wr + mi * 16 + quad * 4 + r;
                if (grow < M)
                    C[(size_t)grow * N + gcol] = f2bf(acc[mi][ni][r]);
            }
        }
    }
}

// z=2 variant (fat_t fallback path)
template <typename TA, bool A_EXACT>
__global__ __launch_bounds__(256, 3) void gemm_mfma_t(
    const TA* __restrict__ A0, const TA* __restrict__ A1,
    const unsigned short* __restrict__ B0h, const unsigned short* __restrict__ B0l,
    const unsigned short* __restrict__ B1h, const unsigned short* __restrict__ B1l,
    unsigned short* __restrict__ C0, unsigned short* __restrict__ C1,
    int M, int K, int N)
{
    const int gx = gridDim.x, gy = gridDim.y;
    const int nwg = gx * gy * (int)gridDim.z;
    int b = ((int)blockIdx.z * gy + blockIdx.y) * gx + blockIdx.x;
    int xcd = b & 7, q8 = nwg >> 3, r8 = nwg & 7;
    int work = (xcd < r8 ? xcd * (q8 + 1) : r8 * (q8 + 1) + (xcd - r8) * q8) + (b >> 3);
    int bx = work % gx; int t2 = work / gx; int by = t2 % gy; int bz = t2 / gy;

    const TA* A = bz ? A1 : A0;
    const unsigned short* Bhg = bz ? B1h : B0h;
    const unsigned short* Blg = bz ? B1l : B0l;
    unsigned short* C = bz ? C1 : C0;
    gemm_body<TA, A_EXACT>(A, Bhg, Blg, C, bx, by, M, K, N);
}

// z=4 variant (merged path: one dispatch covers both relations of a group)
template <typename TA, bool A_EXACT>
__global__ __launch_bounds__(256, 3) void gemm_mfma_t4(
    const TA* __restrict__ A0, const TA* __restrict__ A1,
    const TA* __restrict__ A2, const TA* __restrict__ A3,
    const unsigned short* __restrict__ B0h, const unsigned short* __restrict__ B0l,
    const unsigned short* __restrict__ B1h, const unsigned short* __restrict__ B1l,
    const unsigned short* __restrict__ B2h, const unsigned short* __restrict__ B2l,
    const unsigned short* __restrict__ B3h, const unsigned short* __restrict__ B3l,
    unsigned short* __restrict__ C0, unsigned short* __restrict__ C1,
    unsigned short* __restrict__ C2, unsigned short* __restrict__ C3,
    int M, int K, int N)
{
    const int gx = gridDim.x, gy = gridDim.y;
    const int nwg = gx * gy * (int)gridDim.z;
    int b = ((int)blockIdx.z * gy + blockIdx.y) * gx + blockIdx.x;
    int xcd = b & 7, q8 = nwg >> 3, r8 = nwg & 7;
    int work = (xcd < r8 ? xcd * (q8 + 1) : r8 * (q8 + 1) + (xcd - r8) * q8) + (b >> 3);
    int bx = work % gx; int t2 = work / gx; int by = t2 % gy; int bz = t2 / gy;

    const TA* A = bz == 0 ? A0 : bz == 1 ? A1 : bz == 2 ? A2 : A3;
    const unsigned short* Bhg = bz == 0 ? B0h : bz == 1 ? B1h : bz == 2 ? B2h : B3h;
    const unsigned short* Blg = bz == 0 ? B0l : bz == 1 ? B1l : bz == 2 ? B2l : B3l;
    unsigned short* C = bz == 0 ? C0 : bz == 1 ? C1 : bz == 2 ? C2 : C3;
    gemm_body<TA, A_EXACT>(A, Bhg, Blg, C, bx, by, M, K, N);
}

// ================= OLD 64x64 split-bf16 GEMM (deep fallback; raw f32 W) =============
template <typename TA, bool A_EXACT>
__global__ __launch_bounds__(256) void gemm_mfma(
    const TA* __restrict__ A0, const TA* __restrict__ A1,
    const float* __restrict__ B0, const float* __restrict__ B1, int ldb,
    unsigned short* __restrict__ C0, unsigned short* __restrict__ C1,
    int M, int K, int N)
{
    const TA* A = blockIdx.z ? A1 : A0;
    const float* B = blockIdx.z ? B1 : B0;
    unsigned short* C = blockIdx.z ? C1 : C0;

    __shared__ unsigned short Ah[64][40];
    __shared__ unsigned short Al[64][40];
    __shared__ unsigned short Bh[64][40];
    __shared__ unsigned short Bl[64][40];
    const int tid = threadIdx.x;
    const int wave = tid >> 6, lane = tid & 63;
    const int quad = lane >> 4, lrow = lane & 15;
    const int tileM = blockIdx.y * 64, tileN = blockIdx.x * 64;
    const int wm = (wave >> 1) * 32, wn = (wave & 1) * 32;

    f32x4 acc[2][2] = {};

    const int am = tid >> 2;
    const int aks = (tid & 3) * 8;
    const int bn = tid & 63;
    const int bk0 = (tid >> 6) * 8;

    for (int k0 = 0; k0 < K; k0 += 32) {
        {
            int gm = tileM + am;
            bf16x8 ph = {}, pl = {};
            if (gm < M) {
                #pragma unroll
                for (int j = 0; j < 8; ++j) {
                    unsigned short h, l;
                    splitA(A, (size_t)gm * K + k0 + aks + j, h, l);
                    ph[j] = (short)h; pl[j] = (short)l;
                }
            }
            *reinterpret_cast<bf16x8*>(&Ah[am][aks]) = ph;
            if (!A_EXACT) *reinterpret_cast<bf16x8*>(&Al[am][aks]) = pl;
        }
        {
            bf16x8 ph, pl;
            #pragma unroll
            for (int j = 0; j < 8; ++j) {
                unsigned short h, l;
                split_f32(B[(size_t)(k0 + bk0 + j) * ldb + tileN + bn], h, l);
                ph[j] = (short)h; pl[j] = (short)l;
            }
            *reinterpret_cast<bf16x8*>(&Bh[bn][bk0]) = ph;
            *reinterpret_cast<bf16x8*>(&Bl[bn][bk0]) = pl;
        }
        __syncthreads();
        bf16x8 ah[2], al[2], bh[2], bl[2];
        #pragma unroll
        for (int mi = 0; mi < 2; ++mi) {
            ah[mi] = *reinterpret_cast<const bf16x8*>(&Ah[wm + mi * 16 + lrow][quad * 8]);
            if (!A_EXACT)
                al[mi] = *reinterpret_cast<const bf16x8*>(&Al[wm + mi * 16 + lrow][quad * 8]);
        }
        #pragma unroll
        for (int ni = 0; ni < 2; ++ni) {
            bh[ni] = *reinterpret_cast<const bf16x8*>(&Bh[wn + ni * 16 + lrow][quad * 8]);
            bl[ni] = *reinterpret_cast<const bf16x8*>(&Bl[wn + ni * 16 + lrow][quad * 8]);
        }
        #pragma unroll
        for (int mi = 0; mi < 2; ++mi)
            #pragma unroll
            for (int ni = 0; ni < 2; ++ni) {
                acc[mi][ni] = __builtin_amdgcn_mfma_f32_16x16x32_bf16(
                    ah[mi], bh[ni], acc[mi][ni], 0, 0, 0);
                acc[mi][ni] = __builtin_amdgcn_mfma_f32_16x16x32_bf16(
                    ah[mi], bl[ni], acc[mi][ni], 0, 0, 0);
                if (!A_EXACT)
                    acc[mi][ni] = __builtin_amdgcn_mfma_f32_16x16x32_bf16(
                        al[mi], bh[ni], acc[mi][ni], 0, 0, 0);
            }
        __syncthreads();
    }
    #pragma unroll
    for (int mi = 0; mi < 2; ++mi) {
        #pragma unroll
        for (int ni = 0; ni < 2; ++ni) {
            int gcol = tileN + wn + ni * 16 + lrow;
            #pragma unroll
            for (int r = 0; r < 4; ++r) {
                int grow = tileM + wm + mi * 16 + quad * 4 + r;
                if (grow < M)
                    C[(size_t)grow * N + gcol] = f2bf(acc[mi][ni][r]);
            }
        }
    }
}

// ================= THIN: fused GATv2 pass, one head (deep fallback) =================
__global__ __launch_bounds__(256) void fused_aggr1(
    const int* __restrict__ rowptr, const unsigned short* __restrict__ srcs,
    const unsigned short* __restrict__ xl, const unsigned short* __restrict__ xr,
    const float* __restrict__ att,
    float* __restrict__ acc, int add_in, int fin_mode,
    const float* __restrict__ bA, const float* __restrict__ bB,
    unsigned short* __restrict__ z,
    const int* __restrict__ batch, float* __restrict__ pool)
{
    int dst = (int)((blockIdx.x * (size_t)blockDim.x + threadIdx.x) >> 6);
    int lane = threadIdx.x & 63;
    if (dst >= NN) return;
    int beg = rowptr[dst], end = rowptr[dst + 1];

    unsigned ub = *reinterpret_cast<const unsigned*>(xr + (size_t)dst * CD + lane * 2);
    float br0 = bf2f(ub & 0xffffu), br1 = bf2f(ub >> 16);
    float ta0 = att[lane * 2], ta1 = att[lane * 2 + 1];

    float n0 = 0.f, n1 = 0.f, den = 0.f;
    for (int k = beg; k < end; ++k) {
        int src = srcs[k];
        unsigned ua = *reinterpret_cast<const unsigned*>(xl + (size_t)src * CD + lane * 2);
        float a0 = bf2f(ua & 0xffffu), a1 = bf2f(ua >> 16);
        float v0 = a0 + br0, v1 = a1 + br1;
        v0 = (v0 > 0.f) ? v0 : 0.2f * v0;
        v1 = (v1 > 0.f) ? v1 : 0.2f * v1;
        float d = v0 * ta0 + v1 * ta1;
        #pragma unroll
        for (int off = 1; off < 64; off <<= 1)
            d += __shfl_xor(d, off);
        float p = expf(d);
        n0 += p * a0; n1 += p * a1; den += p;
    }
    float o0 = n0 / den, o1 = n1 / den;
    size_t ai = (size_t)dst * CD + lane * 2;
    if (add_in) { o0 += acc[ai]; o1 += acc[ai + 1]; }
    if (fin_mode == 0) {
        acc[ai] = o0; acc[ai + 1] = o1;
    } else {
        int c0 = lane * 2;
        float bb0 = 0.f, bb1 = 0.f;
        #pragma unroll
        for (int h = 0; h < HH_; ++h) {
            bb0 += bA[h * CD + c0]     + bB[h * CD + c0];
            bb1 += bA[h * CD + c0 + 1] + bB[h * CD + c0 + 1];
        }
        o0 = tanhf(o0 + bb0);
        o1 = tanhf(o1 + bb1);
        if (fin_mode == 1) {
            z[ai] = f2bf(o0); z[ai + 1] = f2bf(o1);
        } else {
            int b = batch[dst];
            atomicAdd(&pool[(size_t)b * CD + c0],     o0);
            atomicAdd(&pool[(size_t)b * CD + c0 + 1], o1);
        }
    }
}

// ================= GATv2 relation pass: 2x-unrolled edge loop =================
// VALU-bound (R3: VALUBusy 67%): leaky as fmaxf (mul+max guaranteed) and __expf
// (v_mul+v_exp vs libm range-reduction) cut ~20% of per-edge VALU instructions.
__device__ __forceinline__ void gat_rel(
    const int* __restrict__ rp, const unsigned short* __restrict__ sr,
    const unsigned short* __restrict__ xl, const unsigned short* __restrict__ xr,
    const float* __restrict__ att, int dst, int lane, float* o)
{
    int beg = rp[dst], end = rp[dst + 1];
    float br[8], ta[8];
    load8bf(xr + (size_t)dst * HHD + lane * 8, br);
    #pragma unroll
    for (int j = 0; j < 8; ++j) ta[j] = att[lane * 8 + j];

    float n[8] = {}; float den = 0.f;
    int k = beg;
    for (; k + 2 <= end; k += 2) {
        int s0 = sr[k], s1 = sr[k + 1];
        float a0[8], a1[8];
        load8bf(xl + (size_t)s0 * HHD + lane * 8, a0);
        load8bf(xl + (size_t)s1 * HHD + lane * 8, a1);
        float d0 = 0.f, d1 = 0.f;
        #pragma unroll
        for (int j = 0; j < 8; ++j) {
            float v0 = a0[j] + br[j];
            v0 = fmaxf(v0, 0.2f * v0);
            d0 += v0 * ta[j];
            float v1 = a1[j] + br[j];
            v1 = fmaxf(v1, 0.2f * v1);
            d1 += v1 * ta[j];
        }
        d0 += __shfl_xor(d0, 1);  d1 += __shfl_xor(d1, 1);
        d0 += __shfl_xor(d0, 2);  d1 += __shfl_xor(d1, 2);
        d0 += __shfl_xor(d0, 4);  d1 += __shfl_xor(d1, 4);
        d0 += __shfl_xor(d0, 8);  d1 += __shfl_xor(d1, 8);
        float p0 = __expf(d0), p1 = __expf(d1);
        den += p0;
        #pragma unroll
        for (int j = 0; j < 8; ++j) n[j] += p0 * a0[j];
        den += p1;
        #pragma unroll
        for (int j = 0; j < 8; ++j) n[j] += p1 * a1[j];
    }
    if (k < end) {
        int s0 = sr[k];
        float a0[8];
        load8bf(xl + (size_t)s0 * HHD + lane * 8, a0);
        float d0 = 0.f;
        #pragma unroll
        for (int j = 0; j < 8; ++j) {
            float v0 = a0[j] + br[j];
            v0 = fmaxf(v0, 0.2f * v0);
            d0 += v0 * ta[j];
        }
        d0 += __shfl_xor(d0, 1);
        d0 += __shfl_xor(d0, 2);
        d0 += __shfl_xor(d0, 4);
        d0 += __shfl_xor(d0, 8);
        float p0 = __expf(d0);
        den += p0;
        #pragma unroll
        for (int j = 0; j < 8; ++j) n[j] += p0 * a0[j];
    }
    float inv = 1.f / den;
    #pragma unroll
    for (int j = 0; j < 8; ++j) {
        o[j] = n[j] * inv;
        o[j] += __shfl_xor(o[j], 16);   // head-sum (once per dst)
        o[j] += __shfl_xor(o[j], 32);
    }
}

// ================= FAT: single-relation pass (fat_t fallback) =================
__global__ __launch_bounds__(256) void fused_aggr4(
    const int* __restrict__ rowptr, const unsigned short* __restrict__ srcs,
    const unsigned short* __restrict__ xl, const unsigned short* __restrict__ xr,
    const float* __restrict__ att,
    float* __restrict__ acc, int add_in, int fin_mode,
    const float* __restrict__ bA, const float* __restrict__ bB,
    unsigned short* __restrict__ z,
    const int* __restrict__ batch, float* __restrict__ pool)
{
    int dst = (int)((blockIdx.x * (size_t)blockDim.x + threadIdx.x) >> 6);
    int lane = threadIdx.x & 63;
    if (dst >= NN) return;

    float o[8];
    gat_rel(rowptr, srcs, xl, xr, att, dst, lane, o);

    if (lane < 16) {
        size_t ai = (size_t)dst * CD + lane * 8;
        if (add_in) {
            #pragma unroll
            for (int j = 0; j < 8; ++j) o[j] += acc[ai + j];
        }
        if (fin_mode == 0) {
            #pragma unroll
            for (int j = 0; j < 8; ++j) acc[ai + j] = o[j];
        } else {
            int c0 = lane * 8;
            #pragma unroll
            for (int j = 0; j < 8; ++j) {
                float bb = 0.f;
                #pragma unroll
                for (int h = 0; h < HH_; ++h)
                    bb += bA[h * CD + c0 + j] + bB[h * CD + c0 + j];
                o[j] = tanhf(o[j] + bb);
            }
            if (fin_mode == 1) {
                #pragma unroll
                for (int j = 0; j < 8; ++j) z[ai + j] = f2bf(o[j]);
            } else {
                #pragma unroll
                for (int j = 0; j < 8; ++j) acc[ai + j] = o[j];
            }
        }
    }
}

// ================= FAT merged: BOTH relations of a group in one dispatch ============
__global__ __launch_bounds__(256) void fused_aggr4d(
    const int* __restrict__ rp0, const unsigned short* __restrict__ sr0,
    const unsigned short* __restrict__ xl0, const unsigned short* __restrict__ xr0,
    const float* __restrict__ attA,
    const int* __restrict__ rp1, const unsigned short* __restrict__ sr1,
    const unsigned short* __restrict__ xl1, const unsigned short* __restrict__ xr1,
    const float* __restrict__ attB,
    float* __restrict__ acc, int fin_mode,
    const float* __restrict__ bA, const float* __restrict__ bB,
    unsigned short* __restrict__ z,
    const int* __restrict__ batch, float* __restrict__ pool)
{
    int dst = (int)((blockIdx.x * (size_t)blockDim.x + threadIdx.x) >> 6);
    int lane = threadIdx.x & 63;
    if (dst >= NN) return;

    float o0[8], o1[8];
    gat_rel(rp0, sr0, xl0, xr0, attA, dst, lane, o0);
    gat_rel(rp1, sr1, xl1, xr1, attB, dst, lane, o1);
    #pragma unroll
    for (int j = 0; j < 8; ++j) o1[j] += o0[j];

    if (lane < 16) {
        size_t ai = (size_t)dst * CD + lane * 8;
        int c0 = lane * 8;
        #pragma unroll
        for (int j = 0; j < 8; ++j) {
            float bb = 0.f;
            #pragma unroll
            for (int h = 0; h < HH_; ++h)
                bb += bA[h * CD + c0 + j] + bB[h * CD + c0 + j];
            o1[j] = tanhf(o1[j] + bb);
        }
        if (fin_mode == 1) {
            #pragma unroll
            for (int j = 0; j < 8; ++j) z[ai + j] = f2bf(o1[j]);
        } else {
            #pragma unroll
            for (int j = 0; j < 8; ++j) acc[ai + j] = o1[j];
        }
    }
}

// ================= pool_reduce: segmented sum over sorted batch (no atomics) ========
__global__ __launch_bounds__(512) void pool_reduce(
    const float* __restrict__ acc, const int* __restrict__ batch,
    float* __restrict__ pool)
{
    int b = blockIdx.x;
    int t = threadIdx.x & (CD - 1);
    int q = threadIdx.x >> 7;
    int lo, hi;
    { int l = 0, r = NN; while (l < r) { int m = (l + r) >> 1; if (batch[m] < b) l = m + 1; else r = m; } lo = l; }
    { int l = lo, r = NN; while (l < r) { int m = (l + r) >> 1; if (batch[m] <= b) l = m + 1; else r = m; } hi = l; }
    float s = 0.f;
    for (int nrow = lo + q; nrow < hi; nrow += 4)
        s += acc[(size_t)nrow * CD + t];
    __shared__ float red[4][CD];
    red[q][t] = s;
    __syncthreads();
    if (q == 0)
        pool[(size_t)b * CD + t] = red[0][t] + red[1][t] + red[2][t] + red[3][t];
}

// ================= head =================
__global__ __launch_bounds__(128) void head_kernel(
    const float* __restrict__ pool_i, const float* __restrict__ pool_j,
    const float* __restrict__ W_out, const float* __restrict__ b_out,
    const float* __restrict__ W_i, const float* __restrict__ b_i,
    const float* __restrict__ W_j, const float* __restrict__ b_j,
    float* __restrict__ out)
{
    int b = blockIdx.x;
    int t = threadIdx.x;
    __shared__ float pi[CD], pj[CD];
    pi[t] = tanhf(pool_i[(size_t)b * CD + t]);
    pj[t] = tanhf(pool_j[(size_t)b * CD + t]);
    __syncthreads();
    if (t < INNERD) {
        float a = b_i[t];
        for (int c = 0; c < CD; ++c) a += pi[c] * W_i[c * INNERD + t];
        out[BG + (size_t)b * INNERD + t] = a;
    } else {
        int k = t - INNERD;
        float a = b_j[k];
        for (int c = 0; c < CD; ++c) a += pj[c] * W_j[c * INNERD + k];
        out[BG + BG * INNERD + (size_t)b * INNERD + k] = a;
    }
    if (t == 0) {
        float a = b_out[0];
        for (int c = 0; c < CD; ++c) a += (pi[c] + pj[c]) * W_out[c];
        out[b] = 1.f / (1.f + expf(-a));
    }
}

// ================= host-side drivers =================
struct Ws {
    unsigned short *xl, *xr, *xl2, *xr2, *z_i, *z_j;
    float* acc;
    int *rowptr[4];
    unsigned short *srcs[4];
    int *cnt, *cursor;
    float *pool_i, *pool_j;
    unsigned short *wt0l_h, *wt0l_l, *wt0r_h, *wt0r_l;
    unsigned short *wt1l_h, *wt1l_l, *wt1r_h, *wt1r_l;
};

static void build_csr(const int* ei, int* rowptr, unsigned short* srcs,
                      int* cnt, int* cursor, hipStream_t stream) {
    hipMemsetAsync(cnt, 0, NN * sizeof(int), stream);
    csr_hist<<<(EE + 255) / 256, 256, 0, stream>>>(ei, cnt);
    csr_scan<<<1, 1024, 0, stream>>>(cnt, rowptr, cursor);
    csr_scatter16<<<(ETOT + 255) / 256, 256, 0, stream>>>(ei, cursor, srcs);
}

// ---- MERGED group pass: z=4 GEMM then one dual-relation aggr ----
template <typename TA, bool A_EXACT>
static void run_group_fat_m(const TA* srcA[2], const TA* dstA[2],
                            const int* rp[2], const unsigned short* sr[2],
                            const int rids[2], int K,
                            const unsigned short* WTl_h, const unsigned short* WTl_l,
                            const unsigned short* WTr_h, const unsigned short* WTr_l,
                            const float* att, const float* bias, int fin_mode,
                            unsigned short* zout, const int* batch, float* pool,
                            const Ws& w, hipStream_t stream)
{
    dim3 gg(HHD / 128, (NN + 127) / 128, 4);
    size_t off0 = (size_t)rids[0] * HHD * K;
    size_t off1 = (size_t)rids[1] * HHD * K;
    gemm_mfma_t4<TA, A_EXACT><<<gg, 256, 0, stream>>>(
        srcA[0], dstA[0], srcA[1], dstA[1],
        WTl_h + off0, WTl_l + off0, WTr_h + off0, WTr_l + off0,
        WTl_h + off1, WTl_l + off1, WTr_h + off1, WTr_l + off1,
        w.xl, w.xr, w.xl2, w.xr2, NN, K, HHD);
    fused_aggr4d<<<NN / 4, 256, 0, stream>>>(
        rp[0], sr[0], w.xl, w.xr, att + (size_t)rids[0] * HHD,
        rp[1], sr[1], w.xl2, w.xr2, att + (size_t)rids[1] * HHD,
        w.acc, fin_mode,
        bias + (size_t)rids[0] * HHD, bias + (size_t)rids[1] * HHD,
        zout, batch, pool);
}

// ---- fat_t group pass (fallback, z=2 GEMM + 2 aggr) ----
template <typename TA, bool A_EXACT>
static void run_group_fat_t(const TA* srcA[2], const TA* dstA[2],
                            const int* rp[2], const unsigned short* sr[2],
                            const int rids[2], int K,
                            const unsigned short* WTl_h, const unsigned short* WTl_l,
                            const unsigned short* WTr_h, const unsigned short* WTr_l,
                            const float* att, const float* bias, int fin_mode,
                            unsigned short* zout, const int* batch, float* pool,
                            const Ws& w, hipStream_t stream)
{
    dim3 gg(HHD / 128, (NN + 127) / 128, 2);
    const int ablocks = NN / 4;
    for (int q = 0; q < 2; ++q) {
        int r = rids[q];
        size_t off = (size_t)r * HHD * K;
        gemm_mfma_t<TA, A_EXACT><<<gg, 256, 0, stream>>>(
            srcA[q], dstA[q],
            WTl_h + off, WTl_l + off, WTr_h + off, WTr_l + off,
            w.xl, w.xr, NN, K, HHD);
        int fm = (q == 1) ? fin_mode : 0;
        fused_aggr4<<<ablocks, 256, 0, stream>>>(
            rp[q], sr[q], w.xl, w.xr,
            att + (size_t)r * HHD,
            w.acc, q > 0 ? 1 : 0, fm,
            bias + (size_t)rids[0] * HHD, bias + (size_t)rids[1] * HHD,
            zout, batch, pool);
    }
}

// ---- OLD FAT group pass (fallback) ----
template <typename TA, bool A_EXACT>
static void run_group_fat(const TA* srcA[2], const TA* dstA[2],
                          const int* rp[2], const unsigned short* sr[2],
                          const int rids[2], int K,
                          const float* Wl, const float* Wr, const float* att,
                          const float* bias, int fin_mode,
                          unsigned short* zout, const int* batch, float* pool,
                          const Ws& w, hipStream_t stream)
{
    dim3 gg(HHD / 64, (NN + 63) / 64, 2);
    const int ablocks = NN / 4;
    for (int q = 0; q < 2; ++q) {
        int r = rids[q];
        gemm_mfma<TA, A_EXACT><<<gg, 256, 0, stream>>>(
            srcA[q], dstA[q],
            Wl + (size_t)r * K * HHD, Wr + (size_t)r * K * HHD, HHD,
            w.xl, w.xr, NN, K, HHD);
        int fm = (q == 1) ? fin_mode : 0;
        fused_aggr4<<<ablocks, 256, 0, stream>>>(
            rp[q], sr[q], w.xl, w.xr,
            att + (size_t)r * HHD,
            w.acc, q > 0 ? 1 : 0, fm,
            bias + (size_t)rids[0] * HHD, bias + (size_t)rids[1] * HHD,
            zout, batch, pool);
    }
}

// ---- THIN group pass (deep fallback) ----
template <typename TA, bool A_EXACT>
static void run_group_thin(const TA* srcA[2], const TA* dstA[2],
                           const int* eis[2], const int rids[2], int K,
                           const float* Wl, const float* Wr, const float* att,
                           const float* bias, int fin_mode,
                           unsigned short* zout, const int* batch, float* pool,
                           const Ws& w, hipStream_t stream)
{
    dim3 gg(2, (NN + 63) / 64, 2);
    const int ablocks = NN / 4;
    for (int q = 0; q < 2; ++q) {
        int r = rids[q];
        build_csr(eis[q], w.rowptr[0], w.srcs[0], w.cnt, w.cursor, stream);
        for (int h = 0; h < HH_; ++h) {
            const float* WlS = Wl + (size_t)r * K * HHD + h * CD;
            const float* WrS = Wr + (size_t)r * K * HHD + h * CD;
            gemm_mfma<TA, A_EXACT><<<gg, 256, 0, stream>>>(
                srcA[q], dstA[q], WlS, WrS, HHD, w.xl, w.xr, NN, K, CD);
            int pass = q * HH_ + h;
            int fm = (pass == 2 * HH_ - 1) ? fin_mode : 0;
            fused_aggr1<<<ablocks, 256, 0, stream>>>(
                w.rowptr[0], w.srcs[0], w.xl, w.xr,
                att + (size_t)r * HHD + h * CD,
                w.acc, pass > 0 ? 1 : 0, fm,
                bias + (size_t)rids[0] * HHD, bias + (size_t)rids[1] * HHD,
                zout, batch, pool);
        }
    }
}

extern "C" void kernel_launch(void* const* d_in, const int* in_sizes, int n_in,
                              void* d_out, int out_size, void* d_ws, size_t ws_size,
                              hipStream_t stream)
{
    const float* x_i   = (const float*)d_in[0];
    const float* x_j   = (const float*)d_in[1];
    const int* ei_ii   = (const int*)d_in[2];
    const int* ei_jj   = (const int*)d_in[3];
    const int* ei_ij   = (const int*)d_in[4];
    const int* ei_ji   = (const int*)d_in[5];
    const int* batch_i = (const int*)d_in[6];
    const int* batch_j = (const int*)d_in[7];
    const float* Wl0   = (const float*)d_in[8];
    const float* Wr0   = (const float*)d_in[9];
    const float* att0  = (const float*)d_in[10];
    const float* b0    = (const float*)d_in[11];
    const float* Wl1   = (const float*)d_in[12];
    const float* Wr1   = (const float*)d_in[13];
    const float* att1  = (const float*)d_in[14];
    const float* b1    = (const float*)d_in[15];
    const float* W_out = (const float*)d_in[16];
    const float* b_out = (const float*)d_in[17];
    const float* W_i   = (const float*)d_in[18];
    const float* b_i   = (const float*)d_in[19];
    const float* W_j   = (const float*)d_in[20];
    const float* b_j   = (const float*)d_in[21];
    float* out = (float*)d_out;

    const size_t FAT2_BYTES = (size_t)NN * HHD * 2 * 2 + (size_t)NN * CD * 4
                            + (size_t)NN * CD * 2 * 2 + 4 * (size_t)ETOT * 2
                            + 4 * (size_t)(NN + 4) * 4 + (size_t)NN * 4 * 2
                            + (size_t)BG * CD * 4 * 2;
    const size_t FAT1_BYTES = (size_t)NN * HHD * 2 * 2 + (size_t)NN * CD * 4
                            + (size_t)NN * CD * 2 * 2 + (size_t)ETOT * 2
                            + (size_t)(NN + 4) * 4 + (size_t)NN * 4 * 2
                            + (size_t)BG * CD * 4 * 2;
    const size_t WT0_ONE = (size_t)4 * 512 * 512 * 2;
    const size_t WT1_ONE = (size_t)4 * 512 * 128 * 2;
    const size_t WT_BYTES = 4 * WT0_ONE + 4 * WT1_ONE;
    const size_t X2_BYTES = 2 * (size_t)NN * HHD * 2;   // second xl/xr pair (merged)

    const int ncsr = (ws_size >= FAT2_BYTES) ? 4 : 1;
    const bool fat = (ws_size >= FAT1_BYTES);
    const bool fat_t = (ws_size >= FAT2_BYTES + WT_BYTES);
    const bool fat_m = (ws_size >= FAT2_BYTES + WT_BYTES + X2_BYTES);   // merged path

    Ws w;
    char* p = (char*)d_ws;
    size_t xbytes = fat ? (size_t)NN * HHD * 2 : (size_t)NN * CD * 2;
    w.xl     = (unsigned short*)p; p += xbytes;
    w.xr     = (unsigned short*)p; p += xbytes;
    w.acc    = (float*)p;          p += (size_t)NN * CD * 4;
    w.z_i    = (unsigned short*)p; p += (size_t)NN * CD * 2;
    w.z_j    = (unsigned short*)p; p += (size_t)NN * CD * 2;
    for (int r = 0; r < 4; ++r) {
        int rr = (r < ncsr) ? r : 0;
        if (r < ncsr) {
            w.rowptr[r] = (int*)p;            p += (size_t)(NN + 4) * 4;
            w.srcs[r]   = (unsigned short*)p; p += (size_t)ETOT * 2;
        } else {
            w.rowptr[r] = w.rowptr[rr]; w.srcs[r] = w.srcs[rr];
        }
    }
    w.cnt    = (int*)p;            p += (size_t)NN * 4;
    w.cursor = (int*)p;            p += (size_t)NN * 4;
    w.pool_i = (float*)p;          p += (size_t)BG * CD * 4;
    w.pool_j = (float*)p;          p += (size_t)BG * CD * 4;
    if (fat_t) {
        w.wt0l_h = (unsigned short*)p; p += WT0_ONE;
        w.wt0l_l = (unsigned short*)p; p += WT0_ONE;
        w.wt0r_h = (unsigned short*)p; p += WT0_ONE;
        w.wt0r_l = (unsigned short*)p; p += WT0_ONE;
        w.wt1l_h = (unsigned short*)p; p += WT1_ONE;
        w.wt1l_l = (unsigned short*)p; p += WT1_ONE;
        w.wt1r_h = (unsigned short*)p; p += WT1_ONE;
        w.wt1r_l = (unsigned short*)p; p += WT1_ONE;
    }
    if (fat_m) {
        w.xl2 = (unsigned short*)p; p += (size_t)NN * HHD * 2;
        w.xr2 = (unsigned short*)p; p += (size_t)NN * HHD * 2;
    }

    hipMemsetAsync(w.pool_i, 0, (size_t)BG * CD * sizeof(float), stream);
    hipMemsetAsync(w.pool_j, 0, (size_t)BG * CD * sizeof(float), stream);

    const int* eis_all[4] = { ei_ii, ei_jj, ei_ij, ei_ji };
    const float* srcA0_i[2] = { x_i, x_j };  const float* dstA0_i[2] = { x_i, x_i };
    const float* srcA0_j[2] = { x_j, x_i };  const float* dstA0_j[2] = { x_j, x_j };
    const int rids_i[2] = { 0, 3 };
    const int rids_j[2] = { 1, 2 };
    const unsigned short* srcA1_i[2] = { w.z_i, w.z_j };
    const unsigned short* dstA1_i[2] = { w.z_i, w.z_i };
    const unsigned short* srcA1_j[2] = { w.z_j, w.z_i };
    const unsigned short* dstA1_j[2] = { w.z_j, w.z_j };

    if (fat_t) {
        // build all 4 CSRs once; pre-split+transpose+frag-tile all weights once
        for (int r = 0; r < 4; ++r)
            build_csr(eis_all[r], w.rowptr[r], w.srcs[r], w.cnt, w.cursor, stream);
        wsplit_t<<<4 * (FD / 64) * 8, 256, 0, stream>>>(Wl0, w.wt0l_h, w.wt0l_l, FD);
        wsplit_t<<<4 * (FD / 64) * 8, 256, 0, stream>>>(Wr0, w.wt0r_h, w.wt0r_l, FD);
        wsplit_t<<<4 * (CD / 64) * 8, 256, 0, stream>>>(Wl1, w.wt1l_h, w.wt1l_l, CD);
        wsplit_t<<<4 * (CD / 64) * 8, 256, 0, stream>>>(Wr1, w.wt1r_h, w.wt1r_l, CD);

        const int* rp_i[2] = { w.rowptr[0], w.rowptr[3] };
        const unsigned short* sr_i[2] = { w.srcs[0], w.srcs[3] };
        const int* rp_j[2] = { w.rowptr[1], w.rowptr[2] };
        const unsigned short* sr_j[2] = { w.srcs[1], w.srcs[2] };

        if (fat_m) {
            run_group_fat_m<float, false>(srcA0_i, dstA0_i, rp_i, sr_i, rids_i, FD,
                                          w.wt0l_h, w.wt0l_l, w.wt0r_h, w.wt0r_l,
                                          att0, b0, 1, w.z_i, nullptr, nullptr, w, stream);
            run_group_fat_m<float, false>(srcA0_j, dstA0_j, rp_j, sr_j, rids_j, FD,
                                          w.wt0l_h, w.wt0l_l, w.wt0r_h, w.wt0r_l,
                                          att0, b0, 1, w.z_j, nullptr, nullptr, w, stream);
            run_group_fat_m<unsigned short, true>(srcA1_i, dstA1_i, rp_i, sr_i, rids_i, CD,
                                                  w.wt1l_h, w.wt1l_l, w.wt1r_h, w.wt1r_l,
                                                  att1, b1, 2, nullptr, batch_i, w.pool_i, w, stream);
            pool_reduce<<<BG, 512, 0, stream>>>(w.acc, batch_i, w.pool_i);
            run_group_fat_m<unsigned short, true>(srcA1_j, dstA1_j, rp_j, sr_j, rids_j, CD,
                                                  w.wt1l_h, w.wt1l_l, w.wt1r_h, w.wt1r_l,
                                                  att1, b1, 2, nullptr, batch_j, w.pool_j, w, stream);
            pool_reduce<<<BG, 512, 0, stream>>>(w.acc, batch_j, w.pool_j);
        } else {
            run_group_fat_t<float, false>(srcA0_i, dstA0_i, rp_i, sr_i, rids_i, FD,
                                          w.wt0l_h, w.wt0l_l, w.wt0r_h, w.wt0r_l,
                                          att0, b0, 1, w.z_i, nullptr, nullptr, w, stream);
            run_group_fat_t<float, false>(srcA0_j, dstA0_j, rp_j, sr_j, rids_j, FD,
                                          w.wt0l_h, w.wt0l_l, w.wt0r_h, w.wt0r_l,
                                          att0, b0, 1, w.z_j, nullptr, nullptr, w, stream);
            run_group_fat_t<unsigned short, true>(srcA1_i, dstA1_i, rp_i, sr_i, rids_i, CD,
                                                  w.wt1l_h, w.wt1l_l, w.wt1r_h, w.wt1r_l,
                                                  att1, b1, 2, nullptr, batch_i, w.pool_i, w, stream);
            pool_reduce<<<BG, 512, 0, stream>>>(w.acc, batch_i, w.pool_i);
            run_group_fat_t<unsigned short, true>(srcA1_j, dstA1_j, rp_j, sr_j, rids_j, CD,
                                                  w.wt1l_h, w.wt1l_l, w.wt1r_h, w.wt1r_l,
                                                  att1, b1, 2, nullptr, batch_j, w.pool_j, w, stream);
            pool_reduce<<<BG, 512, 0, stream>>>(w.acc, batch_j, w.pool_j);
        }
    } else if (fat) {
        if (ncsr == 4) {
            for (int r = 0; r < 4; ++r)
                build_csr(eis_all[r], w.rowptr[r], w.srcs[r], w.cnt, w.cursor, stream);
            const int* rp_i[2] = { w.rowptr[0], w.rowptr[3] };
            const unsigned short* sr_i[2] = { w.srcs[0], w.srcs[3] };
            const int* rp_j[2] = { w.rowptr[1], w.rowptr[2] };
            const unsigned short* sr_j[2] = { w.srcs[1], w.srcs[2] };
            run_group_fat<float, false>(srcA0_i, dstA0_i, rp_i, sr_i, rids_i, FD,
                                        Wl0, Wr0, att0, b0, 1, w.z_i, nullptr, nullptr, w, stream);
            run_group_fat<float, false>(srcA0_j, dstA0_j, rp_j, sr_j, rids_j, FD,
                                        Wl0, Wr0, att0, b0, 1, w.z_j, nullptr, nullptr, w, stream);
            run_group_fat<unsigned short, true>(srcA1_i, dstA1_i, rp_i, sr_i, rids_i, CD,
                                                Wl1, Wr1, att1, b1, 2, nullptr, batch_i, w.pool_i, w, stream);
            pool_reduce<<<BG, 512, 0, stream>>>(w.acc, batch_i, w.pool_i);
            run_group_fat<unsigned short, true>(srcA1_j, dstA1_j, rp_j, sr_j, rids_j, CD,
                                                Wl1, Wr1, att1, b1, 2, nullptr, batch_j, w.pool_j, w, stream);
            pool_reduce<<<BG, 512, 0, stream>>>(w.acc, batch_j, w.pool_j);
        } else {
            for (int pass = 0; pass < 4; ++pass) {
                const int* rids = (pass & 1) ? rids_j : rids_i;
                for (int q = 0; q < 2; ++q) {
                    int r = rids[q];
                    build_csr(eis_all[r], w.rowptr[0], w.srcs[0], w.cnt, w.cursor, stream);
                    dim3 gg(HHD / 64, (NN + 63) / 64, 2);
                    if (pass < 2) {
                        const float* sa = (pass == 0) ? srcA0_i[q] : srcA0_j[q];
                        const float* da = (pass == 0) ? dstA0_i[q] : dstA0_j[q];
                        gemm_mfma<float, false><<<gg, 256, 0, stream>>>(
                            sa, da, Wl0 + (size_t)r * FD * HHD, Wr0 + (size_t)r * FD * HHD,
                            HHD, w.xl, w.xr, NN, FD, HHD);
                        fused_aggr4<<<NN / 4, 256, 0, stream>>>(
                            w.rowptr[0], w.srcs[0], w.xl, w.xr, att0 + (size_t)r * HHD,
                            w.acc, q, (q == 1) ? 1 : 0,
                            b0 + (size_t)rids[0] * HHD, b0 + (size_t)rids[1] * HHD,
                            (pass == 0) ? w.z_i : w.z_j, nullptr, nullptr);
                    } else {
                        const unsigned short* sa = (pass == 2) ? srcA1_i[q] : srcA1_j[q];
                        const unsigned short* da = (pass == 2) ? dstA1_i[q] : dstA1_j[q];
                        gemm_mfma<unsigned short, true><<<gg, 256, 0, stream>>>(
                            sa, da, Wl1 + (size_t)r * CD * HHD, Wr1 + (size_t)r * CD * HHD,
                            HHD, w.xl, w.xr, NN, CD, HHD);
                        fused_aggr4<<<NN / 4, 256, 0, stream>>>(
                            w.rowptr[0], w.srcs[0], w.xl, w.xr, att1 + (size_t)r * HHD,
                            w.acc, q, (q == 1) ? 2 : 0,
                            b1 + (size_t)rids[0] * HHD, b1 + (size_t)rids[1] * HHD,
                            nullptr, (pass == 2) ? batch_i : batch_j,
                            (pass == 2) ? w.pool_i : w.pool_j);
                    }
                }
                if (pass == 2)
                    pool_reduce<<<BG, 512, 0, stream>>>(w.acc, batch_i, w.pool_i);
                else if (pass == 3)
                    pool_reduce<<<BG, 512, 0, stream>>>(w.acc, batch_j, w.pool_j);
            }
        }
    } else {
        const int* eis_i[2] = { ei_ii, ei_ji };
        const int* eis_j[2] = { ei_jj, ei_ij };
        run_group_thin<float, false>(srcA0_i, dstA0_i, eis_i, rids_i, FD, Wl0, Wr0, att0, b0,
                                     1, w.z_i, nullptr, nullptr, w, stream);
        run_group_thin<float, false>(srcA0_j, dstA0_j, eis_j, rids_j, FD, Wl0, Wr0, att0, b0,
                                     1, w.z_j, nullptr, nullptr, w, stream);
        run_group_thin<unsigned short, true>(srcA1_i, dstA1_i, eis_i, rids_i, CD, Wl1, Wr1, att1, b1,
                                             2, nullptr, batch_i, w.pool_i, w, stream);
        run_group_thin<unsigned short, true>(srcA1_j, dstA1_j, eis_j, rids_j, CD, Wl1, Wr1, att1, b1,
                                             2, nullptr, batch_j, w.pool_j, w, stream);
    }

    head_kernel<<<BG, 128, 0, stream>>>(w.pool_i, w.pool_j, W_out, b_out,
                                        W_i, b_i, W_j, b_j, out);
}

// Round 5
// 1351.905 us; speedup vs baseline: 1.4415x; 1.0459x over previous
//
#include <hip/hip_runtime.h>

// ---------------- problem constants ----------------
#define NN      20000     // nodes per type
#define EE      320000    // edges per relation
#define ETOT    340000    // EE + NN self loops
#define FD      512       // raw feature dim
#define HH_     4         // heads
#define CD      128       // channels per head
#define HHD     512       // H*C
#define BG      64        // batch graphs
#define INNERD  64

typedef __attribute__((ext_vector_type(8))) short bf16x8;
typedef __attribute__((ext_vector_type(4))) float f32x4;

// ---- bf16 <-> f32 via raw bits ----
__device__ __forceinline__ float bf2f(unsigned v) { return __uint_as_float(v << 16); }
__device__ __forceinline__ unsigned short f2bf(float f) {
    unsigned u = __float_as_uint(f);
    unsigned r = 0x7fffu + ((u >> 16) & 1u);
    return (unsigned short)((u + r) >> 16);
}
__device__ __forceinline__ void load8bf(const unsigned short* p, float* f) {
    uint4 u = *reinterpret_cast<const uint4*>(p);
    f[0] = bf2f(u.x & 0xffffu); f[1] = bf2f(u.x >> 16);
    f[2] = bf2f(u.y & 0xffffu); f[3] = bf2f(u.y >> 16);
    f[4] = bf2f(u.z & 0xffffu); f[5] = bf2f(u.z >> 16);
    f[6] = bf2f(u.w & 0xffffu); f[7] = bf2f(u.w >> 16);
}
// fast split f32 -> hi + lo bf16 (truncation; residual ~2^-16 relative)
__device__ __forceinline__ void split_f32(float x, unsigned short& hi, unsigned short& lo) {
    unsigned u = __float_as_uint(x);
    hi = (unsigned short)(u >> 16);
    float r = x - bf2f(hi);
    lo = (unsigned short)(__float_as_uint(r) >> 16);
}
template <typename TA>
__device__ __forceinline__ void splitA(const TA* p, size_t i, unsigned short& hi, unsigned short& lo);
template <>
__device__ __forceinline__ void splitA<float>(const float* p, size_t i, unsigned short& hi, unsigned short& lo) {
    split_f32(p[i], hi, lo);
}
template <>
__device__ __forceinline__ void splitA<unsigned short>(const unsigned short* p, size_t i, unsigned short& hi, unsigned short& lo) {
    hi = p[i]; lo = 0;
}

// ================= CSR build (per-relation kernels, fallback paths) =================
__global__ __launch_bounds__(256) void csr_hist(const int* __restrict__ ei, int* __restrict__ cnt) {
    int e = blockIdx.x * blockDim.x + threadIdx.x;
    if (e < EE) atomicAdd(&cnt[ei[EE + e]], 1);
}

__global__ __launch_bounds__(1024) void csr_scan(const int* __restrict__ cnt,
                                                 int* __restrict__ rowptr,
                                                 int* __restrict__ cursor) {
    __shared__ int part[1024];
    int t = threadIdx.x;
    int base = t * 20;
    int s = 0;
    #pragma unroll
    for (int i = 0; i < 20; ++i) { int n = base + i; if (n < NN) s += cnt[n] + 1; }
    part[t] = s;
    __syncthreads();
    for (int off = 1; off < 1024; off <<= 1) {
        int v = (t >= off) ? part[t - off] : 0;
        __syncthreads();
        part[t] += v;
        __syncthreads();
    }
    int run = (t > 0) ? part[t - 1] : 0;
    #pragma unroll
    for (int i = 0; i < 20; ++i) {
        int n = base + i;
        if (n < NN) { rowptr[n] = run; cursor[n] = run; run += cnt[n] + 1; }
    }
    if (t == 1023) rowptr[NN] = run;
}

__global__ __launch_bounds__(256) void csr_scatter16(const int* __restrict__ ei,
                                                     int* __restrict__ cursor,
                                                     unsigned short* __restrict__ srcs) {
    int idx = blockIdx.x * blockDim.x + threadIdx.x;
    if (idx >= ETOT) return;
    int src, dst;
    if (idx < EE) { src = ei[idx]; dst = ei[EE + idx]; }
    else          { src = dst = idx - EE; }
    int pos = atomicAdd(&cursor[dst], 1);
    srcs[pos] = (unsigned short)src;
}

// ================= merged CSR build: ALL 4 relations in 3 dispatches ================
__global__ __launch_bounds__(256) void csr_hist4(
    const int* __restrict__ e0, const int* __restrict__ e1,
    const int* __restrict__ e2, const int* __restrict__ e3,
    int* __restrict__ cnt)
{
    int idx = blockIdx.x * blockDim.x + threadIdx.x;
    if (idx >= 4 * EE) return;
    int r = idx / EE, e = idx - r * EE;
    const int* ei = r == 0 ? e0 : r == 1 ? e1 : r == 2 ? e2 : e3;
    atomicAdd(&cnt[r * NN + ei[EE + e]], 1);
}

__global__ __launch_bounds__(1024) void csr_scan4(const int* __restrict__ cnt_all,
                                                  int* __restrict__ rowptr_all,
                                                  int* __restrict__ cursor_all)
{
    const int r = blockIdx.x;
    const int* cnt = cnt_all + r * NN;
    int* rowptr = rowptr_all + r * (NN + 4);
    int* cursor = cursor_all + r * NN;
    __shared__ int part[1024];
    int t = threadIdx.x;
    int base = t * 20;
    int s = 0;
    #pragma unroll
    for (int i = 0; i < 20; ++i) { int n = base + i; if (n < NN) s += cnt[n] + 1; }
    part[t] = s;
    __syncthreads();
    for (int off = 1; off < 1024; off <<= 1) {
        int v = (t >= off) ? part[t - off] : 0;
        __syncthreads();
        part[t] += v;
        __syncthreads();
    }
    int run = (t > 0) ? part[t - 1] : 0;
    #pragma unroll
    for (int i = 0; i < 20; ++i) {
        int n = base + i;
        if (n < NN) { rowptr[n] = run; cursor[n] = run; run += cnt[n] + 1; }
    }
    if (t == 1023) rowptr[NN] = run;
}

__global__ __launch_bounds__(256) void csr_scatter4(
    const int* __restrict__ e0, const int* __restrict__ e1,
    const int* __restrict__ e2, const int* __restrict__ e3,
    int* __restrict__ cursor_all, unsigned short* __restrict__ srcs_all)
{
    int idx = blockIdx.x * blockDim.x + threadIdx.x;
    if (idx >= 4 * ETOT) return;
    int r = idx / ETOT, t = idx - r * ETOT;
    const int* ei = r == 0 ? e0 : r == 1 ? e1 : r == 2 ? e2 : e3;
    int src, dst;
    if (t < EE) { src = ei[t]; dst = ei[EE + t]; }
    else        { src = dst = t - EE; }
    int pos = atomicAdd(&cursor_all[r * NN + dst], 1);
    srcs_all[(size_t)r * ETOT + pos] = (unsigned short)src;
}

// ================= W pre-split: [R][K][512] f32 -> hi/lo FRAGMENT-TILED bf16 =========
// Output layout per relation: [K/32][N=512][32] — the exact per-lane MFMA B-fragment
// order, so the GEMM reads B directly from L2 (dense 1KB/wave/instr), no LDS staging.
__global__ __launch_bounds__(256) void wsplit_t(const float* __restrict__ W,
                                                unsigned short* __restrict__ Whi,
                                                unsigned short* __restrict__ Wlo,
                                                int K)
{
    __shared__ float tile[64][65];
    const int nt = 512 / 64;
    const int kt = K / 64;
    int bid = blockIdx.x;
    int in = bid % nt; int ik = (bid / nt) % kt; int r = bid / (nt * kt);
    int t = threadIdx.x;
    const float* Wr_ = W + (size_t)r * K * 512;
    #pragma unroll
    for (int rep = 0; rep < 16; ++rep) {
        int idx = rep * 256 + t;
        int kk = idx >> 6, nn = idx & 63;
        tile[kk][nn] = Wr_[(size_t)(ik * 64 + kk) * 512 + in * 64 + nn];
    }
    __syncthreads();
    #pragma unroll
    for (int rep = 0; rep < 16; ++rep) {
        int idx = rep * 256 + t;
        int nn = idx >> 6, kk = idx & 63;
        unsigned short h, l; split_f32(tile[kk][nn], h, l);
        int n = in * 64 + nn;
        int k = ik * 64 + kk;
        size_t o = (size_t)r * 512 * K + ((size_t)(k >> 5) * 512 + n) * 32 + (k & 31);
        Whi[o] = h; Wlo[o] = l;
    }
}

// ================= 128x128 split-bf16 MFMA GEMM core (B direct-from-L2) =============
template <typename TA, bool A_EXACT>
__device__ __forceinline__ void gemm_body(
    const TA* __restrict__ A, const unsigned short* __restrict__ Bhg,
    const unsigned short* __restrict__ Blg, unsigned short* __restrict__ C,
    int bx, int by, int M, int K, int N)
{
    __shared__ unsigned short Ah[128][40];
    __shared__ unsigned short Al[A_EXACT ? 1 : 128][40];

    const int tid = threadIdx.x;
    const int wave = tid >> 6, lane = tid & 63;
    const int quad = lane >> 4, lrow = lane & 15;
    const int wr = (wave >> 1) * 64, wc = (wave & 1) * 64;
    const int tileM = by * 128, tileN = bx * 128;

    const int srow = tid >> 1;
    const int sks  = (tid & 1) * 16;
    const int sgm  = tileM + srow;

    const size_t bfrag = ((size_t)(tileN + wc + lrow) << 5) + quad * 8;
    const size_t kblk  = (size_t)N << 5;

    f32x4 acc[4][4] = {};

    for (int k0 = 0; k0 < K; k0 += 32) {
        if constexpr (!A_EXACT) {
            bf16x8 ph[2] = {{}, {}}, pl[2] = {{}, {}};
            if (sgm < M) {
                const float* Ap = (const float*)A + (size_t)sgm * K + k0 + sks;
                #pragma unroll
                for (int s = 0; s < 2; ++s) {
                    float4 f0 = reinterpret_cast<const float4*>(Ap)[2 * s];
                    float4 f1 = reinterpret_cast<const float4*>(Ap)[2 * s + 1];
                    float xv[8] = {f0.x, f0.y, f0.z, f0.w, f1.x, f1.y, f1.z, f1.w};
                    #pragma unroll
                    for (int pp = 0; pp < 4; ++pp) {
                        unsigned u0 = __float_as_uint(xv[2 * pp]);
                        unsigned u1 = __float_as_uint(xv[2 * pp + 1]);
                        reinterpret_cast<unsigned*>(&ph[s])[pp] =
                            __builtin_amdgcn_perm(u1, u0, 0x07060302u);
                        float r0 = xv[2 * pp]     - __uint_as_float(u0 & 0xffff0000u);
                        float r1 = xv[2 * pp + 1] - __uint_as_float(u1 & 0xffff0000u);
                        reinterpret_cast<unsigned*>(&pl[s])[pp] =
                            __builtin_amdgcn_perm(__float_as_uint(r1), __float_as_uint(r0), 0x07060302u);
                    }
                }
            }
            *reinterpret_cast<bf16x8*>(&Ah[srow][sks])     = ph[0];
            *reinterpret_cast<bf16x8*>(&Ah[srow][sks + 8]) = ph[1];
            *reinterpret_cast<bf16x8*>(&Al[srow][sks])     = pl[0];
            *reinterpret_cast<bf16x8*>(&Al[srow][sks + 8]) = pl[1];
        } else {
            bf16x8 v0 = {}, v1 = {};
            if (sgm < M) {
                const unsigned short* Ap = (const unsigned short*)A + (size_t)sgm * K + k0 + sks;
                v0 = reinterpret_cast<const bf16x8*>(Ap)[0];
                v1 = reinterpret_cast<const bf16x8*>(Ap)[1];
            }
            *reinterpret_cast<bf16x8*>(&Ah[srow][sks])     = v0;
            *reinterpret_cast<bf16x8*>(&Ah[srow][sks + 8]) = v1;
        }
        bf16x8 bh[4], bl[4];
        {
            const unsigned short* Bb = Bhg + (size_t)(k0 >> 5) * kblk + bfrag;
            const unsigned short* Bc = Blg + (size_t)(k0 >> 5) * kblk + bfrag;
            #pragma unroll
            for (int ni = 0; ni < 4; ++ni) {
                bh[ni] = *reinterpret_cast<const bf16x8*>(Bb + ((size_t)ni << 9));
                bl[ni] = *reinterpret_cast<const bf16x8*>(Bc + ((size_t)ni << 9));
            }
        }
        __syncthreads();
        bf16x8 ah[4], al[4];
        #pragma unroll
        for (int mi = 0; mi < 4; ++mi) {
            ah[mi] = *reinterpret_cast<const bf16x8*>(&Ah[wr + mi * 16 + lrow][quad * 8]);
            if constexpr (!A_EXACT)
                al[mi] = *reinterpret_cast<const bf16x8*>(&Al[wr + mi * 16 + lrow][quad * 8]);
        }
        #pragma unroll
        for (int mi = 0; mi < 4; ++mi)
            #pragma unroll
            for (int ni = 0; ni < 4; ++ni) {
                acc[mi][ni] = __builtin_amdgcn_mfma_f32_16x16x32_bf16(
                    ah[mi], bh[ni], acc[mi][ni], 0, 0, 0);
                acc[mi][ni] = __builtin_amdgcn_mfma_f32_16x16x32_bf16(
                    ah[mi], bl[ni], acc[mi][ni], 0, 0, 0);
                if constexpr (!A_EXACT)
                    acc[mi][ni] = __builtin_amdgcn_mfma_f32_16x16x32_bf16(
                        al[mi], bh[ni], acc[mi][ni], 0, 0, 0);
            }
        __syncthreads();
    }
    #pragma unroll
    for (int mi = 0; mi < 4; ++mi) {
        #pragma unroll
        for (int ni = 0; ni < 4; ++ni) {
            int gcol = tileN + wc + ni * 16 + lrow;
            #pragma unroll
            for (int r = 0; r < 4; ++r) {
                int grow = tileM + wr + mi * 16 + quad * 4 + r;
                if (grow < M)
                    C[(size_t)grow * N + gcol] = f2bf(acc[mi][ni][r]);
            }
        }
    }
}

// z=2 variant (fat_t fallback path)
template <typename TA, bool A_EXACT>
__global__ __launch_bounds__(256, 3) void gemm_mfma_t(
    const TA* __restrict__ A0, const TA* __restrict__ A1,
    const unsigned short* __restrict__ B0h, const unsigned short* __restrict__ B0l,
    const unsigned short* __restrict__ B1h, const unsigned short* __restrict__ B1l,
    unsigned short* __restrict__ C0, unsigned short* __restrict__ C1,
    int M, int K, int N)
{
    const int gx = gridDim.x, gy = gridDim.y;
    const int nwg = gx * gy * (int)gridDim.z;
    int b = ((int)blockIdx.z * gy + blockIdx.y) * gx + blockIdx.x;
    int xcd = b & 7, q8 = nwg >> 3, r8 = nwg & 7;
    int work = (xcd < r8 ? xcd * (q8 + 1) : r8 * (q8 + 1) + (xcd - r8) * q8) + (b >> 3);
    int bx = work % gx; int t2 = work / gx; int by = t2 % gy; int bz = t2 / gy;

    const TA* A = bz ? A1 : A0;
    const unsigned short* Bhg = bz ? B1h : B0h;
    const unsigned short* Blg = bz ? B1l : B0l;
    unsigned short* C = bz ? C1 : C0;
    gemm_body<TA, A_EXACT>(A, Bhg, Blg, C, bx, by, M, K, N);
}

// z=4 variant (merged path: one dispatch covers both relations of a group)
template <typename TA, bool A_EXACT>
__global__ __launch_bounds__(256, 3) void gemm_mfma_t4(
    const TA* __restrict__ A0, const TA* __restrict__ A1,
    const TA* __restrict__ A2, const TA* __restrict__ A3,
    const unsigned short* __restrict__ B0h, const unsigned short* __restrict__ B0l,
    const unsigned short* __restrict__ B1h, const unsigned short* __restrict__ B1l,
    const unsigned short* __restrict__ B2h, const unsigned short* __restrict__ B2l,
    const unsigned short* __restrict__ B3h, const unsigned short* __restrict__ B3l,
    unsigned short* __restrict__ C0, unsigned short* __restrict__ C1,
    unsigned short* __restrict__ C2, unsigned short* __restrict__ C3,
    int M, int K, int N)
{
    const int gx = gridDim.x, gy = gridDim.y;
    const int nwg = gx * gy * (int)gridDim.z;
    int b = ((int)blockIdx.z * gy + blockIdx.y) * gx + blockIdx.x;
    int xcd = b & 7, q8 = nwg >> 3, r8 = nwg & 7;
    int work = (xcd < r8 ? xcd * (q8 + 1) : r8 * (q8 + 1) + (xcd - r8) * q8) + (b >> 3);
    int bx = work % gx; int t2 = work / gx; int by = t2 % gy; int bz = t2 / gy;

    const TA* A = bz == 0 ? A0 : bz == 1 ? A1 : bz == 2 ? A2 : A3;
    const unsigned short* Bhg = bz == 0 ? B0h : bz == 1 ? B1h : bz == 2 ? B2h : B3h;
    const unsigned short* Blg = bz == 0 ? B0l : bz == 1 ? B1l : bz == 2 ? B2l : B3l;
    unsigned short* C = bz == 0 ? C0 : bz == 1 ? C1 : bz == 2 ? C2 : C3;
    gemm_body<TA, A_EXACT>(A, Bhg, Blg, C, bx, by, M, K, N);
}

// ================= OLD 64x64 split-bf16 GEMM (deep fallback; raw f32 W) =============
template <typename TA, bool A_EXACT>
__global__ __launch_bounds__(256) void gemm_mfma(
    const TA* __restrict__ A0, const TA* __restrict__ A1,
    const float* __restrict__ B0, const float* __restrict__ B1, int ldb,
    unsigned short* __restrict__ C0, unsigned short* __restrict__ C1,
    int M, int K, int N)
{
    const TA* A = blockIdx.z ? A1 : A0;
    const float* B = blockIdx.z ? B1 : B0;
    unsigned short* C = blockIdx.z ? C1 : C0;

    __shared__ unsigned short Ah[64][40];
    __shared__ unsigned short Al[64][40];
    __shared__ unsigned short Bh[64][40];
    __shared__ unsigned short Bl[64][40];
    const int tid = threadIdx.x;
    const int wave = tid >> 6, lane = tid & 63;
    const int quad = lane >> 4, lrow = lane & 15;
    const int tileM = blockIdx.y * 64, tileN = blockIdx.x * 64;
    const int wm = (wave >> 1) * 32, wn = (wave & 1) * 32;

    f32x4 acc[2][2] = {};

    const int am = tid >> 2;
    const int aks = (tid & 3) * 8;
    const int bn = tid & 63;
    const int bk0 = (tid >> 6) * 8;

    for (int k0 = 0; k0 < K; k0 += 32) {
        {
            int gm = tileM + am;
            bf16x8 ph = {}, pl = {};
            if (gm < M) {
                #pragma unroll
                for (int j = 0; j < 8; ++j) {
                    unsigned short h, l;
                    splitA(A, (size_t)gm * K + k0 + aks + j, h, l);
                    ph[j] = (short)h; pl[j] = (short)l;
                }
            }
            *reinterpret_cast<bf16x8*>(&Ah[am][aks]) = ph;
            if (!A_EXACT) *reinterpret_cast<bf16x8*>(&Al[am][aks]) = pl;
        }
        {
            bf16x8 ph, pl;
            #pragma unroll
            for (int j = 0; j < 8; ++j) {
                unsigned short h, l;
                split_f32(B[(size_t)(k0 + bk0 + j) * ldb + tileN + bn], h, l);
                ph[j] = (short)h; pl[j] = (short)l;
            }
            *reinterpret_cast<bf16x8*>(&Bh[bn][bk0]) = ph;
            *reinterpret_cast<bf16x8*>(&Bl[bn][bk0]) = pl;
        }
        __syncthreads();
        bf16x8 ah[2], al[2], bh[2], bl[2];
        #pragma unroll
        for (int mi = 0; mi < 2; ++mi) {
            ah[mi] = *reinterpret_cast<const bf16x8*>(&Ah[wm + mi * 16 + lrow][quad * 8]);
            if (!A_EXACT)
                al[mi] = *reinterpret_cast<const bf16x8*>(&Al[wm + mi * 16 + lrow][quad * 8]);
        }
        #pragma unroll
        for (int ni = 0; ni < 2; ++ni) {
            bh[ni] = *reinterpret_cast<const bf16x8*>(&Bh[wn + ni * 16 + lrow][quad * 8]);
            bl[ni] = *reinterpret_cast<const bf16x8*>(&Bl[wn + ni * 16 + lrow][quad * 8]);
        }
        #pragma unroll
        for (int mi = 0; mi < 2; ++mi)
            #pragma unroll
            for (int ni = 0; ni < 2; ++ni) {
                acc[mi][ni] = __builtin_amdgcn_mfma_f32_16x16x32_bf16(
                    ah[mi], bh[ni], acc[mi][ni], 0, 0, 0);
                acc[mi][ni] = __builtin_amdgcn_mfma_f32_16x16x32_bf16(
                    ah[mi], bl[ni], acc[mi][ni], 0, 0, 0);
                if (!A_EXACT)
                    acc[mi][ni] = __builtin_amdgcn_mfma_f32_16x16x32_bf16(
                        al[mi], bh[ni], acc[mi][ni], 0, 0, 0);
            }
        __syncthreads();
    }
    #pragma unroll
    for (int mi = 0; mi < 2; ++mi) {
        #pragma unroll
        for (int ni = 0; ni < 2; ++ni) {
            int gcol = tileN + wn + ni * 16 + lrow;
            #pragma unroll
            for (int r = 0; r < 4; ++r) {
                int grow = tileM + wm + mi * 16 + quad * 4 + r;
                if (grow < M)
                    C[(size_t)grow * N + gcol] = f2bf(acc[mi][ni][r]);
            }
        }
    }
}

// ================= THIN: fused GATv2 pass, one head (deep fallback) =================
__global__ __launch_bounds__(256) void fused_aggr1(
    const int* __restrict__ rowptr, const unsigned short* __restrict__ srcs,
    const unsigned short* __restrict__ xl, const unsigned short* __restrict__ xr,
    const float* __restrict__ att,
    float* __restrict__ acc, int add_in, int fin_mode,
    const float* __restrict__ bA, const float* __restrict__ bB,
    unsigned short* __restrict__ z,
    const int* __restrict__ batch, float* __restrict__ pool)
{
    int dst = (int)((blockIdx.x * (size_t)blockDim.x + threadIdx.x) >> 6);
    int lane = threadIdx.x & 63;
    if (dst >= NN) return;
    int beg = rowptr[dst], end = rowptr[dst + 1];

    unsigned ub = *reinterpret_cast<const unsigned*>(xr + (size_t)dst * CD + lane * 2);
    float br0 = bf2f(ub & 0xffffu), br1 = bf2f(ub >> 16);
    float ta0 = att[lane * 2], ta1 = att[lane * 2 + 1];

    float n0 = 0.f, n1 = 0.f, den = 0.f;
    for (int k = beg; k < end; ++k) {
        int src = srcs[k];
        unsigned ua = *reinterpret_cast<const unsigned*>(xl + (size_t)src * CD + lane * 2);
        float a0 = bf2f(ua & 0xffffu), a1 = bf2f(ua >> 16);
        float v0 = a0 + br0, v1 = a1 + br1;
        v0 = (v0 > 0.f) ? v0 : 0.2f * v0;
        v1 = (v1 > 0.f) ? v1 : 0.2f * v1;
        float d = v0 * ta0 + v1 * ta1;
        #pragma unroll
        for (int off = 1; off < 64; off <<= 1)
            d += __shfl_xor(d, off);
        float p = expf(d);
        n0 += p * a0; n1 += p * a1; den += p;
    }
    float o0 = n0 / den, o1 = n1 / den;
    size_t ai = (size_t)dst * CD + lane * 2;
    if (add_in) { o0 += acc[ai]; o1 += acc[ai + 1]; }
    if (fin_mode == 0) {
        acc[ai] = o0; acc[ai + 1] = o1;
    } else {
        int c0 = lane * 2;
        float bb0 = 0.f, bb1 = 0.f;
        #pragma unroll
        for (int h = 0; h < HH_; ++h) {
            bb0 += bA[h * CD + c0]     + bB[h * CD + c0];
            bb1 += bA[h * CD + c0 + 1] + bB[h * CD + c0 + 1];
        }
        o0 = tanhf(o0 + bb0);
        o1 = tanhf(o1 + bb1);
        if (fin_mode == 1) {
            z[ai] = f2bf(o0); z[ai + 1] = f2bf(o1);
        } else {
            int b = batch[dst];
            atomicAdd(&pool[(size_t)b * CD + c0],     o0);
            atomicAdd(&pool[(size_t)b * CD + c0 + 1], o1);
        }
    }
}

// ================= GATv2 aggregation helpers =================
__device__ __forceinline__ float edge_logit(const float* a, const float* br, const float* ta) {
    float d = 0.f;
    #pragma unroll
    for (int j = 0; j < 8; ++j) {
        float v = a[j] + br[j];
        v = fmaxf(v, 0.2f * v);
        d += v * ta[j];
    }
    return d;
}
__device__ __forceinline__ float quad_reduce(float d) {
    d += __shfl_xor(d, 1);
    d += __shfl_xor(d, 2);
    d += __shfl_xor(d, 4);
    d += __shfl_xor(d, 8);
    return d;
}
// drain [k,e) edges of one relation (2x unrolled + tail); k-order accumulation
__device__ __forceinline__ void gat_drain(
    const unsigned short* __restrict__ sr, const unsigned short* __restrict__ xl,
    const float* br, const float* ta, int k, int e, float* n, float& den, int lane)
{
    for (; k + 2 <= e; k += 2) {
        int s0 = sr[k], s1 = sr[k + 1];
        float A0[8], A1[8];
        load8bf(xl + (size_t)s0 * HHD + lane * 8, A0);
        load8bf(xl + (size_t)s1 * HHD + lane * 8, A1);
        float d0 = quad_reduce(edge_logit(A0, br, ta));
        float d1 = quad_reduce(edge_logit(A1, br, ta));
        float p0 = __expf(d0), p1 = __expf(d1);
        den += p0;
        #pragma unroll
        for (int j = 0; j < 8; ++j) n[j] += p0 * A0[j];
        den += p1;
        #pragma unroll
        for (int j = 0; j < 8; ++j) n[j] += p1 * A1[j];
    }
    if (k < e) {
        int s0 = sr[k];
        float A0[8];
        load8bf(xl + (size_t)s0 * HHD + lane * 8, A0);
        float d0 = quad_reduce(edge_logit(A0, br, ta));
        float p0 = __expf(d0);
        den += p0;
        #pragma unroll
        for (int j = 0; j < 8; ++j) n[j] += p0 * A0[j];
    }
}

// single-relation pass (fallback)
__device__ __forceinline__ void gat_rel(
    const int* __restrict__ rp, const unsigned short* __restrict__ sr,
    const unsigned short* __restrict__ xl, const unsigned short* __restrict__ xr,
    const float* __restrict__ att, int dst, int lane, float* o)
{
    int beg = rp[dst], end = rp[dst + 1];
    float br[8], ta[8];
    load8bf(xr + (size_t)dst * HHD + lane * 8, br);
    #pragma unroll
    for (int j = 0; j < 8; ++j) ta[j] = att[lane * 8 + j];
    float n[8] = {}; float den = 0.f;
    gat_drain(sr, xl, br, ta, beg, end, n, den, lane);
    float inv = 1.f / den;
    #pragma unroll
    for (int j = 0; j < 8; ++j) {
        o[j] = n[j] * inv;
        o[j] += __shfl_xor(o[j], 16);
        o[j] += __shfl_xor(o[j], 32);
    }
}

// DUAL-relation pass: interleave both relations' edge loops -> 4 gathers in flight
// (R3 profile: VALUBusy 67%, rest latency-exposed; 2-deep ILP was not enough).
// Per-relation accumulation order is unchanged -> numerically identical.
__device__ __forceinline__ void gat_rel2(
    const int* __restrict__ rp0, const unsigned short* __restrict__ sr0,
    const unsigned short* __restrict__ xl0, const unsigned short* __restrict__ xr0,
    const float* __restrict__ attA,
    const int* __restrict__ rp1, const unsigned short* __restrict__ sr1,
    const unsigned short* __restrict__ xl1, const unsigned short* __restrict__ xr1,
    const float* __restrict__ attB,
    int dst, int lane, float* o0, float* o1)
{
    int k0 = rp0[dst], e0 = rp0[dst + 1];
    int k1 = rp1[dst], e1 = rp1[dst + 1];
    float br0[8], br1[8], ta0[8], ta1[8];
    load8bf(xr0 + (size_t)dst * HHD + lane * 8, br0);
    load8bf(xr1 + (size_t)dst * HHD + lane * 8, br1);
    #pragma unroll
    for (int j = 0; j < 8; ++j) { ta0[j] = attA[lane * 8 + j]; ta1[j] = attB[lane * 8 + j]; }

    float n0[8] = {}, n1[8] = {};
    float den0 = 0.f, den1 = 0.f;

    while (k0 + 2 <= e0 && k1 + 2 <= e1) {
        int sa0 = sr0[k0], sa1 = sr0[k0 + 1];
        int sb0 = sr1[k1], sb1 = sr1[k1 + 1];
        float A0[8], A1[8], B0[8], B1[8];
        load8bf(xl0 + (size_t)sa0 * HHD + lane * 8, A0);
        load8bf(xl0 + (size_t)sa1 * HHD + lane * 8, A1);
        load8bf(xl1 + (size_t)sb0 * HHD + lane * 8, B0);
        load8bf(xl1 + (size_t)sb1 * HHD + lane * 8, B1);
        float dA0 = quad_reduce(edge_logit(A0, br0, ta0));
        float dA1 = quad_reduce(edge_logit(A1, br0, ta0));
        float dB0 = quad_reduce(edge_logit(B0, br1, ta1));
        float dB1 = quad_reduce(edge_logit(B1, br1, ta1));
        float pA0 = __expf(dA0), pA1 = __expf(dA1);
        float pB0 = __expf(dB0), pB1 = __expf(dB1);
        den0 += pA0;
        #pragma unroll
        for (int j = 0; j < 8; ++j) n0[j] += pA0 * A0[j];
        den0 += pA1;
        #pragma unroll
        for (int j = 0; j < 8; ++j) n0[j] += pA1 * A1[j];
        den1 += pB0;
        #pragma unroll
        for (int j = 0; j < 8; ++j) n1[j] += pB0 * B0[j];
        den1 += pB1;
        #pragma unroll
        for (int j = 0; j < 8; ++j) n1[j] += pB1 * B1[j];
        k0 += 2; k1 += 2;
    }
    gat_drain(sr0, xl0, br0, ta0, k0, e0, n0, den0, lane);
    gat_drain(sr1, xl1, br1, ta1, k1, e1, n1, den1, lane);

    float i0 = 1.f / den0, i1 = 1.f / den1;
    #pragma unroll
    for (int j = 0; j < 8; ++j) {
        o0[j] = n0[j] * i0;
        o0[j] += __shfl_xor(o0[j], 16);
        o0[j] += __shfl_xor(o0[j], 32);
        o1[j] = n1[j] * i1;
        o1[j] += __shfl_xor(o1[j], 16);
        o1[j] += __shfl_xor(o1[j], 32);
    }
}

// ================= FAT: single-relation pass (fat_t fallback) =================
__global__ __launch_bounds__(256) void fused_aggr4(
    const int* __restrict__ rowptr, const unsigned short* __restrict__ srcs,
    const unsigned short* __restrict__ xl, const unsigned short* __restrict__ xr,
    const float* __restrict__ att,
    float* __restrict__ acc, int add_in, int fin_mode,
    const float* __restrict__ bA, const float* __restrict__ bB,
    unsigned short* __restrict__ z,
    const int* __restrict__ batch, float* __restrict__ pool)
{
    int dst = (int)((blockIdx.x * (size_t)blockDim.x + threadIdx.x) >> 6);
    int lane = threadIdx.x & 63;
    if (dst >= NN) return;

    float o[8];
    gat_rel(rowptr, srcs, xl, xr, att, dst, lane, o);

    if (lane < 16) {
        size_t ai = (size_t)dst * CD + lane * 8;
        if (add_in) {
            #pragma unroll
            for (int j = 0; j < 8; ++j) o[j] += acc[ai + j];
        }
        if (fin_mode == 0) {
            #pragma unroll
            for (int j = 0; j < 8; ++j) acc[ai + j] = o[j];
        } else {
            int c0 = lane * 8;
            #pragma unroll
            for (int j = 0; j < 8; ++j) {
                float bb = 0.f;
                #pragma unroll
                for (int h = 0; h < HH_; ++h)
                    bb += bA[h * CD + c0 + j] + bB[h * CD + c0 + j];
                o[j] = tanhf(o[j] + bb);
            }
            if (fin_mode == 1) {
                #pragma unroll
                for (int j = 0; j < 8; ++j) z[ai + j] = f2bf(o[j]);
            } else {
                #pragma unroll
                for (int j = 0; j < 8; ++j) acc[ai + j] = o[j];
            }
        }
    }
}

// ================= FAT merged: BOTH relations of a group in one dispatch ============
__global__ __launch_bounds__(256) void fused_aggr4d(
    const int* __restrict__ rp0, const unsigned short* __restrict__ sr0,
    const unsigned short* __restrict__ xl0, const unsigned short* __restrict__ xr0,
    const float* __restrict__ attA,
    const int* __restrict__ rp1, const unsigned short* __restrict__ sr1,
    const unsigned short* __restrict__ xl1, const unsigned short* __restrict__ xr1,
    const float* __restrict__ attB,
    float* __restrict__ acc, int fin_mode,
    const float* __restrict__ bA, const float* __restrict__ bB,
    unsigned short* __restrict__ z,
    const int* __restrict__ batch, float* __restrict__ pool)
{
    int dst = (int)((blockIdx.x * (size_t)blockDim.x + threadIdx.x) >> 6);
    int lane = threadIdx.x & 63;
    if (dst >= NN) return;

    float o0[8], o1[8];
    gat_rel2(rp0, sr0, xl0, xr0, attA, rp1, sr1, xl1, xr1, attB, dst, lane, o0, o1);
    #pragma unroll
    for (int j = 0; j < 8; ++j) o1[j] += o0[j];

    if (lane < 16) {
        size_t ai = (size_t)dst * CD + lane * 8;
        int c0 = lane * 8;
        #pragma unroll
        for (int j = 0; j < 8; ++j) {
            float bb = 0.f;
            #pragma unroll
            for (int h = 0; h < HH_; ++h)
                bb += bA[h * CD + c0 + j] + bB[h * CD + c0 + j];
            o1[j] = tanhf(o1[j] + bb);
        }
        if (fin_mode == 1) {
            #pragma unroll
            for (int j = 0; j < 8; ++j) z[ai + j] = f2bf(o1[j]);
        } else {
            #pragma unroll
            for (int j = 0; j < 8; ++j) acc[ai + j] = o1[j];
        }
    }
}

// ================= pool_reduce: segmented sum over sorted batch (no atomics) ========
__global__ __launch_bounds__(512) void pool_reduce(
    const float* __restrict__ acc, const int* __restrict__ batch,
    float* __restrict__ pool)
{
    int b = blockIdx.x;
    int t = threadIdx.x & (CD - 1);
    int q = threadIdx.x >> 7;
    int lo, hi;
    { int l = 0, r = NN; while (l < r) { int m = (l + r) >> 1; if (batch[m] < b) l = m + 1; else r = m; } lo = l; }
    { int l = lo, r = NN; while (l < r) { int m = (l + r) >> 1; if (batch[m] <= b) l = m + 1; else r = m; } hi = l; }
    float s = 0.f;
    for (int nrow = lo + q; nrow < hi; nrow += 4)
        s += acc[(size_t)nrow * CD + t];
    __shared__ float red[4][CD];
    red[q][t] = s;
    __syncthreads();
    if (q == 0)
        pool[(size_t)b * CD + t] = red[0][t] + red[1][t] + red[2][t] + red[3][t];
}

// ================= head =================
__global__ __launch_bounds__(128) void head_kernel(
    const float* __restrict__ pool_i, const float* __restrict__ pool_j,
    const float* __restrict__ W_out, const float* __restrict__ b_out,
    const float* __restrict__ W_i, const float* __restrict__ b_i,
    const float* __restrict__ W_j, const float* __restrict__ b_j,
    float* __restrict__ out)
{
    int b = blockIdx.x;
    int t = threadIdx.x;
    __shared__ float pi[CD], pj[CD];
    pi[t] = tanhf(pool_i[(size_t)b * CD + t]);
    pj[t] = tanhf(pool_j[(size_t)b * CD + t]);
    __syncthreads();
    if (t < INNERD) {
        float a = b_i[t];
        for (int c = 0; c < CD; ++c) a += pi[c] * W_i[c * INNERD + t];
        out[BG + (size_t)b * INNERD + t] = a;
    } else {
        int k = t - INNERD;
        float a = b_j[k];
        for (int c = 0; c < CD; ++c) a += pj[c] * W_j[c * INNERD + k];
        out[BG + BG * INNERD + (size_t)b * INNERD + k] = a;
    }
    if (t == 0) {
        float a = b_out[0];
        for (int c = 0; c < CD; ++c) a += (pi[c] + pj[c]) * W_out[c];
        out[b] = 1.f / (1.f + expf(-a));
    }
}

// ================= host-side drivers =================
struct Ws {
    unsigned short *xl, *xr, *xl2, *xr2, *z_i, *z_j;
    float* acc;
    int *rowptr[4];
    unsigned short *srcs[4];
    int *cnt, *cursor;
    float *pool_i, *pool_j;
    unsigned short *wt0l_h, *wt0l_l, *wt0r_h, *wt0r_l;
    unsigned short *wt1l_h, *wt1l_l, *wt1r_h, *wt1r_l;
};

static void build_csr(const int* ei, int* rowptr, unsigned short* srcs,
                      int* cnt, int* cursor, hipStream_t stream) {
    hipMemsetAsync(cnt, 0, NN * sizeof(int), stream);
    csr_hist<<<(EE + 255) / 256, 256, 0, stream>>>(ei, cnt);
    csr_scan<<<1, 1024, 0, stream>>>(cnt, rowptr, cursor);
    csr_scatter16<<<(ETOT + 255) / 256, 256, 0, stream>>>(ei, cursor, srcs);
}

// ---- MERGED group pass: z=4 GEMM then one dual-relation aggr ----
template <typename TA, bool A_EXACT>
static void run_group_fat_m(const TA* srcA[2], const TA* dstA[2],
                            const int* rp[2], const unsigned short* sr[2],
                            const int rids[2], int K,
                            const unsigned short* WTl_h, const unsigned short* WTl_l,
                            const unsigned short* WTr_h, const unsigned short* WTr_l,
                            const float* att, const float* bias, int fin_mode,
                            unsigned short* zout, const int* batch, float* pool,
                            const Ws& w, hipStream_t stream)
{
    dim3 gg(HHD / 128, (NN + 127) / 128, 4);
    size_t off0 = (size_t)rids[0] * HHD * K;
    size_t off1 = (size_t)rids[1] * HHD * K;
    gemm_mfma_t4<TA, A_EXACT><<<gg, 256, 0, stream>>>(
        srcA[0], dstA[0], srcA[1], dstA[1],
        WTl_h + off0, WTl_l + off0, WTr_h + off0, WTr_l + off0,
        WTl_h + off1, WTl_l + off1, WTr_h + off1, WTr_l + off1,
        w.xl, w.xr, w.xl2, w.xr2, NN, K, HHD);
    fused_aggr4d<<<NN / 4, 256, 0, stream>>>(
        rp[0], sr[0], w.xl, w.xr, att + (size_t)rids[0] * HHD,
        rp[1], sr[1], w.xl2, w.xr2, att + (size_t)rids[1] * HHD,
        w.acc, fin_mode,
        bias + (size_t)rids[0] * HHD, bias + (size_t)rids[1] * HHD,
        zout, batch, pool);
}

// ---- fat_t group pass (fallback, z=2 GEMM + 2 aggr) ----
template <typename TA, bool A_EXACT>
static void run_group_fat_t(const TA* srcA[2], const TA* dstA[2],
                            const int* rp[2], const unsigned short* sr[2],
                            const int rids[2], int K,
                            const unsigned short* WTl_h, const unsigned short* WTl_l,
                            const unsigned short* WTr_h, const unsigned short* WTr_l,
                            const float* att, const float* bias, int fin_mode,
                            unsigned short* zout, const int* batch, float* pool,
                            const Ws& w, hipStream_t stream)
{
    dim3 gg(HHD / 128, (NN + 127) / 128, 2);
    const int ablocks = NN / 4;
    for (int q = 0; q < 2; ++q) {
        int r = rids[q];
        size_t off = (size_t)r * HHD * K;
        gemm_mfma_t<TA, A_EXACT><<<gg, 256, 0, stream>>>(
            srcA[q], dstA[q],
            WTl_h + off, WTl_l + off, WTr_h + off, WTr_l + off,
            w.xl, w.xr, NN, K, HHD);
        int fm = (q == 1) ? fin_mode : 0;
        fused_aggr4<<<ablocks, 256, 0, stream>>>(
            rp[q], sr[q], w.xl, w.xr,
            att + (size_t)r * HHD,
            w.acc, q > 0 ? 1 : 0, fm,
            bias + (size_t)rids[0] * HHD, bias + (size_t)rids[1] * HHD,
            zout, batch, pool);
    }
}

// ---- OLD FAT group pass (fallback) ----
template <typename TA, bool A_EXACT>
static void run_group_fat(const TA* srcA[2], const TA* dstA[2],
                          const int* rp[2], const unsigned short* sr[2],
                          const int rids[2], int K,
                          const float* Wl, const float* Wr, const float* att,
                          const float* bias, int fin_mode,
                          unsigned short* zout, const int* batch, float* pool,
                          const Ws& w, hipStream_t stream)
{
    dim3 gg(HHD / 64, (NN + 63) / 64, 2);
    const int ablocks = NN / 4;
    for (int q = 0; q < 2; ++q) {
        int r = rids[q];
        gemm_mfma<TA, A_EXACT><<<gg, 256, 0, stream>>>(
            srcA[q], dstA[q],
            Wl + (size_t)r * K * HHD, Wr + (size_t)r * K * HHD, HHD,
            w.xl, w.xr, NN, K, HHD);
        int fm = (q == 1) ? fin_mode : 0;
        fused_aggr4<<<ablocks, 256, 0, stream>>>(
            rp[q], sr[q], w.xl, w.xr,
            att + (size_t)r * HHD,
            w.acc, q > 0 ? 1 : 0, fm,
            bias + (size_t)rids[0] * HHD, bias + (size_t)rids[1] * HHD,
            zout, batch, pool);
    }
}

// ---- THIN group pass (deep fallback) ----
template <typename TA, bool A_EXACT>
static void run_group_thin(const TA* srcA[2], const TA* dstA[2],
                           const int* eis[2], const int rids[2], int K,
                           const float* Wl, const float* Wr, const float* att,
                           const float* bias, int fin_mode,
                           unsigned short* zout, const int* batch, float* pool,
                           const Ws& w, hipStream_t stream)
{
    dim3 gg(2, (NN + 63) / 64, 2);
    const int ablocks = NN / 4;
    for (int q = 0; q < 2; ++q) {
        int r = rids[q];
        build_csr(eis[q], w.rowptr[0], w.srcs[0], w.cnt, w.cursor, stream);
        for (int h = 0; h < HH_; ++h) {
            const float* WlS = Wl + (size_t)r * K * HHD + h * CD;
            const float* WrS = Wr + (size_t)r * K * HHD + h * CD;
            gemm_mfma<TA, A_EXACT><<<gg, 256, 0, stream>>>(
                srcA[q], dstA[q], WlS, WrS, HHD, w.xl, w.xr, NN, K, CD);
            int pass = q * HH_ + h;
            int fm = (pass == 2 * HH_ - 1) ? fin_mode : 0;
            fused_aggr1<<<ablocks, 256, 0, stream>>>(
                w.rowptr[0], w.srcs[0], w.xl, w.xr,
                att + (size_t)r * HHD + h * CD,
                w.acc, pass > 0 ? 1 : 0, fm,
                bias + (size_t)rids[0] * HHD, bias + (size_t)rids[1] * HHD,
                zout, batch, pool);
        }
    }
}

extern "C" void kernel_launch(void* const* d_in, const int* in_sizes, int n_in,
                              void* d_out, int out_size, void* d_ws, size_t ws_size,
                              hipStream_t stream)
{
    const float* x_i   = (const float*)d_in[0];
    const float* x_j   = (const float*)d_in[1];
    const int* ei_ii   = (const int*)d_in[2];
    const int* ei_jj   = (const int*)d_in[3];
    const int* ei_ij   = (const int*)d_in[4];
    const int* ei_ji   = (const int*)d_in[5];
    const int* batch_i = (const int*)d_in[6];
    const int* batch_j = (const int*)d_in[7];
    const float* Wl0   = (const float*)d_in[8];
    const float* Wr0   = (const float*)d_in[9];
    const float* att0  = (const float*)d_in[10];
    const float* b0    = (const float*)d_in[11];
    const float* Wl1   = (const float*)d_in[12];
    const float* Wr1   = (const float*)d_in[13];
    const float* att1  = (const float*)d_in[14];
    const float* b1    = (const float*)d_in[15];
    const float* W_out = (const float*)d_in[16];
    const float* b_out = (const float*)d_in[17];
    const float* W_i   = (const float*)d_in[18];
    const float* b_i   = (const float*)d_in[19];
    const float* W_j   = (const float*)d_in[20];
    const float* b_j   = (const float*)d_in[21];
    float* out = (float*)d_out;

    // cnt/cursor now sized ncsr*NN (merged CSR build needs per-relation cursors)
    const size_t FAT2_BYTES = (size_t)NN * HHD * 2 * 2 + (size_t)NN * CD * 4
                            + (size_t)NN * CD * 2 * 2 + 4 * (size_t)ETOT * 2
                            + 4 * (size_t)(NN + 4) * 4 + 4 * (size_t)NN * 4 * 2
                            + (size_t)BG * CD * 4 * 2;
    const size_t FAT1_BYTES = (size_t)NN * HHD * 2 * 2 + (size_t)NN * CD * 4
                            + (size_t)NN * CD * 2 * 2 + (size_t)ETOT * 2
                            + (size_t)(NN + 4) * 4 + (size_t)NN * 4 * 2
                            + (size_t)BG * CD * 4 * 2;
    const size_t WT0_ONE = (size_t)4 * 512 * 512 * 2;
    const size_t WT1_ONE = (size_t)4 * 512 * 128 * 2;
    const size_t WT_BYTES = 4 * WT0_ONE + 4 * WT1_ONE;
    const size_t X2_BYTES = 2 * (size_t)NN * HHD * 2;   // second xl/xr pair (merged)

    const int ncsr = (ws_size >= FAT2_BYTES) ? 4 : 1;
    const bool fat = (ws_size >= FAT1_BYTES);
    const bool fat_t = (ws_size >= FAT2_BYTES + WT_BYTES);
    const bool fat_m = (ws_size >= FAT2_BYTES + WT_BYTES + X2_BYTES);   // merged path

    Ws w;
    char* p = (char*)d_ws;
    size_t xbytes = fat ? (size_t)NN * HHD * 2 : (size_t)NN * CD * 2;
    w.xl     = (unsigned short*)p; p += xbytes;
    w.xr     = (unsigned short*)p; p += xbytes;
    w.acc    = (float*)p;          p += (size_t)NN * CD * 4;
    w.z_i    = (unsigned short*)p; p += (size_t)NN * CD * 2;
    w.z_j    = (unsigned short*)p; p += (size_t)NN * CD * 2;
    // contiguous rowptr / srcs arenas (stride (NN+4) ints / ETOT shorts)
    {
        int* rowptr_all = (int*)p;            p += (size_t)ncsr * (NN + 4) * 4;
        unsigned short* srcs_all = (unsigned short*)p; p += (size_t)ncsr * ETOT * 2;
        for (int r = 0; r < 4; ++r) {
            int rr = (r < ncsr) ? r : 0;
            w.rowptr[r] = rowptr_all + (size_t)rr * (NN + 4);
            w.srcs[r]   = srcs_all + (size_t)rr * ETOT;
        }
    }
    w.cnt    = (int*)p;            p += (size_t)ncsr * NN * 4;
    w.cursor = (int*)p;            p += (size_t)ncsr * NN * 4;
    w.pool_i = (float*)p;          p += (size_t)BG * CD * 4;
    w.pool_j = (float*)p;          p += (size_t)BG * CD * 4;
    if (fat_t) {
        w.wt0l_h = (unsigned short*)p; p += WT0_ONE;
        w.wt0l_l = (unsigned short*)p; p += WT0_ONE;
        w.wt0r_h = (unsigned short*)p; p += WT0_ONE;
        w.wt0r_l = (unsigned short*)p; p += WT0_ONE;
        w.wt1l_h = (unsigned short*)p; p += WT1_ONE;
        w.wt1l_l = (unsigned short*)p; p += WT1_ONE;
        w.wt1r_h = (unsigned short*)p; p += WT1_ONE;
        w.wt1r_l = (unsigned short*)p; p += WT1_ONE;
    }
    if (fat_m) {
        w.xl2 = (unsigned short*)p; p += (size_t)NN * HHD * 2;
        w.xr2 = (unsigned short*)p; p += (size_t)NN * HHD * 2;
    }

    hipMemsetAsync(w.pool_i, 0, (size_t)BG * CD * sizeof(float), stream);
    hipMemsetAsync(w.pool_j, 0, (size_t)BG * CD * sizeof(float), stream);

    const int* eis_all[4] = { ei_ii, ei_jj, ei_ij, ei_ji };
    const float* srcA0_i[2] = { x_i, x_j };  const float* dstA0_i[2] = { x_i, x_i };
    const float* srcA0_j[2] = { x_j, x_i };  const float* dstA0_j[2] = { x_j, x_j };
    const int rids_i[2] = { 0, 3 };
    const int rids_j[2] = { 1, 2 };
    const unsigned short* srcA1_i[2] = { w.z_i, w.z_j };
    const unsigned short* dstA1_i[2] = { w.z_i, w.z_i };
    const unsigned short* srcA1_j[2] = { w.z_j, w.z_i };
    const unsigned short* dstA1_j[2] = { w.z_j, w.z_j };

    if (fat_t) {
        // merged CSR build for all 4 relations: 3 dispatches + 1 memset (was 16)
        hipMemsetAsync(w.cnt, 0, 4 * NN * sizeof(int), stream);
        csr_hist4<<<(4 * EE + 255) / 256, 256, 0, stream>>>(
            ei_ii, ei_jj, ei_ij, ei_ji, w.cnt);
        csr_scan4<<<4, 1024, 0, stream>>>(w.cnt, w.rowptr[0], w.cursor);
        csr_scatter4<<<(4 * ETOT + 255) / 256, 256, 0, stream>>>(
            ei_ii, ei_jj, ei_ij, ei_ji, w.cursor, w.srcs[0]);
        // pre-split+transpose+frag-tile all weights once
        wsplit_t<<<4 * (FD / 64) * 8, 256, 0, stream>>>(Wl0, w.wt0l_h, w.wt0l_l, FD);
        wsplit_t<<<4 * (FD / 64) * 8, 256, 0, stream>>>(Wr0, w.wt0r_h, w.wt0r_l, FD);
        wsplit_t<<<4 * (CD / 64) * 8, 256, 0, stream>>>(Wl1, w.wt1l_h, w.wt1l_l, CD);
        wsplit_t<<<4 * (CD / 64) * 8, 256, 0, stream>>>(Wr1, w.wt1r_h, w.wt1r_l, CD);

        const int* rp_i[2] = { w.rowptr[0], w.rowptr[3] };
        const unsigned short* sr_i[2] = { w.srcs[0], w.srcs[3] };
        const int* rp_j[2] = { w.rowptr[1], w.rowptr[2] };
        const unsigned short* sr_j[2] = { w.srcs[1], w.srcs[2] };

        if (fat_m) {
            run_group_fat_m<float, false>(srcA0_i, dstA0_i, rp_i, sr_i, rids_i, FD,
                                          w.wt0l_h, w.wt0l_l, w.wt0r_h, w.wt0r_l,
                                          att0, b0, 1, w.z_i, nullptr, nullptr, w, stream);
            run_group_fat_m<float, false>(srcA0_j, dstA0_j, rp_j, sr_j, rids_j, FD,
                                          w.wt0l_h, w.wt0l_l, w.wt0r_h, w.wt0r_l,
                                          att0, b0, 1, w.z_j, nullptr, nullptr, w, stream);
            run_group_fat_m<unsigned short, true>(srcA1_i, dstA1_i, rp_i, sr_i, rids_i, CD,
                                                  w.wt1l_h, w.wt1l_l, w.wt1r_h, w.wt1r_l,
                                                  att1, b1, 2, nullptr, batch_i, w.pool_i, w, stream);
            pool_reduce<<<BG, 512, 0, stream>>>(w.acc, batch_i, w.pool_i);
            run_group_fat_m<unsigned short, true>(srcA1_j, dstA1_j, rp_j, sr_j, rids_j, CD,
                                                  w.wt1l_h, w.wt1l_l, w.wt1r_h, w.wt1r_l,
                                                  att1, b1, 2, nullptr, batch_j, w.pool_j, w, stream);
            pool_reduce<<<BG, 512, 0, stream>>>(w.acc, batch_j, w.pool_j);
        } else {
            run_group_fat_t<float, false>(srcA0_i, dstA0_i, rp_i, sr_i, rids_i, FD,
                                          w.wt0l_h, w.wt0l_l, w.wt0r_h, w.wt0r_l,
                                          att0, b0, 1, w.z_i, nullptr, nullptr, w, stream);
            run_group_fat_t<float, false>(srcA0_j, dstA0_j, rp_j, sr_j, rids_j, FD,
                                          w.wt0l_h, w.wt0l_l, w.wt0r_h, w.wt0r_l,
                                          att0, b0, 1, w.z_j, nullptr, nullptr, w, stream);
            run_group_fat_t<unsigned short, true>(srcA1_i, dstA1_i, rp_i, sr_i, rids_i, CD,
                                                  w.wt1l_h, w.wt1l_l, w.wt1r_h, w.wt1r_l,
                                                  att1, b1, 2, nullptr, batch_i, w.pool_i, w, stream);
            pool_reduce<<<BG, 512, 0, stream>>>(w.acc, batch_i, w.pool_i);
            run_group_fat_t<unsigned short, true>(srcA1_j, dstA1_j, rp_j, sr_j, rids_j, CD,
                                                  w.wt1l_h, w.wt1l_l, w.wt1r_h, w.wt1r_l,
                                                  att1, b1, 2, nullptr, batch_j, w.pool_j, w, stream);
            pool_reduce<<<BG, 512, 0, stream>>>(w.acc, batch_j, w.pool_j);
        }
    } else if (fat) {
        if (ncsr == 4) {
            for (int r = 0; r < 4; ++r)
                build_csr(eis_all[r], w.rowptr[r], w.srcs[r], w.cnt, w.cursor, stream);
            const int* rp_i[2] = { w.rowptr[0], w.rowptr[3] };
            const unsigned short* sr_i[2] = { w.srcs[0], w.srcs[3] };
            const int* rp_j[2] = { w.rowptr[1], w.rowptr[2] };
            const unsigned short* sr_j[2] = { w.srcs[1], w.srcs[2] };
            run_group_fat<float, false>(srcA0_i, dstA0_i, rp_i, sr_i, rids_i, FD,
                                        Wl0, Wr0, att0, b0, 1, w.z_i, nullptr, nullptr, w, stream);
            run_group_fat<float, false>(srcA0_j, dstA0_j, rp_j, sr_j, rids_j, FD,
                                        Wl0, Wr0, att0, b0, 1, w.z_j, nullptr, nullptr, w, stream);
            run_group_fat<unsigned short, true>(srcA1_i, dstA1_i, rp_i, sr_i, rids_i, CD,
                                                Wl1, Wr1, att1, b1, 2, nullptr, batch_i, w.pool_i, w, stream);
            pool_reduce<<<BG, 512, 0, stream>>>(w.acc, batch_i, w.pool_i);
            run_group_fat<unsigned short, true>(srcA1_j, dstA1_j, rp_j, sr_j, rids_j, CD,
                                                Wl1, Wr1, att1, b1, 2, nullptr, batch_j, w.pool_j, w, stream);
            pool_reduce<<<BG, 512, 0, stream>>>(w.acc, batch_j, w.pool_j);
        } else {
            for (int pass = 0; pass < 4; ++pass) {
                const int* rids = (pass & 1) ? rids_j : rids_i;
                for (int q = 0; q < 2; ++q) {
                    int r = rids[q];
                    build_csr(eis_all[r], w.rowptr[0], w.srcs[0], w.cnt, w.cursor, stream);
                    dim3 gg(HHD / 64, (NN + 63) / 64, 2);
                    if (pass < 2) {
                        const float* sa = (pass == 0) ? srcA0_i[q] : srcA0_j[q];
                        const float* da = (pass == 0) ? dstA0_i[q] : dstA0_j[q];
                        gemm_mfma<float, false><<<gg, 256, 0, stream>>>(
                            sa, da, Wl0 + (size_t)r * FD * HHD, Wr0 + (size_t)r * FD * HHD,
                            HHD, w.xl, w.xr, NN, FD, HHD);
                        fused_aggr4<<<NN / 4, 256, 0, stream>>>(
                            w.rowptr[0], w.srcs[0], w.xl, w.xr, att0 + (size_t)r * HHD,
                            w.acc, q, (q == 1) ? 1 : 0,
                            b0 + (size_t)rids[0] * HHD, b0 + (size_t)rids[1] * HHD,
                            (pass == 0) ? w.z_i : w.z_j, nullptr, nullptr);
                    } else {
                        const unsigned short* sa = (pass == 2) ? srcA1_i[q] : srcA1_j[q];
                        const unsigned short* da = (pass == 2) ? dstA1_i[q] : dstA1_j[q];
                        gemm_mfma<unsigned short, true><<<gg, 256, 0, stream>>>(
                            sa, da, Wl1 + (size_t)r * CD * HHD, Wr1 + (size_t)r * CD * HHD,
                            HHD, w.xl, w.xr, NN, CD, HHD);
                        fused_aggr4<<<NN / 4, 256, 0, stream>>>(
                            w.rowptr[0], w.srcs[0], w.xl, w.xr, att1 + (size_t)r * HHD,
                            w.acc, q, (q == 1) ? 2 : 0,
                            b1 + (size_t)rids[0] * HHD, b1 + (size_t)rids[1] * HHD,
                            nullptr, (pass == 2) ? batch_i : batch_j,
                            (pass == 2) ? w.pool_i : w.pool_j);
                    }
                }
                if (pass == 2)
                    pool_reduce<<<BG, 512, 0, stream>>>(w.acc, batch_i, w.pool_i);
                else if (pass == 3)
                    pool_reduce<<<BG, 512, 0, stream>>>(w.acc, batch_j, w.pool_j);
            }
        }
    } else {
        const int* eis_i[2] = { ei_ii, ei_ji };
        const int* eis_j[2] = { ei_jj, ei_ij };
        run_group_thin<float, false>(srcA0_i, dstA0_i, eis_i, rids_i, FD, Wl0, Wr0, att0, b0,
                                     1, w.z_i, nullptr, nullptr, w, stream);
        run_group_thin<float, false>(srcA0_j, dstA0_j, eis_j, rids_j, FD, Wl0, Wr0, att0, b0,
                                     1, w.z_j, nullptr, nullptr, w, stream);
        run_group_thin<unsigned short, true>(srcA1_i, dstA1_i, eis_i, rids_i, CD, Wl1, Wr1, att1, b1,
                                             2, nullptr, batch_i, w.pool_i, w, stream);
        run_group_thin<unsigned short, true>(srcA1_j, dstA1_j, eis_j, rids_j, CD, Wl1, Wr1, att1, b1,
                                             2, nullptr, batch_j, w.pool_j, w, stream);
    }

    head_kernel<<<BG, 128, 0, stream>>>(w.pool_i, w.pool_j, W_out, b_out,
                                        W_i, b_i, W_j, b_j, out);
}

// Round 6
// 1310.066 us; speedup vs baseline: 1.4875x; 1.0319x over previous
//
#include <hip/hip_runtime.h>

// ---------------- problem constants ----------------
#define NN      20000     // nodes per type
#define EE      320000    // edges per relation
#define ETOT    340000    // EE + NN self loops
#define FD      512       // raw feature dim
#define HH_     4         // heads
#define CD      128       // channels per head
#define HHD     512       // H*C
#define BG      64        // batch graphs
#define INNERD  64

typedef __attribute__((ext_vector_type(8))) short bf16x8;
typedef __attribute__((ext_vector_type(4))) float f32x4;

// ---- bf16 <-> f32 via raw bits ----
__device__ __forceinline__ float bf2f(unsigned v) { return __uint_as_float(v << 16); }
__device__ __forceinline__ unsigned short f2bf(float f) {
    unsigned u = __float_as_uint(f);
    unsigned r = 0x7fffu + ((u >> 16) & 1u);
    return (unsigned short)((u + r) >> 16);
}
__device__ __forceinline__ void load8bf(const unsigned short* p, float* f) {
    uint4 u = *reinterpret_cast<const uint4*>(p);
    f[0] = bf2f(u.x & 0xffffu); f[1] = bf2f(u.x >> 16);
    f[2] = bf2f(u.y & 0xffffu); f[3] = bf2f(u.y >> 16);
    f[4] = bf2f(u.z & 0xffffu); f[5] = bf2f(u.z >> 16);
    f[6] = bf2f(u.w & 0xffffu); f[7] = bf2f(u.w >> 16);
}
// fast split f32 -> hi + lo bf16 (truncation; residual ~2^-16 relative)
__device__ __forceinline__ void split_f32(float x, unsigned short& hi, unsigned short& lo) {
    unsigned u = __float_as_uint(x);
    hi = (unsigned short)(u >> 16);
    float r = x - bf2f(hi);
    lo = (unsigned short)(__float_as_uint(r) >> 16);
}
template <typename TA>
__device__ __forceinline__ void splitA(const TA* p, size_t i, unsigned short& hi, unsigned short& lo);
template <>
__device__ __forceinline__ void splitA<float>(const float* p, size_t i, unsigned short& hi, unsigned short& lo) {
    split_f32(p[i], hi, lo);
}
template <>
__device__ __forceinline__ void splitA<unsigned short>(const unsigned short* p, size_t i, unsigned short& hi, unsigned short& lo) {
    hi = p[i]; lo = 0;
}

// ================= CSR build (per-relation kernels, fallback paths) =================
__global__ __launch_bounds__(256) void csr_hist(const int* __restrict__ ei, int* __restrict__ cnt) {
    int e = blockIdx.x * blockDim.x + threadIdx.x;
    if (e < EE) atomicAdd(&cnt[ei[EE + e]], 1);
}

__global__ __launch_bounds__(1024) void csr_scan(const int* __restrict__ cnt,
                                                 int* __restrict__ rowptr,
                                                 int* __restrict__ cursor) {
    __shared__ int part[1024];
    int t = threadIdx.x;
    int base = t * 20;
    int s = 0;
    #pragma unroll
    for (int i = 0; i < 20; ++i) { int n = base + i; if (n < NN) s += cnt[n] + 1; }
    part[t] = s;
    __syncthreads();
    for (int off = 1; off < 1024; off <<= 1) {
        int v = (t >= off) ? part[t - off] : 0;
        __syncthreads();
        part[t] += v;
        __syncthreads();
    }
    int run = (t > 0) ? part[t - 1] : 0;
    #pragma unroll
    for (int i = 0; i < 20; ++i) {
        int n = base + i;
        if (n < NN) { rowptr[n] = run; cursor[n] = run; run += cnt[n] + 1; }
    }
    if (t == 1023) rowptr[NN] = run;
}

__global__ __launch_bounds__(256) void csr_scatter16(const int* __restrict__ ei,
                                                     int* __restrict__ cursor,
                                                     unsigned short* __restrict__ srcs) {
    int idx = blockIdx.x * blockDim.x + threadIdx.x;
    if (idx >= ETOT) return;
    int src, dst;
    if (idx < EE) { src = ei[idx]; dst = ei[EE + idx]; }
    else          { src = dst = idx - EE; }
    int pos = atomicAdd(&cursor[dst], 1);
    srcs[pos] = (unsigned short)src;
}

// ================= merged CSR build: ALL 4 relations in 3 dispatches ================
__global__ __launch_bounds__(256) void csr_hist4(
    const int* __restrict__ e0, const int* __restrict__ e1,
    const int* __restrict__ e2, const int* __restrict__ e3,
    int* __restrict__ cnt)
{
    int idx = blockIdx.x * blockDim.x + threadIdx.x;
    if (idx >= 4 * EE) return;
    int r = idx / EE, e = idx - r * EE;
    const int* ei = r == 0 ? e0 : r == 1 ? e1 : r == 2 ? e2 : e3;
    atomicAdd(&cnt[r * NN + ei[EE + e]], 1);
}

__global__ __launch_bounds__(1024) void csr_scan4(const int* __restrict__ cnt_all,
                                                  int* __restrict__ rowptr_all,
                                                  int* __restrict__ cursor_all)
{
    const int r = blockIdx.x;
    const int* cnt = cnt_all + r * NN;
    int* rowptr = rowptr_all + r * (NN + 4);
    int* cursor = cursor_all + r * NN;
    __shared__ int part[1024];
    int t = threadIdx.x;
    int base = t * 20;
    int s = 0;
    #pragma unroll
    for (int i = 0; i < 20; ++i) { int n = base + i; if (n < NN) s += cnt[n] + 1; }
    part[t] = s;
    __syncthreads();
    for (int off = 1; off < 1024; off <<= 1) {
        int v = (t >= off) ? part[t - off] : 0;
        __syncthreads();
        part[t] += v;
        __syncthreads();
    }
    int run = (t > 0) ? part[t - 1] : 0;
    #pragma unroll
    for (int i = 0; i < 20; ++i) {
        int n = base + i;
        if (n < NN) { rowptr[n] = run; cursor[n] = run; run += cnt[n] + 1; }
    }
    if (t == 1023) rowptr[NN] = run;
}

__global__ __launch_bounds__(256) void csr_scatter4(
    const int* __restrict__ e0, const int* __restrict__ e1,
    const int* __restrict__ e2, const int* __restrict__ e3,
    int* __restrict__ cursor_all, unsigned short* __restrict__ srcs_all)
{
    int idx = blockIdx.x * blockDim.x + threadIdx.x;
    if (idx >= 4 * ETOT) return;
    int r = idx / ETOT, t = idx - r * ETOT;
    const int* ei = r == 0 ? e0 : r == 1 ? e1 : r == 2 ? e2 : e3;
    int src, dst;
    if (t < EE) { src = ei[t]; dst = ei[EE + t]; }
    else        { src = dst = t - EE; }
    int pos = atomicAdd(&cursor_all[r * NN + dst], 1);
    srcs_all[(size_t)r * ETOT + pos] = (unsigned short)src;
}

// ================= W pre-split: [R][K][512] f32 -> hi/lo FRAGMENT-TILED bf16 =========
// Output layout per relation: [K/32][N=512][32] — the exact per-lane MFMA B-fragment
// order, so the GEMM reads B directly from L2 (dense 1KB/wave/instr), no LDS staging.
__global__ __launch_bounds__(256) void wsplit_t(const float* __restrict__ W,
                                                unsigned short* __restrict__ Whi,
                                                unsigned short* __restrict__ Wlo,
                                                int K)
{
    __shared__ float tile[64][65];
    const int nt = 512 / 64;
    const int kt = K / 64;
    int bid = blockIdx.x;
    int in = bid % nt; int ik = (bid / nt) % kt; int r = bid / (nt * kt);
    int t = threadIdx.x;
    const float* Wr_ = W + (size_t)r * K * 512;
    #pragma unroll
    for (int rep = 0; rep < 16; ++rep) {
        int idx = rep * 256 + t;
        int kk = idx >> 6, nn = idx & 63;
        tile[kk][nn] = Wr_[(size_t)(ik * 64 + kk) * 512 + in * 64 + nn];
    }
    __syncthreads();
    #pragma unroll
    for (int rep = 0; rep < 16; ++rep) {
        int idx = rep * 256 + t;
        int nn = idx >> 6, kk = idx & 63;
        unsigned short h, l; split_f32(tile[kk][nn], h, l);
        int n = in * 64 + nn;
        int k = ik * 64 + kk;
        size_t o = (size_t)r * 512 * K + ((size_t)(k >> 5) * 512 + n) * 32 + (k & 31);
        Whi[o] = h; Wlo[o] = l;
    }
}

// ================= 128x128 split-bf16 MFMA GEMM core (B direct-from-L2) =============
template <typename TA, bool A_EXACT>
__device__ __forceinline__ void gemm_body(
    const TA* __restrict__ A, const unsigned short* __restrict__ Bhg,
    const unsigned short* __restrict__ Blg, unsigned short* __restrict__ C,
    int bx, int by, int M, int K, int N)
{
    __shared__ unsigned short Ah[128][40];
    __shared__ unsigned short Al[A_EXACT ? 1 : 128][40];

    const int tid = threadIdx.x;
    const int wave = tid >> 6, lane = tid & 63;
    const int quad = lane >> 4, lrow = lane & 15;
    const int wr = (wave >> 1) * 64, wc = (wave & 1) * 64;
    const int tileM = by * 128, tileN = bx * 128;

    const int srow = tid >> 1;
    const int sks  = (tid & 1) * 16;
    const int sgm  = tileM + srow;

    const size_t bfrag = ((size_t)(tileN + wc + lrow) << 5) + quad * 8;
    const size_t kblk  = (size_t)N << 5;

    f32x4 acc[4][4] = {};

    for (int k0 = 0; k0 < K; k0 += 32) {
        if constexpr (!A_EXACT) {
            bf16x8 ph[2] = {{}, {}}, pl[2] = {{}, {}};
            if (sgm < M) {
                const float* Ap = (const float*)A + (size_t)sgm * K + k0 + sks;
                #pragma unroll
                for (int s = 0; s < 2; ++s) {
                    float4 f0 = reinterpret_cast<const float4*>(Ap)[2 * s];
                    float4 f1 = reinterpret_cast<const float4*>(Ap)[2 * s + 1];
                    float xv[8] = {f0.x, f0.y, f0.z, f0.w, f1.x, f1.y, f1.z, f1.w};
                    #pragma unroll
                    for (int pp = 0; pp < 4; ++pp) {
                        unsigned u0 = __float_as_uint(xv[2 * pp]);
                        unsigned u1 = __float_as_uint(xv[2 * pp + 1]);
                        reinterpret_cast<unsigned*>(&ph[s])[pp] =
                            __builtin_amdgcn_perm(u1, u0, 0x07060302u);
                        float r0 = xv[2 * pp]     - __uint_as_float(u0 & 0xffff0000u);
                        float r1 = xv[2 * pp + 1] - __uint_as_float(u1 & 0xffff0000u);
                        reinterpret_cast<unsigned*>(&pl[s])[pp] =
                            __builtin_amdgcn_perm(__float_as_uint(r1), __float_as_uint(r0), 0x07060302u);
                    }
                }
            }
            *reinterpret_cast<bf16x8*>(&Ah[srow][sks])     = ph[0];
            *reinterpret_cast<bf16x8*>(&Ah[srow][sks + 8]) = ph[1];
            *reinterpret_cast<bf16x8*>(&Al[srow][sks])     = pl[0];
            *reinterpret_cast<bf16x8*>(&Al[srow][sks + 8]) = pl[1];
        } else {
            bf16x8 v0 = {}, v1 = {};
            if (sgm < M) {
                const unsigned short* Ap = (const unsigned short*)A + (size_t)sgm * K + k0 + sks;
                v0 = reinterpret_cast<const bf16x8*>(Ap)[0];
                v1 = reinterpret_cast<const bf16x8*>(Ap)[1];
            }
            *reinterpret_cast<bf16x8*>(&Ah[srow][sks])     = v0;
            *reinterpret_cast<bf16x8*>(&Ah[srow][sks + 8]) = v1;
        }
        bf16x8 bh[4], bl[4];
        {
            const unsigned short* Bb = Bhg + (size_t)(k0 >> 5) * kblk + bfrag;
            const unsigned short* Bc = Blg + (size_t)(k0 >> 5) * kblk + bfrag;
            #pragma unroll
            for (int ni = 0; ni < 4; ++ni) {
                bh[ni] = *reinterpret_cast<const bf16x8*>(Bb + ((size_t)ni << 9));
                bl[ni] = *reinterpret_cast<const bf16x8*>(Bc + ((size_t)ni << 9));
            }
        }
        __syncthreads();
        bf16x8 ah[4], al[4];
        #pragma unroll
        for (int mi = 0; mi < 4; ++mi) {
            ah[mi] = *reinterpret_cast<const bf16x8*>(&Ah[wr + mi * 16 + lrow][quad * 8]);
            if constexpr (!A_EXACT)
                al[mi] = *reinterpret_cast<const bf16x8*>(&Al[wr + mi * 16 + lrow][quad * 8]);
        }
        #pragma unroll
        for (int mi = 0; mi < 4; ++mi)
            #pragma unroll
            for (int ni = 0; ni < 4; ++ni) {
                acc[mi][ni] = __builtin_amdgcn_mfma_f32_16x16x32_bf16(
                    ah[mi], bh[ni], acc[mi][ni], 0, 0, 0);
                acc[mi][ni] = __builtin_amdgcn_mfma_f32_16x16x32_bf16(
                    ah[mi], bl[ni], acc[mi][ni], 0, 0, 0);
                if constexpr (!A_EXACT)
                    acc[mi][ni] = __builtin_amdgcn_mfma_f32_16x16x32_bf16(
                        al[mi], bh[ni], acc[mi][ni], 0, 0, 0);
            }
        __syncthreads();
    }
    #pragma unroll
    for (int mi = 0; mi < 4; ++mi) {
        #pragma unroll
        for (int ni = 0; ni < 4; ++ni) {
            int gcol = tileN + wc + ni * 16 + lrow;
            #pragma unroll
            for (int r = 0; r < 4; ++r) {
                int grow = tileM + wr + mi * 16 + quad * 4 + r;
                if (grow < M)
                    C[(size_t)grow * N + gcol] = f2bf(acc[mi][ni][r]);
            }
        }
    }
}

// z=2 variant (fat_t fallback path)
template <typename TA, bool A_EXACT>
__global__ __launch_bounds__(256, 3) void gemm_mfma_t(
    const TA* __restrict__ A0, const TA* __restrict__ A1,
    const unsigned short* __restrict__ B0h, const unsigned short* __restrict__ B0l,
    const unsigned short* __restrict__ B1h, const unsigned short* __restrict__ B1l,
    unsigned short* __restrict__ C0, unsigned short* __restrict__ C1,
    int M, int K, int N)
{
    const int gx = gridDim.x, gy = gridDim.y;
    const int nwg = gx * gy * (int)gridDim.z;
    int b = ((int)blockIdx.z * gy + blockIdx.y) * gx + blockIdx.x;
    int xcd = b & 7, q8 = nwg >> 3, r8 = nwg & 7;
    int work = (xcd < r8 ? xcd * (q8 + 1) : r8 * (q8 + 1) + (xcd - r8) * q8) + (b >> 3);
    int bx = work % gx; int t2 = work / gx; int by = t2 % gy; int bz = t2 / gy;

    const TA* A = bz ? A1 : A0;
    const unsigned short* Bhg = bz ? B1h : B0h;
    const unsigned short* Blg = bz ? B1l : B0l;
    unsigned short* C = bz ? C1 : C0;
    gemm_body<TA, A_EXACT>(A, Bhg, Blg, C, bx, by, M, K, N);
}

// z=4 variant (one dispatch covers both relations of a group)
template <typename TA, bool A_EXACT>
__global__ __launch_bounds__(256, 3) void gemm_mfma_t4(
    const TA* __restrict__ A0, const TA* __restrict__ A1,
    const TA* __restrict__ A2, const TA* __restrict__ A3,
    const unsigned short* __restrict__ B0h, const unsigned short* __restrict__ B0l,
    const unsigned short* __restrict__ B1h, const unsigned short* __restrict__ B1l,
    const unsigned short* __restrict__ B2h, const unsigned short* __restrict__ B2l,
    const unsigned short* __restrict__ B3h, const unsigned short* __restrict__ B3l,
    unsigned short* __restrict__ C0, unsigned short* __restrict__ C1,
    unsigned short* __restrict__ C2, unsigned short* __restrict__ C3,
    int M, int K, int N)
{
    const int gx = gridDim.x, gy = gridDim.y;
    const int nwg = gx * gy * (int)gridDim.z;
    int b = ((int)blockIdx.z * gy + blockIdx.y) * gx + blockIdx.x;
    int xcd = b & 7, q8 = nwg >> 3, r8 = nwg & 7;
    int work = (xcd < r8 ? xcd * (q8 + 1) : r8 * (q8 + 1) + (xcd - r8) * q8) + (b >> 3);
    int bx = work % gx; int t2 = work / gx; int by = t2 % gy; int bz = t2 / gy;

    const TA* A = bz == 0 ? A0 : bz == 1 ? A1 : bz == 2 ? A2 : A3;
    const unsigned short* Bhg = bz == 0 ? B0h : bz == 1 ? B1h : bz == 2 ? B2h : B3h;
    const unsigned short* Blg = bz == 0 ? B0l : bz == 1 ? B1l : bz == 2 ? B2l : B3l;
    unsigned short* C = bz == 0 ? C0 : bz == 1 ? C1 : bz == 2 ? C2 : C3;
    gemm_body<TA, A_EXACT>(A, Bhg, Blg, C, bx, by, M, K, N);
}

// z=8 variant: ALL 8 L1 GEMM slices (both groups) in one dispatch.
// Slice table (bz): 0:(zi,Wl,r0)->C0 1:(zi,Wr,r0)->C1 2:(zj,Wl,r3)->C2 3:(zi,Wr,r3)->C3
//                   4:(zj,Wl,r1)->C4 5:(zj,Wr,r1)->C5 6:(zi,Wl,r2)->C6 7:(zj,Wr,r2)->C7
__global__ __launch_bounds__(256, 3) void gemm_mfma_L1x8(
    const unsigned short* __restrict__ zi, const unsigned short* __restrict__ zj,
    const unsigned short* __restrict__ Wlh, const unsigned short* __restrict__ Wll,
    const unsigned short* __restrict__ Wrh, const unsigned short* __restrict__ Wrl,
    unsigned short* __restrict__ C0, unsigned short* __restrict__ C1,
    unsigned short* __restrict__ C2, unsigned short* __restrict__ C3,
    unsigned short* __restrict__ C4, unsigned short* __restrict__ C5,
    unsigned short* __restrict__ C6, unsigned short* __restrict__ C7,
    int M, int K, int N)
{
    const int gx = gridDim.x, gy = gridDim.y;
    const int nwg = gx * gy * (int)gridDim.z;
    int b = ((int)blockIdx.z * gy + blockIdx.y) * gx + blockIdx.x;
    int xcd = b & 7, q8 = nwg >> 3, r8 = nwg & 7;
    int work = (xcd < r8 ? xcd * (q8 + 1) : r8 * (q8 + 1) + (xcd - r8) * q8) + (b >> 3);
    int bx = work % gx; int t2 = work / gx; int by = t2 % gy; int bz = t2 / gy;

    int rr = bz >> 1;
    int rel = rr == 0 ? 0 : rr == 1 ? 3 : rr == 2 ? 1 : 2;
    bool aj = (bz == 2 || bz == 4 || bz == 5 || bz == 7);
    const unsigned short* A = aj ? zj : zi;
    size_t off = (size_t)rel * HHD * K;
    const unsigned short* Bh = ((bz & 1) ? Wrh : Wlh) + off;
    const unsigned short* Bl = ((bz & 1) ? Wrl : Wll) + off;
    unsigned short* C = bz == 0 ? C0 : bz == 1 ? C1 : bz == 2 ? C2 : bz == 3 ? C3
                      : bz == 4 ? C4 : bz == 5 ? C5 : bz == 6 ? C6 : C7;
    gemm_body<unsigned short, true>(A, Bh, Bl, C, bx, by, M, K, N);
}

// ================= OLD 64x64 split-bf16 GEMM (deep fallback; raw f32 W) =============
template <typename TA, bool A_EXACT>
__global__ __launch_bounds__(256) void gemm_mfma(
    const TA* __restrict__ A0, const TA* __restrict__ A1,
    const float* __restrict__ B0, const float* __restrict__ B1, int ldb,
    unsigned short* __restrict__ C0, unsigned short* __restrict__ C1,
    int M, int K, int N)
{
    const TA* A = blockIdx.z ? A1 : A0;
    const float* B = blockIdx.z ? B1 : B0;
    unsigned short* C = blockIdx.z ? C1 : C0;

    __shared__ unsigned short Ah[64][40];
    __shared__ unsigned short Al[64][40];
    __shared__ unsigned short Bh[64][40];
    __shared__ unsigned short Bl[64][40];
    const int tid = threadIdx.x;
    const int wave = tid >> 6, lane = tid & 63;
    const int quad = lane >> 4, lrow = lane & 15;
    const int tileM = blockIdx.y * 64, tileN = blockIdx.x * 64;
    const int wm = (wave >> 1) * 32, wn = (wave & 1) * 32;

    f32x4 acc[2][2] = {};

    const int am = tid >> 2;
    const int aks = (tid & 3) * 8;
    const int bn = tid & 63;
    const int bk0 = (tid >> 6) * 8;

    for (int k0 = 0; k0 < K; k0 += 32) {
        {
            int gm = tileM + am;
            bf16x8 ph = {}, pl = {};
            if (gm < M) {
                #pragma unroll
                for (int j = 0; j < 8; ++j) {
                    unsigned short h, l;
                    splitA(A, (size_t)gm * K + k0 + aks + j, h, l);
                    ph[j] = (short)h; pl[j] = (short)l;
                }
            }
            *reinterpret_cast<bf16x8*>(&Ah[am][aks]) = ph;
            if (!A_EXACT) *reinterpret_cast<bf16x8*>(&Al[am][aks]) = pl;
        }
        {
            bf16x8 ph, pl;
            #pragma unroll
            for (int j = 0; j < 8; ++j) {
                unsigned short h, l;
                split_f32(B[(size_t)(k0 + bk0 + j) * ldb + tileN + bn], h, l);
                ph[j] = (short)h; pl[j] = (short)l;
            }
            *reinterpret_cast<bf16x8*>(&Bh[bn][bk0]) = ph;
            *reinterpret_cast<bf16x8*>(&Bl[bn][bk0]) = pl;
        }
        __syncthreads();
        bf16x8 ah[2], al[2], bh[2], bl[2];
        #pragma unroll
        for (int mi = 0; mi < 2; ++mi) {
            ah[mi] = *reinterpret_cast<const bf16x8*>(&Ah[wm + mi * 16 + lrow][quad * 8]);
            if (!A_EXACT)
                al[mi] = *reinterpret_cast<const bf16x8*>(&Al[wm + mi * 16 + lrow][quad * 8]);
        }
        #pragma unroll
        for (int ni = 0; ni < 2; ++ni) {
            bh[ni] = *reinterpret_cast<const bf16x8*>(&Bh[wn + ni * 16 + lrow][quad * 8]);
            bl[ni] = *reinterpret_cast<const bf16x8*>(&Bl[wn + ni * 16 + lrow][quad * 8]);
        }
        #pragma unroll
        for (int mi = 0; mi < 2; ++mi)
            #pragma unroll
            for (int ni = 0; ni < 2; ++ni) {
                acc[mi][ni] = __builtin_amdgcn_mfma_f32_16x16x32_bf16(
                    ah[mi], bh[ni], acc[mi][ni], 0, 0, 0);
                acc[mi][ni] = __builtin_amdgcn_mfma_f32_16x16x32_bf16(
                    ah[mi], bl[ni], acc[mi][ni], 0, 0, 0);
                if (!A_EXACT)
                    acc[mi][ni] = __builtin_amdgcn_mfma_f32_16x16x32_bf16(
                        al[mi], bh[ni], acc[mi][ni], 0, 0, 0);
            }
        __syncthreads();
    }
    #pragma unroll
    for (int mi = 0; mi < 2; ++mi) {
        #pragma unroll
        for (int ni = 0; ni < 2; ++ni) {
            int gcol = tileN + wn + ni * 16 + lrow;
            #pragma unroll
            for (int r = 0; r < 4; ++r) {
                int grow = tileM + wm + mi * 16 + quad * 4 + r;
                if (grow < M)
                    C[(size_t)grow * N + gcol] = f2bf(acc[mi][ni][r]);
            }
        }
    }
}

// ================= THIN: fused GATv2 pass, one head (deep fallback) =================
__global__ __launch_bounds__(256) void fused_aggr1(
    const int* __restrict__ rowptr, const unsigned short* __restrict__ srcs,
    const unsigned short* __restrict__ xl, const unsigned short* __restrict__ xr,
    const float* __restrict__ att,
    float* __restrict__ acc, int add_in, int fin_mode,
    const float* __restrict__ bA, const float* __restrict__ bB,
    unsigned short* __restrict__ z,
    const int* __restrict__ batch, float* __restrict__ pool)
{
    int dst = (int)((blockIdx.x * (size_t)blockDim.x + threadIdx.x) >> 6);
    int lane = threadIdx.x & 63;
    if (dst >= NN) return;
    int beg = rowptr[dst], end = rowptr[dst + 1];

    unsigned ub = *reinterpret_cast<const unsigned*>(xr + (size_t)dst * CD + lane * 2);
    float br0 = bf2f(ub & 0xffffu), br1 = bf2f(ub >> 16);
    float ta0 = att[lane * 2], ta1 = att[lane * 2 + 1];

    float n0 = 0.f, n1 = 0.f, den = 0.f;
    for (int k = beg; k < end; ++k) {
        int src = srcs[k];
        unsigned ua = *reinterpret_cast<const unsigned*>(xl + (size_t)src * CD + lane * 2);
        float a0 = bf2f(ua & 0xffffu), a1 = bf2f(ua >> 16);
        float v0 = a0 + br0, v1 = a1 + br1;
        v0 = (v0 > 0.f) ? v0 : 0.2f * v0;
        v1 = (v1 > 0.f) ? v1 : 0.2f * v1;
        float d = v0 * ta0 + v1 * ta1;
        #pragma unroll
        for (int off = 1; off < 64; off <<= 1)
            d += __shfl_xor(d, off);
        float p = expf(d);
        n0 += p * a0; n1 += p * a1; den += p;
    }
    float o0 = n0 / den, o1 = n1 / den;
    size_t ai = (size_t)dst * CD + lane * 2;
    if (add_in) { o0 += acc[ai]; o1 += acc[ai + 1]; }
    if (fin_mode == 0) {
        acc[ai] = o0; acc[ai + 1] = o1;
    } else {
        int c0 = lane * 2;
        float bb0 = 0.f, bb1 = 0.f;
        #pragma unroll
        for (int h = 0; h < HH_; ++h) {
            bb0 += bA[h * CD + c0]     + bB[h * CD + c0];
            bb1 += bA[h * CD + c0 + 1] + bB[h * CD + c0 + 1];
        }
        o0 = tanhf(o0 + bb0);
        o1 = tanhf(o1 + bb1);
        if (fin_mode == 1) {
            z[ai] = f2bf(o0); z[ai + 1] = f2bf(o1);
        } else {
            int b = batch[dst];
            atomicAdd(&pool[(size_t)b * CD + c0],     o0);
            atomicAdd(&pool[(size_t)b * CD + c0 + 1], o1);
        }
    }
}

// ================= GATv2 aggregation helpers =================
__device__ __forceinline__ float edge_logit(const float* a, const float* br, const float* ta) {
    float d = 0.f;
    #pragma unroll
    for (int j = 0; j < 8; ++j) {
        float v = a[j] + br[j];
        v = fmaxf(v, 0.2f * v);
        d += v * ta[j];
    }
    return d;
}
__device__ __forceinline__ float quad_reduce(float d) {
    d += __shfl_xor(d, 1);
    d += __shfl_xor(d, 2);
    d += __shfl_xor(d, 4);
    d += __shfl_xor(d, 8);
    return d;
}
// drain [k,e) edges of one relation (2x unrolled + tail); k-order accumulation
__device__ __forceinline__ void gat_drain(
    const unsigned short* __restrict__ sr, const unsigned short* __restrict__ xl,
    const float* br, const float* ta, int k, int e, float* n, float& den, int lane)
{
    for (; k + 2 <= e; k += 2) {
        int s0 = sr[k], s1 = sr[k + 1];
        float A0[8], A1[8];
        load8bf(xl + (size_t)s0 * HHD + lane * 8, A0);
        load8bf(xl + (size_t)s1 * HHD + lane * 8, A1);
        float d0 = quad_reduce(edge_logit(A0, br, ta));
        float d1 = quad_reduce(edge_logit(A1, br, ta));
        float p0 = __expf(d0), p1 = __expf(d1);
        den += p0;
        #pragma unroll
        for (int j = 0; j < 8; ++j) n[j] += p0 * A0[j];
        den += p1;
        #pragma unroll
        for (int j = 0; j < 8; ++j) n[j] += p1 * A1[j];
    }
    if (k < e) {
        int s0 = sr[k];
        float A0[8];
        load8bf(xl + (size_t)s0 * HHD + lane * 8, A0);
        float d0 = quad_reduce(edge_logit(A0, br, ta));
        float p0 = __expf(d0);
        den += p0;
        #pragma unroll
        for (int j = 0; j < 8; ++j) n[j] += p0 * A0[j];
    }
}

// single-relation pass (fallback)
__device__ __forceinline__ void gat_rel(
    const int* __restrict__ rp, const unsigned short* __restrict__ sr,
    const unsigned short* __restrict__ xl, const unsigned short* __restrict__ xr,
    const float* __restrict__ att, int dst, int lane, float* o)
{
    int beg = rp[dst], end = rp[dst + 1];
    float br[8], ta[8];
    load8bf(xr + (size_t)dst * HHD + lane * 8, br);
    #pragma unroll
    for (int j = 0; j < 8; ++j) ta[j] = att[lane * 8 + j];
    float n[8] = {}; float den = 0.f;
    gat_drain(sr, xl, br, ta, beg, end, n, den, lane);
    float inv = 1.f / den;
    #pragma unroll
    for (int j = 0; j < 8; ++j) {
        o[j] = n[j] * inv;
        o[j] += __shfl_xor(o[j], 16);
        o[j] += __shfl_xor(o[j], 32);
    }
}

// DUAL-relation pass: interleave both relations' edge loops (4 gathers in flight).
// Per-relation accumulation order is unchanged -> numerically identical.
__device__ __forceinline__ void gat_rel2(
    const int* __restrict__ rp0, const unsigned short* __restrict__ sr0,
    const unsigned short* __restrict__ xl0, const unsigned short* __restrict__ xr0,
    const float* __restrict__ attA,
    const int* __restrict__ rp1, const unsigned short* __restrict__ sr1,
    const unsigned short* __restrict__ xl1, const unsigned short* __restrict__ xr1,
    const float* __restrict__ attB,
    int dst, int lane, float* o0, float* o1)
{
    int k0 = rp0[dst], e0 = rp0[dst + 1];
    int k1 = rp1[dst], e1 = rp1[dst + 1];
    float br0[8], br1[8], ta0[8], ta1[8];
    load8bf(xr0 + (size_t)dst * HHD + lane * 8, br0);
    load8bf(xr1 + (size_t)dst * HHD + lane * 8, br1);
    #pragma unroll
    for (int j = 0; j < 8; ++j) { ta0[j] = attA[lane * 8 + j]; ta1[j] = attB[lane * 8 + j]; }

    float n0[8] = {}, n1[8] = {};
    float den0 = 0.f, den1 = 0.f;

    while (k0 + 2 <= e0 && k1 + 2 <= e1) {
        int sa0 = sr0[k0], sa1 = sr0[k0 + 1];
        int sb0 = sr1[k1], sb1 = sr1[k1 + 1];
        float A0[8], A1[8], B0[8], B1[8];
        load8bf(xl0 + (size_t)sa0 * HHD + lane * 8, A0);
        load8bf(xl0 + (size_t)sa1 * HHD + lane * 8, A1);
        load8bf(xl1 + (size_t)sb0 * HHD + lane * 8, B0);
        load8bf(xl1 + (size_t)sb1 * HHD + lane * 8, B1);
        float dA0 = quad_reduce(edge_logit(A0, br0, ta0));
        float dA1 = quad_reduce(edge_logit(A1, br0, ta0));
        float dB0 = quad_reduce(edge_logit(B0, br1, ta1));
        float dB1 = quad_reduce(edge_logit(B1, br1, ta1));
        float pA0 = __expf(dA0), pA1 = __expf(dA1);
        float pB0 = __expf(dB0), pB1 = __expf(dB1);
        den0 += pA0;
        #pragma unroll
        for (int j = 0; j < 8; ++j) n0[j] += pA0 * A0[j];
        den0 += pA1;
        #pragma unroll
        for (int j = 0; j < 8; ++j) n0[j] += pA1 * A1[j];
        den1 += pB0;
        #pragma unroll
        for (int j = 0; j < 8; ++j) n1[j] += pB0 * B0[j];
        den1 += pB1;
        #pragma unroll
        for (int j = 0; j < 8; ++j) n1[j] += pB1 * B1[j];
        k0 += 2; k1 += 2;
    }
    gat_drain(sr0, xl0, br0, ta0, k0, e0, n0, den0, lane);
    gat_drain(sr1, xl1, br1, ta1, k1, e1, n1, den1, lane);

    float i0 = 1.f / den0, i1 = 1.f / den1;
    #pragma unroll
    for (int j = 0; j < 8; ++j) {
        o0[j] = n0[j] * i0;
        o0[j] += __shfl_xor(o0[j], 16);
        o0[j] += __shfl_xor(o0[j], 32);
        o1[j] = n1[j] * i1;
        o1[j] += __shfl_xor(o1[j], 16);
        o1[j] += __shfl_xor(o1[j], 32);
    }
}

// dual-relation aggr body (standalone kernel AND fused kernel share this)
__device__ __forceinline__ void aggr4d_body(
    int dst, int lane,
    const int* __restrict__ rp0, const unsigned short* __restrict__ sr0,
    const unsigned short* __restrict__ xl0, const unsigned short* __restrict__ xr0,
    const float* __restrict__ attA,
    const int* __restrict__ rp1, const unsigned short* __restrict__ sr1,
    const unsigned short* __restrict__ xl1, const unsigned short* __restrict__ xr1,
    const float* __restrict__ attB,
    float* __restrict__ acc, int fin_mode,
    const float* __restrict__ bA, const float* __restrict__ bB,
    unsigned short* __restrict__ z)
{
    float o0[8], o1[8];
    gat_rel2(rp0, sr0, xl0, xr0, attA, rp1, sr1, xl1, xr1, attB, dst, lane, o0, o1);
    #pragma unroll
    for (int j = 0; j < 8; ++j) o1[j] += o0[j];

    if (lane < 16) {
        size_t ai = (size_t)dst * CD + lane * 8;
        int c0 = lane * 8;
        #pragma unroll
        for (int j = 0; j < 8; ++j) {
            float bb = 0.f;
            #pragma unroll
            for (int h = 0; h < HH_; ++h)
                bb += bA[h * CD + c0 + j] + bB[h * CD + c0 + j];
            o1[j] = tanhf(o1[j] + bb);
        }
        if (fin_mode == 1) {
            #pragma unroll
            for (int j = 0; j < 8; ++j) z[ai + j] = f2bf(o1[j]);
        } else {
            #pragma unroll
            for (int j = 0; j < 8; ++j) acc[ai + j] = o1[j];
        }
    }
}

// ================= FAT: single-relation pass (fat_t fallback) =================
__global__ __launch_bounds__(256) void fused_aggr4(
    const int* __restrict__ rowptr, const unsigned short* __restrict__ srcs,
    const unsigned short* __restrict__ xl, const unsigned short* __restrict__ xr,
    const float* __restrict__ att,
    float* __restrict__ acc, int add_in, int fin_mode,
    const float* __restrict__ bA, const float* __restrict__ bB,
    unsigned short* __restrict__ z,
    const int* __restrict__ batch, float* __restrict__ pool)
{
    int dst = (int)((blockIdx.x * (size_t)blockDim.x + threadIdx.x) >> 6);
    int lane = threadIdx.x & 63;
    if (dst >= NN) return;

    float o[8];
    gat_rel(rowptr, srcs, xl, xr, att, dst, lane, o);

    if (lane < 16) {
        size_t ai = (size_t)dst * CD + lane * 8;
        if (add_in) {
            #pragma unroll
            for (int j = 0; j < 8; ++j) o[j] += acc[ai + j];
        }
        if (fin_mode == 0) {
            #pragma unroll
            for (int j = 0; j < 8; ++j) acc[ai + j] = o[j];
        } else {
            int c0 = lane * 8;
            #pragma unroll
            for (int j = 0; j < 8; ++j) {
                float bb = 0.f;
                #pragma unroll
                for (int h = 0; h < HH_; ++h)
                    bb += bA[h * CD + c0 + j] + bB[h * CD + c0 + j];
                o[j] = tanhf(o[j] + bb);
            }
            if (fin_mode == 1) {
                #pragma unroll
                for (int j = 0; j < 8; ++j) z[ai + j] = f2bf(o[j]);
            } else {
                #pragma unroll
                for (int j = 0; j < 8; ++j) acc[ai + j] = o[j];
            }
        }
    }
}

// ================= FAT merged: BOTH relations of a group in one dispatch ============
__global__ __launch_bounds__(256) void fused_aggr4d(
    const int* __restrict__ rp0, const unsigned short* __restrict__ sr0,
    const unsigned short* __restrict__ xl0, const unsigned short* __restrict__ xr0,
    const float* __restrict__ attA,
    const int* __restrict__ rp1, const unsigned short* __restrict__ sr1,
    const unsigned short* __restrict__ xl1, const unsigned short* __restrict__ xr1,
    const float* __restrict__ attB,
    float* __restrict__ acc, int fin_mode,
    const float* __restrict__ bA, const float* __restrict__ bB,
    unsigned short* __restrict__ z,
    const int* __restrict__ batch, float* __restrict__ pool)
{
    int dst = (int)((blockIdx.x * (size_t)blockDim.x + threadIdx.x) >> 6);
    int lane = threadIdx.x & 63;
    if (dst >= NN) return;
    aggr4d_body(dst, lane, rp0, sr0, xl0, xr0, attA, rp1, sr1, xl1, xr1, attB,
                acc, fin_mode, bA, bB, z);
}

// ================= FUSED: GEMM (z=4 slices) + dual-relation aggr in ONE dispatch =====
// blocks [0,ngemm): compute-bound GEMM; blocks [ngemm, ngemm+NN/4): latency-bound aggr.
// Independent work (cross-group) -> CU scheduler overlaps MFMA and gather waves (m114).
template <typename TA, bool A_EXACT>
__global__ __launch_bounds__(256, 3) void gemm_aggr_fused(
    int ngemm,
    const TA* __restrict__ A0, const TA* __restrict__ A1,
    const TA* __restrict__ A2, const TA* __restrict__ A3,
    const unsigned short* __restrict__ B0h, const unsigned short* __restrict__ B0l,
    const unsigned short* __restrict__ B1h, const unsigned short* __restrict__ B1l,
    const unsigned short* __restrict__ B2h, const unsigned short* __restrict__ B2l,
    const unsigned short* __restrict__ B3h, const unsigned short* __restrict__ B3l,
    unsigned short* __restrict__ C0, unsigned short* __restrict__ C1,
    unsigned short* __restrict__ C2, unsigned short* __restrict__ C3,
    int M, int K, int N,
    const int* __restrict__ rp0, const unsigned short* __restrict__ sr0,
    const unsigned short* __restrict__ xl0, const unsigned short* __restrict__ xr0,
    const float* __restrict__ attA,
    const int* __restrict__ rp1, const unsigned short* __restrict__ sr1,
    const unsigned short* __restrict__ xl1, const unsigned short* __restrict__ xr1,
    const float* __restrict__ attB,
    float* __restrict__ acc, int fin_mode,
    const float* __restrict__ bA, const float* __restrict__ bB,
    unsigned short* __restrict__ zout)
{
    if ((int)blockIdx.x < ngemm) {
        int b = blockIdx.x;
        int xcd = b & 7, q8 = ngemm >> 3, r8 = ngemm & 7;
        int work = (xcd < r8 ? xcd * (q8 + 1) : r8 * (q8 + 1) + (xcd - r8) * q8) + (b >> 3);
        const int gx = N / 128, gy = (M + 127) / 128;
        int bx = work % gx; int t2 = work / gx; int by = t2 % gy; int bz = t2 / gy;
        const TA* A = bz == 0 ? A0 : bz == 1 ? A1 : bz == 2 ? A2 : A3;
        const unsigned short* Bh = bz == 0 ? B0h : bz == 1 ? B1h : bz == 2 ? B2h : B3h;
        const unsigned short* Bl = bz == 0 ? B0l : bz == 1 ? B1l : bz == 2 ? B2l : B3l;
        unsigned short* C = bz == 0 ? C0 : bz == 1 ? C1 : bz == 2 ? C2 : C3;
        gemm_body<TA, A_EXACT>(A, Bh, Bl, C, bx, by, M, K, N);
    } else {
        int dst = (int)(((blockIdx.x - ngemm) * (size_t)blockDim.x + threadIdx.x) >> 6);
        int lane = threadIdx.x & 63;
        if (dst >= NN) return;
        aggr4d_body(dst, lane, rp0, sr0, xl0, xr0, attA, rp1, sr1, xl1, xr1, attB,
                    acc, fin_mode, bA, bB, zout);
    }
}

// ================= pool_reduce: segmented sum over sorted batch (no atomics) ========
__global__ __launch_bounds__(512) void pool_reduce(
    const float* __restrict__ acc, const int* __restrict__ batch,
    float* __restrict__ pool)
{
    int b = blockIdx.x;
    int t = threadIdx.x & (CD - 1);
    int q = threadIdx.x >> 7;
    int lo, hi;
    { int l = 0, r = NN; while (l < r) { int m = (l + r) >> 1; if (batch[m] < b) l = m + 1; else r = m; } lo = l; }
    { int l = lo, r = NN; while (l < r) { int m = (l + r) >> 1; if (batch[m] <= b) l = m + 1; else r = m; } hi = l; }
    float s = 0.f;
    for (int nrow = lo + q; nrow < hi; nrow += 4)
        s += acc[(size_t)nrow * CD + t];
    __shared__ float red[4][CD];
    red[q][t] = s;
    __syncthreads();
    if (q == 0)
        pool[(size_t)b * CD + t] = red[0][t] + red[1][t] + red[2][t] + red[3][t];
}

// ================= head =================
__global__ __launch_bounds__(128) void head_kernel(
    const float* __restrict__ pool_i, const float* __restrict__ pool_j,
    const float* __restrict__ W_out, const float* __restrict__ b_out,
    const float* __restrict__ W_i, const float* __restrict__ b_i,
    const float* __restrict__ W_j, const float* __restrict__ b_j,
    float* __restrict__ out)
{
    int b = blockIdx.x;
    int t = threadIdx.x;
    __shared__ float pi[CD], pj[CD];
    pi[t] = tanhf(pool_i[(size_t)b * CD + t]);
    pj[t] = tanhf(pool_j[(size_t)b * CD + t]);
    __syncthreads();
    if (t < INNERD) {
        float a = b_i[t];
        for (int c = 0; c < CD; ++c) a += pi[c] * W_i[c * INNERD + t];
        out[BG + (size_t)b * INNERD + t] = a;
    } else {
        int k = t - INNERD;
        float a = b_j[k];
        for (int c = 0; c < CD; ++c) a += pj[c] * W_j[c * INNERD + k];
        out[BG + BG * INNERD + (size_t)b * INNERD + k] = a;
    }
    if (t == 0) {
        float a = b_out[0];
        for (int c = 0; c < CD; ++c) a += (pi[c] + pj[c]) * W_out[c];
        out[b] = 1.f / (1.f + expf(-a));
    }
}

// ================= host-side drivers =================
struct Ws {
    unsigned short *xl, *xr, *xl2, *xr2, *xl3, *xr3, *xl4, *xr4, *z_i, *z_j;
    float* acc;
    int *rowptr[4];
    unsigned short *srcs[4];
    int *cnt, *cursor;
    float *pool_i, *pool_j;
    unsigned short *wt0l_h, *wt0l_l, *wt0r_h, *wt0r_l;
    unsigned short *wt1l_h, *wt1l_l, *wt1r_h, *wt1r_l;
};

static void build_csr(const int* ei, int* rowptr, unsigned short* srcs,
                      int* cnt, int* cursor, hipStream_t stream) {
    hipMemsetAsync(cnt, 0, NN * sizeof(int), stream);
    csr_hist<<<(EE + 255) / 256, 256, 0, stream>>>(ei, cnt);
    csr_scan<<<1, 1024, 0, stream>>>(cnt, rowptr, cursor);
    csr_scatter16<<<(ETOT + 255) / 256, 256, 0, stream>>>(ei, cursor, srcs);
}

// ---- MERGED group pass: z=4 GEMM then one dual-relation aggr (fat_m fallback) ----
template <typename TA, bool A_EXACT>
static void run_group_fat_m(const TA* srcA[2], const TA* dstA[2],
                            const int* rp[2], const unsigned short* sr[2],
                            const int rids[2], int K,
                            const unsigned short* WTl_h, const unsigned short* WTl_l,
                            const unsigned short* WTr_h, const unsigned short* WTr_l,
                            const float* att, const float* bias, int fin_mode,
                            unsigned short* zout, const int* batch, float* pool,
                            const Ws& w, hipStream_t stream)
{
    dim3 gg(HHD / 128, (NN + 127) / 128, 4);
    size_t off0 = (size_t)rids[0] * HHD * K;
    size_t off1 = (size_t)rids[1] * HHD * K;
    gemm_mfma_t4<TA, A_EXACT><<<gg, 256, 0, stream>>>(
        srcA[0], dstA[0], srcA[1], dstA[1],
        WTl_h + off0, WTl_l + off0, WTr_h + off0, WTr_l + off0,
        WTl_h + off1, WTl_l + off1, WTr_h + off1, WTr_l + off1,
        w.xl, w.xr, w.xl2, w.xr2, NN, K, HHD);
    fused_aggr4d<<<NN / 4, 256, 0, stream>>>(
        rp[0], sr[0], w.xl, w.xr, att + (size_t)rids[0] * HHD,
        rp[1], sr[1], w.xl2, w.xr2, att + (size_t)rids[1] * HHD,
        w.acc, fin_mode,
        bias + (size_t)rids[0] * HHD, bias + (size_t)rids[1] * HHD,
        zout, batch, pool);
}

// ---- fat_t group pass (fallback, z=2 GEMM + 2 aggr) ----
template <typename TA, bool A_EXACT>
static void run_group_fat_t(const TA* srcA[2], const TA* dstA[2],
                            const int* rp[2], const unsigned short* sr[2],
                            const int rids[2], int K,
                            const unsigned short* WTl_h, const unsigned short* WTl_l,
                            const unsigned short* WTr_h, const unsigned short* WTr_l,
                            const float* att, const float* bias, int fin_mode,
                            unsigned short* zout, const int* batch, float* pool,
                            const Ws& w, hipStream_t stream)
{
    dim3 gg(HHD / 128, (NN + 127) / 128, 2);
    const int ablocks = NN / 4;
    for (int q = 0; q < 2; ++q) {
        int r = rids[q];
        size_t off = (size_t)r * HHD * K;
        gemm_mfma_t<TA, A_EXACT><<<gg, 256, 0, stream>>>(
            srcA[q], dstA[q],
            WTl_h + off, WTl_l + off, WTr_h + off, WTr_l + off,
            w.xl, w.xr, NN, K, HHD);
        int fm = (q == 1) ? fin_mode : 0;
        fused_aggr4<<<ablocks, 256, 0, stream>>>(
            rp[q], sr[q], w.xl, w.xr,
            att + (size_t)r * HHD,
            w.acc, q > 0 ? 1 : 0, fm,
            bias + (size_t)rids[0] * HHD, bias + (size_t)rids[1] * HHD,
            zout, batch, pool);
    }
}

// ---- OLD FAT group pass (fallback) ----
template <typename TA, bool A_EXACT>
static void run_group_fat(const TA* srcA[2], const TA* dstA[2],
                          const int* rp[2], const unsigned short* sr[2],
                          const int rids[2], int K,
                          const float* Wl, const float* Wr, const float* att,
                          const float* bias, int fin_mode,
                          unsigned short* zout, const int* batch, float* pool,
                          const Ws& w, hipStream_t stream)
{
    dim3 gg(HHD / 64, (NN + 63) / 64, 2);
    const int ablocks = NN / 4;
    for (int q = 0; q < 2; ++q) {
        int r = rids[q];
        gemm_mfma<TA, A_EXACT><<<gg, 256, 0, stream>>>(
            srcA[q], dstA[q],
            Wl + (size_t)r * K * HHD, Wr + (size_t)r * K * HHD, HHD,
            w.xl, w.xr, NN, K, HHD);
        int fm = (q == 1) ? fin_mode : 0;
        fused_aggr4<<<ablocks, 256, 0, stream>>>(
            rp[q], sr[q], w.xl, w.xr,
            att + (size_t)r * HHD,
            w.acc, q > 0 ? 1 : 0, fm,
            bias + (size_t)rids[0] * HHD, bias + (size_t)rids[1] * HHD,
            zout, batch, pool);
    }
}

// ---- THIN group pass (deep fallback) ----
template <typename TA, bool A_EXACT>
static void run_group_thin(const TA* srcA[2], const TA* dstA[2],
                           const int* eis[2], const int rids[2], int K,
                           const float* Wl, const float* Wr, const float* att,
                           const float* bias, int fin_mode,
                           unsigned short* zout, const int* batch, float* pool,
                           const Ws& w, hipStream_t stream)
{
    dim3 gg(2, (NN + 63) / 64, 2);
    const int ablocks = NN / 4;
    for (int q = 0; q < 2; ++q) {
        int r = rids[q];
        build_csr(eis[q], w.rowptr[0], w.srcs[0], w.cnt, w.cursor, stream);
        for (int h = 0; h < HH_; ++h) {
            const float* WlS = Wl + (size_t)r * K * HHD + h * CD;
            const float* WrS = Wr + (size_t)r * K * HHD + h * CD;
            gemm_mfma<TA, A_EXACT><<<gg, 256, 0, stream>>>(
                srcA[q], dstA[q], WlS, WrS, HHD, w.xl, w.xr, NN, K, CD);
            int pass = q * HH_ + h;
            int fm = (pass == 2 * HH_ - 1) ? fin_mode : 0;
            fused_aggr1<<<ablocks, 256, 0, stream>>>(
                w.rowptr[0], w.srcs[0], w.xl, w.xr,
                att + (size_t)r * HHD + h * CD,
                w.acc, pass > 0 ? 1 : 0, fm,
                bias + (size_t)rids[0] * HHD, bias + (size_t)rids[1] * HHD,
                zout, batch, pool);
        }
    }
}

extern "C" void kernel_launch(void* const* d_in, const int* in_sizes, int n_in,
                              void* d_out, int out_size, void* d_ws, size_t ws_size,
                              hipStream_t stream)
{
    const float* x_i   = (const float*)d_in[0];
    const float* x_j   = (const float*)d_in[1];
    const int* ei_ii   = (const int*)d_in[2];
    const int* ei_jj   = (const int*)d_in[3];
    const int* ei_ij   = (const int*)d_in[4];
    const int* ei_ji   = (const int*)d_in[5];
    const int* batch_i = (const int*)d_in[6];
    const int* batch_j = (const int*)d_in[7];
    const float* Wl0   = (const float*)d_in[8];
    const float* Wr0   = (const float*)d_in[9];
    const float* att0  = (const float*)d_in[10];
    const float* b0    = (const float*)d_in[11];
    const float* Wl1   = (const float*)d_in[12];
    const float* Wr1   = (const float*)d_in[13];
    const float* att1  = (const float*)d_in[14];
    const float* b1    = (const float*)d_in[15];
    const float* W_out = (const float*)d_in[16];
    const float* b_out = (const float*)d_in[17];
    const float* W_i   = (const float*)d_in[18];
    const float* b_i   = (const float*)d_in[19];
    const float* W_j   = (const float*)d_in[20];
    const float* b_j   = (const float*)d_in[21];
    float* out = (float*)d_out;

    const size_t FAT2_BYTES = (size_t)NN * HHD * 2 * 2 + (size_t)NN * CD * 4
                            + (size_t)NN * CD * 2 * 2 + 4 * (size_t)ETOT * 2
                            + 4 * (size_t)(NN + 4) * 4 + 4 * (size_t)NN * 4 * 2
                            + (size_t)BG * CD * 4 * 2;
    const size_t FAT1_BYTES = (size_t)NN * HHD * 2 * 2 + (size_t)NN * CD * 4
                            + (size_t)NN * CD * 2 * 2 + (size_t)ETOT * 2
                            + (size_t)(NN + 4) * 4 + (size_t)NN * 4 * 2
                            + (size_t)BG * CD * 4 * 2;
    const size_t WT0_ONE = (size_t)4 * 512 * 512 * 2;
    const size_t WT1_ONE = (size_t)4 * 512 * 128 * 2;
    const size_t WT_BYTES = 4 * WT0_ONE + 4 * WT1_ONE;
    const size_t X2_BYTES = 2 * (size_t)NN * HHD * 2;   // one extra xl/xr pair

    const int ncsr = (ws_size >= FAT2_BYTES) ? 4 : 1;
    const bool fat = (ws_size >= FAT1_BYTES);
    const bool fat_t = (ws_size >= FAT2_BYTES + WT_BYTES);
    const bool fat_m = (ws_size >= FAT2_BYTES + WT_BYTES + X2_BYTES);
    const bool fat_f = (ws_size >= FAT2_BYTES + WT_BYTES + 3 * X2_BYTES);  // fused path

    Ws w;
    char* p = (char*)d_ws;
    size_t xbytes = fat ? (size_t)NN * HHD * 2 : (size_t)NN * CD * 2;
    w.xl     = (unsigned short*)p; p += xbytes;
    w.xr     = (unsigned short*)p; p += xbytes;
    w.acc    = (float*)p;          p += (size_t)NN * CD * 4;
    w.z_i    = (unsigned short*)p; p += (size_t)NN * CD * 2;
    w.z_j    = (unsigned short*)p; p += (size_t)NN * CD * 2;
    {
        int* rowptr_all = (int*)p;            p += (size_t)ncsr * (NN + 4) * 4;
        unsigned short* srcs_all = (unsigned short*)p; p += (size_t)ncsr * ETOT * 2;
        for (int r = 0; r < 4; ++r) {
            int rr = (r < ncsr) ? r : 0;
            w.rowptr[r] = rowptr_all + (size_t)rr * (NN + 4);
            w.srcs[r]   = srcs_all + (size_t)rr * ETOT;
        }
    }
    w.cnt    = (int*)p;            p += (size_t)ncsr * NN * 4;
    w.cursor = (int*)p;            p += (size_t)ncsr * NN * 4;
    w.pool_i = (float*)p;          p += (size_t)BG * CD * 4;
    w.pool_j = (float*)p;          p += (size_t)BG * CD * 4;
    if (fat_t) {
        w.wt0l_h = (unsigned short*)p; p += WT0_ONE;
        w.wt0l_l = (unsigned short*)p; p += WT0_ONE;
        w.wt0r_h = (unsigned short*)p; p += WT0_ONE;
        w.wt0r_l = (unsigned short*)p; p += WT0_ONE;
        w.wt1l_h = (unsigned short*)p; p += WT1_ONE;
        w.wt1l_l = (unsigned short*)p; p += WT1_ONE;
        w.wt1r_h = (unsigned short*)p; p += WT1_ONE;
        w.wt1r_l = (unsigned short*)p; p += WT1_ONE;
    }
    if (fat_m) {
        w.xl2 = (unsigned short*)p; p += (size_t)NN * HHD * 2;
        w.xr2 = (unsigned short*)p; p += (size_t)NN * HHD * 2;
    }
    if (fat_f) {
        w.xl3 = (unsigned short*)p; p += (size_t)NN * HHD * 2;
        w.xr3 = (unsigned short*)p; p += (size_t)NN * HHD * 2;
        w.xl4 = (unsigned short*)p; p += (size_t)NN * HHD * 2;
        w.xr4 = (unsigned short*)p; p += (size_t)NN * HHD * 2;
    }

    hipMemsetAsync(w.pool_i, 0, (size_t)BG * CD * sizeof(float), stream);
    hipMemsetAsync(w.pool_j, 0, (size_t)BG * CD * sizeof(float), stream);

    const int* eis_all[4] = { ei_ii, ei_jj, ei_ij, ei_ji };
    const float* srcA0_i[2] = { x_i, x_j };  const float* dstA0_i[2] = { x_i, x_i };
    const float* srcA0_j[2] = { x_j, x_i };  const float* dstA0_j[2] = { x_j, x_j };
    const int rids_i[2] = { 0, 3 };
    const int rids_j[2] = { 1, 2 };
    const unsigned short* srcA1_i[2] = { w.z_i, w.z_j };
    const unsigned short* dstA1_i[2] = { w.z_i, w.z_i };
    const unsigned short* srcA1_j[2] = { w.z_j, w.z_i };
    const unsigned short* dstA1_j[2] = { w.z_j, w.z_j };

    if (fat_t) {
        // merged CSR build for all 4 relations: 3 dispatches + 1 memset
        hipMemsetAsync(w.cnt, 0, 4 * NN * sizeof(int), stream);
        csr_hist4<<<(4 * EE + 255) / 256, 256, 0, stream>>>(
            ei_ii, ei_jj, ei_ij, ei_ji, w.cnt);
        csr_scan4<<<4, 1024, 0, stream>>>(w.cnt, w.rowptr[0], w.cursor);
        csr_scatter4<<<(4 * ETOT + 255) / 256, 256, 0, stream>>>(
            ei_ii, ei_jj, ei_ij, ei_ji, w.cursor, w.srcs[0]);
        // pre-split+transpose+frag-tile all weights once
        wsplit_t<<<4 * (FD / 64) * 8, 256, 0, stream>>>(Wl0, w.wt0l_h, w.wt0l_l, FD);
        wsplit_t<<<4 * (FD / 64) * 8, 256, 0, stream>>>(Wr0, w.wt0r_h, w.wt0r_l, FD);
        wsplit_t<<<4 * (CD / 64) * 8, 256, 0, stream>>>(Wl1, w.wt1l_h, w.wt1l_l, CD);
        wsplit_t<<<4 * (CD / 64) * 8, 256, 0, stream>>>(Wr1, w.wt1r_h, w.wt1r_l, CD);

        const int* rp_i[2] = { w.rowptr[0], w.rowptr[3] };
        const unsigned short* sr_i[2] = { w.srcs[0], w.srcs[3] };
        const int* rp_j[2] = { w.rowptr[1], w.rowptr[2] };
        const unsigned short* sr_j[2] = { w.srcs[1], w.srcs[2] };

        if (fat_f) {
            const size_t o0 = (size_t)0 * HHD * FD, o3 = (size_t)3 * HHD * FD;
            const size_t o1 = (size_t)1 * HHD * FD, o2 = (size_t)2 * HHD * FD;
            // 1) GEMM0_i (z=4) -> xl,xr (rel0), xl2,xr2 (rel3)
            dim3 gg(HHD / 128, (NN + 127) / 128, 4);
            gemm_mfma_t4<float, false><<<gg, 256, 0, stream>>>(
                x_i, x_i, x_j, x_i,
                w.wt0l_h + o0, w.wt0l_l + o0, w.wt0r_h + o0, w.wt0r_l + o0,
                w.wt0l_h + o3, w.wt0l_l + o3, w.wt0r_h + o3, w.wt0r_l + o3,
                w.xl, w.xr, w.xl2, w.xr2, NN, FD, HHD);
            // 2) FUSED: GEMM0_j -> xl3..xr4  ||  aggr0_i -> z_i
            const int ngemm = (HHD / 128) * ((NN + 127) / 128) * 4;   // 2512
            gemm_aggr_fused<float, false><<<ngemm + NN / 4, 256, 0, stream>>>(
                ngemm,
                x_j, x_j, x_i, x_j,
                w.wt0l_h + o1, w.wt0l_l + o1, w.wt0r_h + o1, w.wt0r_l + o1,
                w.wt0l_h + o2, w.wt0l_l + o2, w.wt0r_h + o2, w.wt0r_l + o2,
                w.xl3, w.xr3, w.xl4, w.xr4, NN, FD, HHD,
                w.rowptr[0], w.srcs[0], w.xl, w.xr, att0 + (size_t)0 * HHD,
                w.rowptr[3], w.srcs[3], w.xl2, w.xr2, att0 + (size_t)3 * HHD,
                w.acc, 1, b0 + (size_t)0 * HHD, b0 + (size_t)3 * HHD, w.z_i);
            // 3) aggr0_j -> z_j
            fused_aggr4d<<<NN / 4, 256, 0, stream>>>(
                w.rowptr[1], w.srcs[1], w.xl3, w.xr3, att0 + (size_t)1 * HHD,
                w.rowptr[2], w.srcs[2], w.xl4, w.xr4, att0 + (size_t)2 * HHD,
                w.acc, 1, b0 + (size_t)1 * HHD, b0 + (size_t)2 * HHD,
                w.z_j, nullptr, nullptr);
            // 4) ALL 8 L1 GEMM slices in one z=8 launch
            dim3 g8(HHD / 128, (NN + 127) / 128, 8);
            gemm_mfma_L1x8<<<g8, 256, 0, stream>>>(
                w.z_i, w.z_j, w.wt1l_h, w.wt1l_l, w.wt1r_h, w.wt1r_l,
                w.xl, w.xr, w.xl2, w.xr2, w.xl3, w.xr3, w.xl4, w.xr4,
                NN, CD, HHD);
            // 5) aggr1_i -> acc; pool_i   (acc reuse is stream-ordered safe)
            fused_aggr4d<<<NN / 4, 256, 0, stream>>>(
                w.rowptr[0], w.srcs[0], w.xl, w.xr, att1 + (size_t)0 * HHD,
                w.rowptr[3], w.srcs[3], w.xl2, w.xr2, att1 + (size_t)3 * HHD,
                w.acc, 2, b1 + (size_t)0 * HHD, b1 + (size_t)3 * HHD,
                nullptr, nullptr, nullptr);
            pool_reduce<<<BG, 512, 0, stream>>>(w.acc, batch_i, w.pool_i);
            // 6) aggr1_j -> acc; pool_j
            fused_aggr4d<<<NN / 4, 256, 0, stream>>>(
                w.rowptr[1], w.srcs[1], w.xl3, w.xr3, att1 + (size_t)1 * HHD,
                w.rowptr[2], w.srcs[2], w.xl4, w.xr4, att1 + (size_t)2 * HHD,
                w.acc, 2, b1 + (size_t)1 * HHD, b1 + (size_t)2 * HHD,
                nullptr, nullptr, nullptr);
            pool_reduce<<<BG, 512, 0, stream>>>(w.acc, batch_j, w.pool_j);
        } else if (fat_m) {
            run_group_fat_m<float, false>(srcA0_i, dstA0_i, rp_i, sr_i, rids_i, FD,
                                          w.wt0l_h, w.wt0l_l, w.wt0r_h, w.wt0r_l,
                                          att0, b0, 1, w.z_i, nullptr, nullptr, w, stream);
            run_group_fat_m<float, false>(srcA0_j, dstA0_j, rp_j, sr_j, rids_j, FD,
                                          w.wt0l_h, w.wt0l_l, w.wt0r_h, w.wt0r_l,
                                          att0, b0, 1, w.z_j, nullptr, nullptr, w, stream);
            run_group_fat_m<unsigned short, true>(srcA1_i, dstA1_i, rp_i, sr_i, rids_i, CD,
                                                  w.wt1l_h, w.wt1l_l, w.wt1r_h, w.wt1r_l,
                                                  att1, b1, 2, nullptr, batch_i, w.pool_i, w, stream);
            pool_reduce<<<BG, 512, 0, stream>>>(w.acc, batch_i, w.pool_i);
            run_group_fat_m<unsigned short, true>(srcA1_j, dstA1_j, rp_j, sr_j, rids_j, CD,
                                                  w.wt1l_h, w.wt1l_l, w.wt1r_h, w.wt1r_l,
                                                  att1, b1, 2, nullptr, batch_j, w.pool_j, w, stream);
            pool_reduce<<<BG, 512, 0, stream>>>(w.acc, batch_j, w.pool_j);
        } else {
            run_group_fat_t<float, false>(srcA0_i, dstA0_i, rp_i, sr_i, rids_i, FD,
                                          w.wt0l_h, w.wt0l_l, w.wt0r_h, w.wt0r_l,
                                          att0, b0, 1, w.z_i, nullptr, nullptr, w, stream);
            run_group_fat_t<float, false>(srcA0_j, dstA0_j, rp_j, sr_j, rids_j, FD,
                                          w.wt0l_h, w.wt0l_l, w.wt0r_h, w.wt0r_l,
                                          att0, b0, 1, w.z_j, nullptr, nullptr, w, stream);
            run_group_fat_t<unsigned short, true>(srcA1_i, dstA1_i, rp_i, sr_i, rids_i, CD,
                                                  w.wt1l_h, w.wt1l_l, w.wt1r_h, w.wt1r_l,
                                                  att1, b1, 2, nullptr, batch_i, w.pool_i, w, stream);
            pool_reduce<<<BG, 512, 0, stream>>>(w.acc, batch_i, w.pool_i);
            run_group_fat_t<unsigned short, true>(srcA1_j, dstA1_j, rp_j, sr_j, rids_j, CD,
                                                  w.wt1l_h, w.wt1l_l, w.wt1r_h, w.wt1r_l,
                                                  att1, b1, 2, nullptr, batch_j, w.pool_j, w, stream);
            pool_reduce<<<BG, 512, 0, stream>>>(w.acc, batch_j, w.pool_j);
        }
    } else if (fat) {
        if (ncsr == 4) {
            for (int r = 0; r < 4; ++r)
                build_csr(eis_all[r], w.rowptr[r], w.srcs[r], w.cnt, w.cursor, stream);
            const int* rp_i[2] = { w.rowptr[0], w.rowptr[3] };
            const unsigned short* sr_i[2] = { w.srcs[0], w.srcs[3] };
            const int* rp_j[2] = { w.rowptr[1], w.rowptr[2] };
            const unsigned short* sr_j[2] = { w.srcs[1], w.srcs[2] };
            run_group_fat<float, false>(srcA0_i, dstA0_i, rp_i, sr_i, rids_i, FD,
                                        Wl0, Wr0, att0, b0, 1, w.z_i, nullptr, nullptr, w, stream);
            run_group_fat<float, false>(srcA0_j, dstA0_j, rp_j, sr_j, rids_j, FD,
                                        Wl0, Wr0, att0, b0, 1, w.z_j, nullptr, nullptr, w, stream);
            run_group_fat<unsigned short, true>(srcA1_i, dstA1_i, rp_i, sr_i, rids_i, CD,
                                                Wl1, Wr1, att1, b1, 2, nullptr, batch_i, w.pool_i, w, stream);
            pool_reduce<<<BG, 512, 0, stream>>>(w.acc, batch_i, w.pool_i);
            run_group_fat<unsigned short, true>(srcA1_j, dstA1_j, rp_j, sr_j, rids_j, CD,
                                                Wl1, Wr1, att1, b1, 2, nullptr, batch_j, w.pool_j, w, stream);
            pool_reduce<<<BG, 512, 0, stream>>>(w.acc, batch_j, w.pool_j);
        } else {
            for (int pass = 0; pass < 4; ++pass) {
                const int* rids = (pass & 1) ? rids_j : rids_i;
                for (int q = 0; q < 2; ++q) {
                    int r = rids[q];
                    build_csr(eis_all[r], w.rowptr[0], w.srcs[0], w.cnt, w.cursor, stream);
                    dim3 gg(HHD / 64, (NN + 63) / 64, 2);
                    if (pass < 2) {
                        const float* sa = (pass == 0) ? srcA0_i[q] : srcA0_j[q];
                        const float* da = (pass == 0) ? dstA0_i[q] : dstA0_j[q];
                        gemm_mfma<float, false><<<gg, 256, 0, stream>>>(
                            sa, da, Wl0 + (size_t)r * FD * HHD, Wr0 + (size_t)r * FD * HHD,
                            HHD, w.xl, w.xr, NN, FD, HHD);
                        fused_aggr4<<<NN / 4, 256, 0, stream>>>(
                            w.rowptr[0], w.srcs[0], w.xl, w.xr, att0 + (size_t)r * HHD,
                            w.acc, q, (q == 1) ? 1 : 0,
                            b0 + (size_t)rids[0] * HHD, b0 + (size_t)rids[1] * HHD,
                            (pass == 0) ? w.z_i : w.z_j, nullptr, nullptr);
                    } else {
                        const unsigned short* sa = (pass == 2) ? srcA1_i[q] : srcA1_j[q];
                        const unsigned short* da = (pass == 2) ? dstA1_i[q] : dstA1_j[q];
                        gemm_mfma<unsigned short, true><<<gg, 256, 0, stream>>>(
                            sa, da, Wl1 + (size_t)r * CD * HHD, Wr1 + (size_t)r * CD * HHD,
                            HHD, w.xl, w.xr, NN, CD, HHD);
                        fused_aggr4<<<NN / 4, 256, 0, stream>>>(
                            w.rowptr[0], w.srcs[0], w.xl, w.xr, att1 + (size_t)r * HHD,
                            w.acc, q, (q == 1) ? 2 : 0,
                            b1 + (size_t)rids[0] * HHD, b1 + (size_t)rids[1] * HHD,
                            nullptr, (pass == 2) ? batch_i : batch_j,
                            (pass == 2) ? w.pool_i : w.pool_j);
                    }
                }
                if (pass == 2)
                    pool_reduce<<<BG, 512, 0, stream>>>(w.acc, batch_i, w.pool_i);
                else if (pass == 3)
                    pool_reduce<<<BG, 512, 0, stream>>>(w.acc, batch_j, w.pool_j);
            }
        }
    } else {
        const int* eis_i[2] = { ei_ii, ei_ji };
        const int* eis_j[2] = { ei_jj, ei_ij };
        run_group_thin<float, false>(srcA0_i, dstA0_i, eis_i, rids_i, FD, Wl0, Wr0, att0, b0,
                                     1, w.z_i, nullptr, nullptr, w, stream);
        run_group_thin<float, false>(srcA0_j, dstA0_j, eis_j, rids_j, FD, Wl0, Wr0, att0, b0,
                                     1, w.z_j, nullptr, nullptr, w, stream);
        run_group_thin<unsigned short, true>(srcA1_i, dstA1_i, eis_i, rids_i, CD, Wl1, Wr1, att1, b1,
                                             2, nullptr, batch_i, w.pool_i, w, stream);
        run_group_thin<unsigned short, true>(srcA1_j, dstA1_j, eis_j, rids_j, CD, Wl1, Wr1, att1, b1,
                                             2, nullptr, batch_j, w.pool_j, w, stream);
    }

    head_kernel<<<BG, 128, 0, stream>>>(w.pool_i, w.pool_j, W_out, b_out,
                                        W_i, b_i, W_j, b_j, out);
}

// Round 7
// 1237.269 us; speedup vs baseline: 1.5751x; 1.0588x over previous
//
#include <hip/hip_runtime.h>

// ---------------- problem constants ----------------
#define NN      20000     // nodes per type
#define EE      320000    // edges per relation
#define ETOT    340000    // EE + NN self loops
#define FD      512       // raw feature dim
#define HH_     4         // heads
#define CD      128       // channels per head
#define HHD     512       // H*C
#define BG      64        // batch graphs
#define INNERD  64

typedef __attribute__((ext_vector_type(8))) short bf16x8;
typedef __attribute__((ext_vector_type(4))) float f32x4;

// ---- bf16 <-> f32 via raw bits ----
__device__ __forceinline__ float bf2f(unsigned v) { return __uint_as_float(v << 16); }
__device__ __forceinline__ unsigned short f2bf(float f) {
    unsigned u = __float_as_uint(f);
    unsigned r = 0x7fffu + ((u >> 16) & 1u);
    return (unsigned short)((u + r) >> 16);
}
__device__ __forceinline__ void load8bf(const unsigned short* p, float* f) {
    uint4 u = *reinterpret_cast<const uint4*>(p);
    f[0] = bf2f(u.x & 0xffffu); f[1] = bf2f(u.x >> 16);
    f[2] = bf2f(u.y & 0xffffu); f[3] = bf2f(u.y >> 16);
    f[4] = bf2f(u.z & 0xffffu); f[5] = bf2f(u.z >> 16);
    f[6] = bf2f(u.w & 0xffffu); f[7] = bf2f(u.w >> 16);
}
// fast split f32 -> hi + lo bf16 (truncation; residual ~2^-16 relative)
__device__ __forceinline__ void split_f32(float x, unsigned short& hi, unsigned short& lo) {
    unsigned u = __float_as_uint(x);
    hi = (unsigned short)(u >> 16);
    float r = x - bf2f(hi);
    lo = (unsigned short)(__float_as_uint(r) >> 16);
}
template <typename TA>
__device__ __forceinline__ void splitA(const TA* p, size_t i, unsigned short& hi, unsigned short& lo);
template <>
__device__ __forceinline__ void splitA<float>(const float* p, size_t i, unsigned short& hi, unsigned short& lo) {
    split_f32(p[i], hi, lo);
}
template <>
__device__ __forceinline__ void splitA<unsigned short>(const unsigned short* p, size_t i, unsigned short& hi, unsigned short& lo) {
    hi = p[i]; lo = 0;
}

// ================= CSR build (per-relation kernels, fallback paths) =================
__global__ __launch_bounds__(256) void csr_hist(const int* __restrict__ ei, int* __restrict__ cnt) {
    int e = blockIdx.x * blockDim.x + threadIdx.x;
    if (e < EE) atomicAdd(&cnt[ei[EE + e]], 1);
}

__global__ __launch_bounds__(1024) void csr_scan(const int* __restrict__ cnt,
                                                 int* __restrict__ rowptr,
                                                 int* __restrict__ cursor) {
    __shared__ int part[1024];
    int t = threadIdx.x;
    int base = t * 20;
    int s = 0;
    #pragma unroll
    for (int i = 0; i < 20; ++i) { int n = base + i; if (n < NN) s += cnt[n] + 1; }
    part[t] = s;
    __syncthreads();
    for (int off = 1; off < 1024; off <<= 1) {
        int v = (t >= off) ? part[t - off] : 0;
        __syncthreads();
        part[t] += v;
        __syncthreads();
    }
    int run = (t > 0) ? part[t - 1] : 0;
    #pragma unroll
    for (int i = 0; i < 20; ++i) {
        int n = base + i;
        if (n < NN) { rowptr[n] = run; cursor[n] = run; run += cnt[n] + 1; }
    }
    if (t == 1023) rowptr[NN] = run;
}

__global__ __launch_bounds__(256) void csr_scatter16(const int* __restrict__ ei,
                                                     int* __restrict__ cursor,
                                                     unsigned short* __restrict__ srcs) {
    int idx = blockIdx.x * blockDim.x + threadIdx.x;
    if (idx >= ETOT) return;
    int src, dst;
    if (idx < EE) { src = ei[idx]; dst = ei[EE + idx]; }
    else          { src = dst = idx - EE; }
    int pos = atomicAdd(&cursor[dst], 1);
    srcs[pos] = (unsigned short)src;
}

// ================= merged CSR build: ALL 4 relations in 3 dispatches ================
__global__ __launch_bounds__(256) void csr_hist4(
    const int* __restrict__ e0, const int* __restrict__ e1,
    const int* __restrict__ e2, const int* __restrict__ e3,
    int* __restrict__ cnt)
{
    int idx = blockIdx.x * blockDim.x + threadIdx.x;
    if (idx >= 4 * EE) return;
    int r = idx / EE, e = idx - r * EE;
    const int* ei = r == 0 ? e0 : r == 1 ? e1 : r == 2 ? e2 : e3;
    atomicAdd(&cnt[r * NN + ei[EE + e]], 1);
}

__global__ __launch_bounds__(1024) void csr_scan4(const int* __restrict__ cnt_all,
                                                  int* __restrict__ rowptr_all,
                                                  int* __restrict__ cursor_all)
{
    const int r = blockIdx.x;
    const int* cnt = cnt_all + r * NN;
    int* rowptr = rowptr_all + r * (NN + 4);
    int* cursor = cursor_all + r * NN;
    __shared__ int part[1024];
    int t = threadIdx.x;
    int base = t * 20;
    int s = 0;
    #pragma unroll
    for (int i = 0; i < 20; ++i) { int n = base + i; if (n < NN) s += cnt[n] + 1; }
    part[t] = s;
    __syncthreads();
    for (int off = 1; off < 1024; off <<= 1) {
        int v = (t >= off) ? part[t - off] : 0;
        __syncthreads();
        part[t] += v;
        __syncthreads();
    }
    int run = (t > 0) ? part[t - 1] : 0;
    #pragma unroll
    for (int i = 0; i < 20; ++i) {
        int n = base + i;
        if (n < NN) { rowptr[n] = run; cursor[n] = run; run += cnt[n] + 1; }
    }
    if (t == 1023) rowptr[NN] = run;
}

__global__ __launch_bounds__(256) void csr_scatter4(
    const int* __restrict__ e0, const int* __restrict__ e1,
    const int* __restrict__ e2, const int* __restrict__ e3,
    int* __restrict__ cursor_all, unsigned short* __restrict__ srcs_all)
{
    int idx = blockIdx.x * blockDim.x + threadIdx.x;
    if (idx >= 4 * ETOT) return;
    int r = idx / ETOT, t = idx - r * ETOT;
    const int* ei = r == 0 ? e0 : r == 1 ? e1 : r == 2 ? e2 : e3;
    int src, dst;
    if (t < EE) { src = ei[t]; dst = ei[EE + t]; }
    else        { src = dst = t - EE; }
    int pos = atomicAdd(&cursor_all[r * NN + dst], 1);
    srcs_all[(size_t)r * ETOT + pos] = (unsigned short)src;
}

// ================= W pre-split: [R][K][512] f32 -> hi/lo FRAGMENT-TILED bf16 =========
__global__ __launch_bounds__(256) void wsplit_t(const float* __restrict__ W,
                                                unsigned short* __restrict__ Whi,
                                                unsigned short* __restrict__ Wlo,
                                                int K)
{
    __shared__ float tile[64][65];
    const int nt = 512 / 64;
    const int kt = K / 64;
    int bid = blockIdx.x;
    int in = bid % nt; int ik = (bid / nt) % kt; int r = bid / (nt * kt);
    int t = threadIdx.x;
    const float* Wr_ = W + (size_t)r * K * 512;
    #pragma unroll
    for (int rep = 0; rep < 16; ++rep) {
        int idx = rep * 256 + t;
        int kk = idx >> 6, nn = idx & 63;
        tile[kk][nn] = Wr_[(size_t)(ik * 64 + kk) * 512 + in * 64 + nn];
    }
    __syncthreads();
    #pragma unroll
    for (int rep = 0; rep < 16; ++rep) {
        int idx = rep * 256 + t;
        int nn = idx >> 6, kk = idx & 63;
        unsigned short h, l; split_f32(tile[kk][nn], h, l);
        int n = in * 64 + nn;
        int k = ik * 64 + kk;
        size_t o = (size_t)r * 512 * K + ((size_t)(k >> 5) * 512 + n) * 32 + (k & 31);
        Whi[o] = h; Wlo[o] = l;
    }
}

// ================= 128x128 split-bf16 MFMA GEMM core (B direct-from-L2) =============
template <typename TA, bool A_EXACT>
__device__ __forceinline__ void gemm_body(
    const TA* __restrict__ A, const unsigned short* __restrict__ Bhg,
    const unsigned short* __restrict__ Blg, unsigned short* __restrict__ C,
    int bx, int by, int M, int K, int N)
{
    __shared__ unsigned short Ah[128][40];
    __shared__ unsigned short Al[A_EXACT ? 1 : 128][40];

    const int tid = threadIdx.x;
    const int wave = tid >> 6, lane = tid & 63;
    const int quad = lane >> 4, lrow = lane & 15;
    const int wr = (wave >> 1) * 64, wc = (wave & 1) * 64;
    const int tileM = by * 128, tileN = bx * 128;

    const int srow = tid >> 1;
    const int sks  = (tid & 1) * 16;
    const int sgm  = tileM + srow;

    const size_t bfrag = ((size_t)(tileN + wc + lrow) << 5) + quad * 8;
    const size_t kblk  = (size_t)N << 5;

    f32x4 acc[4][4] = {};

    for (int k0 = 0; k0 < K; k0 += 32) {
        if constexpr (!A_EXACT) {
            bf16x8 ph[2] = {{}, {}}, pl[2] = {{}, {}};
            if (sgm < M) {
                const float* Ap = (const float*)A + (size_t)sgm * K + k0 + sks;
                #pragma unroll
                for (int s = 0; s < 2; ++s) {
                    float4 f0 = reinterpret_cast<const float4*>(Ap)[2 * s];
                    float4 f1 = reinterpret_cast<const float4*>(Ap)[2 * s + 1];
                    float xv[8] = {f0.x, f0.y, f0.z, f0.w, f1.x, f1.y, f1.z, f1.w};
                    #pragma unroll
                    for (int pp = 0; pp < 4; ++pp) {
                        unsigned u0 = __float_as_uint(xv[2 * pp]);
                        unsigned u1 = __float_as_uint(xv[2 * pp + 1]);
                        reinterpret_cast<unsigned*>(&ph[s])[pp] =
                            __builtin_amdgcn_perm(u1, u0, 0x07060302u);
                        float r0 = xv[2 * pp]     - __uint_as_float(u0 & 0xffff0000u);
                        float r1 = xv[2 * pp + 1] - __uint_as_float(u1 & 0xffff0000u);
                        reinterpret_cast<unsigned*>(&pl[s])[pp] =
                            __builtin_amdgcn_perm(__float_as_uint(r1), __float_as_uint(r0), 0x07060302u);
                    }
                }
            }
            *reinterpret_cast<bf16x8*>(&Ah[srow][sks])     = ph[0];
            *reinterpret_cast<bf16x8*>(&Ah[srow][sks + 8]) = ph[1];
            *reinterpret_cast<bf16x8*>(&Al[srow][sks])     = pl[0];
            *reinterpret_cast<bf16x8*>(&Al[srow][sks + 8]) = pl[1];
        } else {
            bf16x8 v0 = {}, v1 = {};
            if (sgm < M) {
                const unsigned short* Ap = (const unsigned short*)A + (size_t)sgm * K + k0 + sks;
                v0 = reinterpret_cast<const bf16x8*>(Ap)[0];
                v1 = reinterpret_cast<const bf16x8*>(Ap)[1];
            }
            *reinterpret_cast<bf16x8*>(&Ah[srow][sks])     = v0;
            *reinterpret_cast<bf16x8*>(&Ah[srow][sks + 8]) = v1;
        }
        bf16x8 bh[4], bl[4];
        {
            const unsigned short* Bb = Bhg + (size_t)(k0 >> 5) * kblk + bfrag;
            const unsigned short* Bc = Blg + (size_t)(k0 >> 5) * kblk + bfrag;
            #pragma unroll
            for (int ni = 0; ni < 4; ++ni) {
                bh[ni] = *reinterpret_cast<const bf16x8*>(Bb + ((size_t)ni << 9));
                bl[ni] = *reinterpret_cast<const bf16x8*>(Bc + ((size_t)ni << 9));
            }
        }
        __syncthreads();
        bf16x8 ah[4], al[4];
        #pragma unroll
        for (int mi = 0; mi < 4; ++mi) {
            ah[mi] = *reinterpret_cast<const bf16x8*>(&Ah[wr + mi * 16 + lrow][quad * 8]);
            if constexpr (!A_EXACT)
                al[mi] = *reinterpret_cast<const bf16x8*>(&Al[wr + mi * 16 + lrow][quad * 8]);
        }
        #pragma unroll
        for (int mi = 0; mi < 4; ++mi)
            #pragma unroll
            for (int ni = 0; ni < 4; ++ni) {
                acc[mi][ni] = __builtin_amdgcn_mfma_f32_16x16x32_bf16(
                    ah[mi], bh[ni], acc[mi][ni], 0, 0, 0);
                acc[mi][ni] = __builtin_amdgcn_mfma_f32_16x16x32_bf16(
                    ah[mi], bl[ni], acc[mi][ni], 0, 0, 0);
                if constexpr (!A_EXACT)
                    acc[mi][ni] = __builtin_amdgcn_mfma_f32_16x16x32_bf16(
                        al[mi], bh[ni], acc[mi][ni], 0, 0, 0);
            }
        __syncthreads();
    }
    #pragma unroll
    for (int mi = 0; mi < 4; ++mi) {
        #pragma unroll
        for (int ni = 0; ni < 4; ++ni) {
            int gcol = tileN + wc + ni * 16 + lrow;
            #pragma unroll
            for (int r = 0; r < 4; ++r) {
                int grow = tileM + wr + mi * 16 + quad * 4 + r;
                if (grow < M)
                    C[(size_t)grow * N + gcol] = f2bf(acc[mi][ni][r]);
            }
        }
    }
}

// z=2 variant (fat_t fallback path)
template <typename TA, bool A_EXACT>
__global__ __launch_bounds__(256, 3) void gemm_mfma_t(
    const TA* __restrict__ A0, const TA* __restrict__ A1,
    const unsigned short* __restrict__ B0h, const unsigned short* __restrict__ B0l,
    const unsigned short* __restrict__ B1h, const unsigned short* __restrict__ B1l,
    unsigned short* __restrict__ C0, unsigned short* __restrict__ C1,
    int M, int K, int N)
{
    const int gx = gridDim.x, gy = gridDim.y;
    const int nwg = gx * gy * (int)gridDim.z;
    int b = ((int)blockIdx.z * gy + blockIdx.y) * gx + blockIdx.x;
    int xcd = b & 7, q8 = nwg >> 3, r8 = nwg & 7;
    int work = (xcd < r8 ? xcd * (q8 + 1) : r8 * (q8 + 1) + (xcd - r8) * q8) + (b >> 3);
    int bx = work % gx; int t2 = work / gx; int by = t2 % gy; int bz = t2 / gy;

    const TA* A = bz ? A1 : A0;
    const unsigned short* Bhg = bz ? B1h : B0h;
    const unsigned short* Blg = bz ? B1l : B0l;
    unsigned short* C = bz ? C1 : C0;
    gemm_body<TA, A_EXACT>(A, Bhg, Blg, C, bx, by, M, K, N);
}

// z=4 variant (one dispatch covers 4 GEMM slices)
template <typename TA, bool A_EXACT>
__global__ __launch_bounds__(256, 3) void gemm_mfma_t4(
    const TA* __restrict__ A0, const TA* __restrict__ A1,
    const TA* __restrict__ A2, const TA* __restrict__ A3,
    const unsigned short* __restrict__ B0h, const unsigned short* __restrict__ B0l,
    const unsigned short* __restrict__ B1h, const unsigned short* __restrict__ B1l,
    const unsigned short* __restrict__ B2h, const unsigned short* __restrict__ B2l,
    const unsigned short* __restrict__ B3h, const unsigned short* __restrict__ B3l,
    unsigned short* __restrict__ C0, unsigned short* __restrict__ C1,
    unsigned short* __restrict__ C2, unsigned short* __restrict__ C3,
    int M, int K, int N)
{
    const int gx = gridDim.x, gy = gridDim.y;
    const int nwg = gx * gy * (int)gridDim.z;
    int b = ((int)blockIdx.z * gy + blockIdx.y) * gx + blockIdx.x;
    int xcd = b & 7, q8 = nwg >> 3, r8 = nwg & 7;
    int work = (xcd < r8 ? xcd * (q8 + 1) : r8 * (q8 + 1) + (xcd - r8) * q8) + (b >> 3);
    int bx = work % gx; int t2 = work / gx; int by = t2 % gy; int bz = t2 / gy;

    const TA* A = bz == 0 ? A0 : bz == 1 ? A1 : bz == 2 ? A2 : A3;
    const unsigned short* Bhg = bz == 0 ? B0h : bz == 1 ? B1h : bz == 2 ? B2h : B3h;
    const unsigned short* Blg = bz == 0 ? B0l : bz == 1 ? B1l : bz == 2 ? B2l : B3l;
    unsigned short* C = bz == 0 ? C0 : bz == 1 ? C1 : bz == 2 ? C2 : C3;
    gemm_body<TA, A_EXACT>(A, Bhg, Blg, C, bx, by, M, K, N);
}

// z=8 variant: ALL 8 L1 GEMM slices in one dispatch (fat_f fallback path)
__global__ __launch_bounds__(256, 3) void gemm_mfma_L1x8(
    const unsigned short* __restrict__ zi, const unsigned short* __restrict__ zj,
    const unsigned short* __restrict__ Wlh, const unsigned short* __restrict__ Wll,
    const unsigned short* __restrict__ Wrh, const unsigned short* __restrict__ Wrl,
    unsigned short* __restrict__ C0, unsigned short* __restrict__ C1,
    unsigned short* __restrict__ C2, unsigned short* __restrict__ C3,
    unsigned short* __restrict__ C4, unsigned short* __restrict__ C5,
    unsigned short* __restrict__ C6, unsigned short* __restrict__ C7,
    int M, int K, int N)
{
    const int gx = gridDim.x, gy = gridDim.y;
    const int nwg = gx * gy * (int)gridDim.z;
    int b = ((int)blockIdx.z * gy + blockIdx.y) * gx + blockIdx.x;
    int xcd = b & 7, q8 = nwg >> 3, r8 = nwg & 7;
    int work = (xcd < r8 ? xcd * (q8 + 1) : r8 * (q8 + 1) + (xcd - r8) * q8) + (b >> 3);
    int bx = work % gx; int t2 = work / gx; int by = t2 % gy; int bz = t2 / gy;

    int rr = bz >> 1;
    int rel = rr == 0 ? 0 : rr == 1 ? 3 : rr == 2 ? 1 : 2;
    bool aj = (bz == 2 || bz == 4 || bz == 5 || bz == 7);
    const unsigned short* A = aj ? zj : zi;
    size_t off = (size_t)rel * HHD * K;
    const unsigned short* Bh = ((bz & 1) ? Wrh : Wlh) + off;
    const unsigned short* Bl = ((bz & 1) ? Wrl : Wll) + off;
    unsigned short* C = bz == 0 ? C0 : bz == 1 ? C1 : bz == 2 ? C2 : bz == 3 ? C3
                      : bz == 4 ? C4 : bz == 5 ? C5 : bz == 6 ? C6 : C7;
    gemm_body<unsigned short, true>(A, Bh, Bl, C, bx, by, M, K, N);
}

// ================= OLD 64x64 split-bf16 GEMM (deep fallback; raw f32 W) =============
template <typename TA, bool A_EXACT>
__global__ __launch_bounds__(256) void gemm_mfma(
    const TA* __restrict__ A0, const TA* __restrict__ A1,
    const float* __restrict__ B0, const float* __restrict__ B1, int ldb,
    unsigned short* __restrict__ C0, unsigned short* __restrict__ C1,
    int M, int K, int N)
{
    const TA* A = blockIdx.z ? A1 : A0;
    const float* B = blockIdx.z ? B1 : B0;
    unsigned short* C = blockIdx.z ? C1 : C0;

    __shared__ unsigned short Ah[64][40];
    __shared__ unsigned short Al[64][40];
    __shared__ unsigned short Bh[64][40];
    __shared__ unsigned short Bl[64][40];
    const int tid = threadIdx.x;
    const int wave = tid >> 6, lane = tid & 63;
    const int quad = lane >> 4, lrow = lane & 15;
    const int tileM = blockIdx.y * 64, tileN = blockIdx.x * 64;
    const int wm = (wave >> 1) * 32, wn = (wave & 1) * 32;

    f32x4 acc[2][2] = {};

    const int am = tid >> 2;
    const int aks = (tid & 3) * 8;
    const int bn = tid & 63;
    const int bk0 = (tid >> 6) * 8;

    for (int k0 = 0; k0 < K; k0 += 32) {
        {
            int gm = tileM + am;
            bf16x8 ph = {}, pl = {};
            if (gm < M) {
                #pragma unroll
                for (int j = 0; j < 8; ++j) {
                    unsigned short h, l;
                    splitA(A, (size_t)gm * K + k0 + aks + j, h, l);
                    ph[j] = (short)h; pl[j] = (short)l;
                }
            }
            *reinterpret_cast<bf16x8*>(&Ah[am][aks]) = ph;
            if (!A_EXACT) *reinterpret_cast<bf16x8*>(&Al[am][aks]) = pl;
        }
        {
            bf16x8 ph, pl;
            #pragma unroll
            for (int j = 0; j < 8; ++j) {
                unsigned short h, l;
                split_f32(B[(size_t)(k0 + bk0 + j) * ldb + tileN + bn], h, l);
                ph[j] = (short)h; pl[j] = (short)l;
            }
            *reinterpret_cast<bf16x8*>(&Bh[bn][bk0]) = ph;
            *reinterpret_cast<bf16x8*>(&Bl[bn][bk0]) = pl;
        }
        __syncthreads();
        bf16x8 ah[2], al[2], bh[2], bl[2];
        #pragma unroll
        for (int mi = 0; mi < 2; ++mi) {
            ah[mi] = *reinterpret_cast<const bf16x8*>(&Ah[wm + mi * 16 + lrow][quad * 8]);
            if (!A_EXACT)
                al[mi] = *reinterpret_cast<const bf16x8*>(&Al[wm + mi * 16 + lrow][quad * 8]);
        }
        #pragma unroll
        for (int ni = 0; ni < 2; ++ni) {
            bh[ni] = *reinterpret_cast<const bf16x8*>(&Bh[wn + ni * 16 + lrow][quad * 8]);
            bl[ni] = *reinterpret_cast<const bf16x8*>(&Bl[wn + ni * 16 + lrow][quad * 8]);
        }
        #pragma unroll
        for (int mi = 0; mi < 2; ++mi)
            #pragma unroll
            for (int ni = 0; ni < 2; ++ni) {
                acc[mi][ni] = __builtin_amdgcn_mfma_f32_16x16x32_bf16(
                    ah[mi], bh[ni], acc[mi][ni], 0, 0, 0);
                acc[mi][ni] = __builtin_amdgcn_mfma_f32_16x16x32_bf16(
                    ah[mi], bl[ni], acc[mi][ni], 0, 0, 0);
                if (!A_EXACT)
                    acc[mi][ni] = __builtin_amdgcn_mfma_f32_16x16x32_bf16(
                        al[mi], bh[ni], acc[mi][ni], 0, 0, 0);
            }
        __syncthreads();
    }
    #pragma unroll
    for (int mi = 0; mi < 2; ++mi) {
        #pragma unroll
        for (int ni = 0; ni < 2; ++ni) {
            int gcol = tileN + wn + ni * 16 + lrow;
            #pragma unroll
            for (int r = 0; r < 4; ++r) {
                int grow = tileM + wm + mi * 16 + quad * 4 + r;
                if (grow < M)
                    C[(size_t)grow * N + gcol] = f2bf(acc[mi][ni][r]);
            }
        }
    }
}

// ================= THIN: fused GATv2 pass, one head (deep fallback) =================
__global__ __launch_bounds__(256) void fused_aggr1(
    const int* __restrict__ rowptr, const unsigned short* __restrict__ srcs,
    const unsigned short* __restrict__ xl, const unsigned short* __restrict__ xr,
    const float* __restrict__ att,
    float* __restrict__ acc, int add_in, int fin_mode,
    const float* __restrict__ bA, const float* __restrict__ bB,
    unsigned short* __restrict__ z,
    const int* __restrict__ batch, float* __restrict__ pool)
{
    int dst = (int)((blockIdx.x * (size_t)blockDim.x + threadIdx.x) >> 6);
    int lane = threadIdx.x & 63;
    if (dst >= NN) return;
    int beg = rowptr[dst], end = rowptr[dst + 1];

    unsigned ub = *reinterpret_cast<const unsigned*>(xr + (size_t)dst * CD + lane * 2);
    float br0 = bf2f(ub & 0xffffu), br1 = bf2f(ub >> 16);
    float ta0 = att[lane * 2], ta1 = att[lane * 2 + 1];

    float n0 = 0.f, n1 = 0.f, den = 0.f;
    for (int k = beg; k < end; ++k) {
        int src = srcs[k];
        unsigned ua = *reinterpret_cast<const unsigned*>(xl + (size_t)src * CD + lane * 2);
        float a0 = bf2f(ua & 0xffffu), a1 = bf2f(ua >> 16);
        float v0 = a0 + br0, v1 = a1 + br1;
        v0 = (v0 > 0.f) ? v0 : 0.2f * v0;
        v1 = (v1 > 0.f) ? v1 : 0.2f * v1;
        float d = v0 * ta0 + v1 * ta1;
        #pragma unroll
        for (int off = 1; off < 64; off <<= 1)
            d += __shfl_xor(d, off);
        float p = expf(d);
        n0 += p * a0; n1 += p * a1; den += p;
    }
    float o0 = n0 / den, o1 = n1 / den;
    size_t ai = (size_t)dst * CD + lane * 2;
    if (add_in) { o0 += acc[ai]; o1 += acc[ai + 1]; }
    if (fin_mode == 0) {
        acc[ai] = o0; acc[ai + 1] = o1;
    } else {
        int c0 = lane * 2;
        float bb0 = 0.f, bb1 = 0.f;
        #pragma unroll
        for (int h = 0; h < HH_; ++h) {
            bb0 += bA[h * CD + c0]     + bB[h * CD + c0];
            bb1 += bA[h * CD + c0 + 1] + bB[h * CD + c0 + 1];
        }
        o0 = tanhf(o0 + bb0);
        o1 = tanhf(o1 + bb1);
        if (fin_mode == 1) {
            z[ai] = f2bf(o0); z[ai + 1] = f2bf(o1);
        } else {
            int b = batch[dst];
            atomicAdd(&pool[(size_t)b * CD + c0],     o0);
            atomicAdd(&pool[(size_t)b * CD + c0 + 1], o1);
        }
    }
}

// ================= GATv2 aggregation helpers =================
__device__ __forceinline__ float edge_logit(const float* a, const float* br, const float* ta) {
    float d = 0.f;
    #pragma unroll
    for (int j = 0; j < 8; ++j) {
        float v = a[j] + br[j];
        v = fmaxf(v, 0.2f * v);
        d += v * ta[j];
    }
    return d;
}
__device__ __forceinline__ float quad_reduce(float d) {
    d += __shfl_xor(d, 1);
    d += __shfl_xor(d, 2);
    d += __shfl_xor(d, 4);
    d += __shfl_xor(d, 8);
    return d;
}
// drain [k,e) edges of one relation (2x unrolled + tail); k-order accumulation
__device__ __forceinline__ void gat_drain(
    const unsigned short* __restrict__ sr, const unsigned short* __restrict__ xl,
    const float* br, const float* ta, int k, int e, float* n, float& den, int lane)
{
    for (; k + 2 <= e; k += 2) {
        int s0 = sr[k], s1 = sr[k + 1];
        float A0[8], A1[8];
        load8bf(xl + (size_t)s0 * HHD + lane * 8, A0);
        load8bf(xl + (size_t)s1 * HHD + lane * 8, A1);
        float d0 = quad_reduce(edge_logit(A0, br, ta));
        float d1 = quad_reduce(edge_logit(A1, br, ta));
        float p0 = __expf(d0), p1 = __expf(d1);
        den += p0;
        #pragma unroll
        for (int j = 0; j < 8; ++j) n[j] += p0 * A0[j];
        den += p1;
        #pragma unroll
        for (int j = 0; j < 8; ++j) n[j] += p1 * A1[j];
    }
    if (k < e) {
        int s0 = sr[k];
        float A0[8];
        load8bf(xl + (size_t)s0 * HHD + lane * 8, A0);
        float d0 = quad_reduce(edge_logit(A0, br, ta));
        float p0 = __expf(d0);
        den += p0;
        #pragma unroll
        for (int j = 0; j < 8; ++j) n[j] += p0 * A0[j];
    }
}

// single-relation pass (fallback)
__device__ __forceinline__ void gat_rel(
    const int* __restrict__ rp, const unsigned short* __restrict__ sr,
    const unsigned short* __restrict__ xl, const unsigned short* __restrict__ xr,
    const float* __restrict__ att, int dst, int lane, float* o)
{
    int beg = rp[dst], end = rp[dst + 1];
    float br[8], ta[8];
    load8bf(xr + (size_t)dst * HHD + lane * 8, br);
    #pragma unroll
    for (int j = 0; j < 8; ++j) ta[j] = att[lane * 8 + j];
    float n[8] = {}; float den = 0.f;
    gat_drain(sr, xl, br, ta, beg, end, n, den, lane);
    float inv = 1.f / den;
    #pragma unroll
    for (int j = 0; j < 8; ++j) {
        o[j] = n[j] * inv;
        o[j] += __shfl_xor(o[j], 16);
        o[j] += __shfl_xor(o[j], 32);
    }
}

// DUAL-relation pass: interleave both relations' edge loops (4 gathers in flight).
// Per-relation accumulation order is unchanged -> numerically identical.
__device__ __forceinline__ void gat_rel2(
    const int* __restrict__ rp0, const unsigned short* __restrict__ sr0,
    const unsigned short* __restrict__ xl0, const unsigned short* __restrict__ xr0,
    const float* __restrict__ attA,
    const int* __restrict__ rp1, const unsigned short* __restrict__ sr1,
    const unsigned short* __restrict__ xl1, const unsigned short* __restrict__ xr1,
    const float* __restrict__ attB,
    int dst, int lane, float* o0, float* o1)
{
    int k0 = rp0[dst], e0 = rp0[dst + 1];
    int k1 = rp1[dst], e1 = rp1[dst + 1];
    float br0[8], br1[8], ta0[8], ta1[8];
    load8bf(xr0 + (size_t)dst * HHD + lane * 8, br0);
    load8bf(xr1 + (size_t)dst * HHD + lane * 8, br1);
    #pragma unroll
    for (int j = 0; j < 8; ++j) { ta0[j] = attA[lane * 8 + j]; ta1[j] = attB[lane * 8 + j]; }

    float n0[8] = {}, n1[8] = {};
    float den0 = 0.f, den1 = 0.f;

    while (k0 + 2 <= e0 && k1 + 2 <= e1) {
        int sa0 = sr0[k0], sa1 = sr0[k0 + 1];
        int sb0 = sr1[k1], sb1 = sr1[k1 + 1];
        float A0[8], A1[8], B0[8], B1[8];
        load8bf(xl0 + (size_t)sa0 * HHD + lane * 8, A0);
        load8bf(xl0 + (size_t)sa1 * HHD + lane * 8, A1);
        load8bf(xl1 + (size_t)sb0 * HHD + lane * 8, B0);
        load8bf(xl1 + (size_t)sb1 * HHD + lane * 8, B1);
        float dA0 = quad_reduce(edge_logit(A0, br0, ta0));
        float dA1 = quad_reduce(edge_logit(A1, br0, ta0));
        float dB0 = quad_reduce(edge_logit(B0, br1, ta1));
        float dB1 = quad_reduce(edge_logit(B1, br1, ta1));
        float pA0 = __expf(dA0), pA1 = __expf(dA1);
        float pB0 = __expf(dB0), pB1 = __expf(dB1);
        den0 += pA0;
        #pragma unroll
        for (int j = 0; j < 8; ++j) n0[j] += pA0 * A0[j];
        den0 += pA1;
        #pragma unroll
        for (int j = 0; j < 8; ++j) n0[j] += pA1 * A1[j];
        den1 += pB0;
        #pragma unroll
        for (int j = 0; j < 8; ++j) n1[j] += pB0 * B0[j];
        den1 += pB1;
        #pragma unroll
        for (int j = 0; j < 8; ++j) n1[j] += pB1 * B1[j];
        k0 += 2; k1 += 2;
    }
    gat_drain(sr0, xl0, br0, ta0, k0, e0, n0, den0, lane);
    gat_drain(sr1, xl1, br1, ta1, k1, e1, n1, den1, lane);

    float i0 = 1.f / den0, i1 = 1.f / den1;
    #pragma unroll
    for (int j = 0; j < 8; ++j) {
        o0[j] = n0[j] * i0;
        o0[j] += __shfl_xor(o0[j], 16);
        o0[j] += __shfl_xor(o0[j], 32);
        o1[j] = n1[j] * i1;
        o1[j] += __shfl_xor(o1[j], 16);
        o1[j] += __shfl_xor(o1[j], 32);
    }
}

// dual-relation aggr body (shared by standalone / fused / paired kernels)
__device__ __forceinline__ void aggr4d_body(
    int dst, int lane,
    const int* __restrict__ rp0, const unsigned short* __restrict__ sr0,
    const unsigned short* __restrict__ xl0, const unsigned short* __restrict__ xr0,
    const float* __restrict__ attA,
    const int* __restrict__ rp1, const unsigned short* __restrict__ sr1,
    const unsigned short* __restrict__ xl1, const unsigned short* __restrict__ xr1,
    const float* __restrict__ attB,
    float* __restrict__ acc, int fin_mode,
    const float* __restrict__ bA, const float* __restrict__ bB,
    unsigned short* __restrict__ z)
{
    float o0[8], o1[8];
    gat_rel2(rp0, sr0, xl0, xr0, attA, rp1, sr1, xl1, xr1, attB, dst, lane, o0, o1);
    #pragma unroll
    for (int j = 0; j < 8; ++j) o1[j] += o0[j];

    if (lane < 16) {
        size_t ai = (size_t)dst * CD + lane * 8;
        int c0 = lane * 8;
        #pragma unroll
        for (int j = 0; j < 8; ++j) {
            float bb = 0.f;
            #pragma unroll
            for (int h = 0; h < HH_; ++h)
                bb += bA[h * CD + c0 + j] + bB[h * CD + c0 + j];
            o1[j] = tanhf(o1[j] + bb);
        }
        if (fin_mode == 1) {
            #pragma unroll
            for (int j = 0; j < 8; ++j) z[ai + j] = f2bf(o1[j]);
        } else {
            #pragma unroll
            for (int j = 0; j < 8; ++j) acc[ai + j] = o1[j];
        }
    }
}

// ================= FAT: single-relation pass (fat_t fallback) =================
__global__ __launch_bounds__(256) void fused_aggr4(
    const int* __restrict__ rowptr, const unsigned short* __restrict__ srcs,
    const unsigned short* __restrict__ xl, const unsigned short* __restrict__ xr,
    const float* __restrict__ att,
    float* __restrict__ acc, int add_in, int fin_mode,
    const float* __restrict__ bA, const float* __restrict__ bB,
    unsigned short* __restrict__ z,
    const int* __restrict__ batch, float* __restrict__ pool)
{
    int dst = (int)((blockIdx.x * (size_t)blockDim.x + threadIdx.x) >> 6);
    int lane = threadIdx.x & 63;
    if (dst >= NN) return;

    float o[8];
    gat_rel(rowptr, srcs, xl, xr, att, dst, lane, o);

    if (lane < 16) {
        size_t ai = (size_t)dst * CD + lane * 8;
        if (add_in) {
            #pragma unroll
            for (int j = 0; j < 8; ++j) o[j] += acc[ai + j];
        }
        if (fin_mode == 0) {
            #pragma unroll
            for (int j = 0; j < 8; ++j) acc[ai + j] = o[j];
        } else {
            int c0 = lane * 8;
            #pragma unroll
            for (int j = 0; j < 8; ++j) {
                float bb = 0.f;
                #pragma unroll
                for (int h = 0; h < HH_; ++h)
                    bb += bA[h * CD + c0 + j] + bB[h * CD + c0 + j];
                o[j] = tanhf(o[j] + bb);
            }
            if (fin_mode == 1) {
                #pragma unroll
                for (int j = 0; j < 8; ++j) z[ai + j] = f2bf(o[j]);
            } else {
                #pragma unroll
                for (int j = 0; j < 8; ++j) acc[ai + j] = o[j];
            }
        }
    }
}

// ================= FAT merged: BOTH relations of a group in one dispatch ============
__global__ __launch_bounds__(256) void fused_aggr4d(
    const int* __restrict__ rp0, const unsigned short* __restrict__ sr0,
    const unsigned short* __restrict__ xl0, const unsigned short* __restrict__ xr0,
    const float* __restrict__ attA,
    const int* __restrict__ rp1, const unsigned short* __restrict__ sr1,
    const unsigned short* __restrict__ xl1, const unsigned short* __restrict__ xr1,
    const float* __restrict__ attB,
    float* __restrict__ acc, int fin_mode,
    const float* __restrict__ bA, const float* __restrict__ bB,
    unsigned short* __restrict__ z,
    const int* __restrict__ batch, float* __restrict__ pool)
{
    int dst = (int)((blockIdx.x * (size_t)blockDim.x + threadIdx.x) >> 6);
    int lane = threadIdx.x & 63;
    if (dst >= NN) return;
    aggr4d_body(dst, lane, rp0, sr0, xl0, xr0, attA, rp1, sr1, xl1, xr1, attB,
                acc, fin_mode, bA, bB, z);
}

// ================= PAIRED: both groups' dual-relation aggr in ONE dispatch ==========
// Independent gather work x2 resident -> more memory-level parallelism (latency-bound
// regime per R5/R6: 2.15 TB/s « 6.3 achievable, VALU 54%). Group i -> accA, j -> accB.
__global__ __launch_bounds__(256) void fused_aggr4d_pair(
    // group i
    const int* __restrict__ irp0, const unsigned short* __restrict__ isr0,
    const unsigned short* __restrict__ ixl0, const unsigned short* __restrict__ ixr0,
    const float* __restrict__ iattA,
    const int* __restrict__ irp1, const unsigned short* __restrict__ isr1,
    const unsigned short* __restrict__ ixl1, const unsigned short* __restrict__ ixr1,
    const float* __restrict__ iattB,
    float* __restrict__ accA,
    const float* __restrict__ ibA, const float* __restrict__ ibB,
    // group j
    const int* __restrict__ jrp0, const unsigned short* __restrict__ jsr0,
    const unsigned short* __restrict__ jxl0, const unsigned short* __restrict__ jxr0,
    const float* __restrict__ jattA,
    const int* __restrict__ jrp1, const unsigned short* __restrict__ jsr1,
    const unsigned short* __restrict__ jxl1, const unsigned short* __restrict__ jxr1,
    const float* __restrict__ jattB,
    float* __restrict__ accB,
    const float* __restrict__ jbA, const float* __restrict__ jbB)
{
    const int half = NN / 4;
    int lane = threadIdx.x & 63;
    if ((int)blockIdx.x < half) {
        int dst = (int)((blockIdx.x * (size_t)blockDim.x + threadIdx.x) >> 6);
        if (dst >= NN) return;
        aggr4d_body(dst, lane, irp0, isr0, ixl0, ixr0, iattA,
                    irp1, isr1, ixl1, ixr1, iattB, accA, 2, ibA, ibB, nullptr);
    } else {
        int dst = (int)(((blockIdx.x - half) * (size_t)blockDim.x + threadIdx.x) >> 6);
        if (dst >= NN) return;
        aggr4d_body(dst, lane, jrp0, jsr0, jxl0, jxr0, jattA,
                    jrp1, jsr1, jxl1, jxr1, jattB, accB, 2, jbA, jbB, nullptr);
    }
}

// ================= FUSED: GEMM (z=4 slices) + dual-relation aggr in ONE dispatch =====
template <typename TA, bool A_EXACT>
__global__ __launch_bounds__(256, 3) void gemm_aggr_fused(
    int ngemm,
    const TA* __restrict__ A0, const TA* __restrict__ A1,
    const TA* __restrict__ A2, const TA* __restrict__ A3,
    const unsigned short* __restrict__ B0h, const unsigned short* __restrict__ B0l,
    const unsigned short* __restrict__ B1h, const unsigned short* __restrict__ B1l,
    const unsigned short* __restrict__ B2h, const unsigned short* __restrict__ B2l,
    const unsigned short* __restrict__ B3h, const unsigned short* __restrict__ B3l,
    unsigned short* __restrict__ C0, unsigned short* __restrict__ C1,
    unsigned short* __restrict__ C2, unsigned short* __restrict__ C3,
    int M, int K, int N,
    const int* __restrict__ rp0, const unsigned short* __restrict__ sr0,
    const unsigned short* __restrict__ xl0, const unsigned short* __restrict__ xr0,
    const float* __restrict__ attA,
    const int* __restrict__ rp1, const unsigned short* __restrict__ sr1,
    const unsigned short* __restrict__ xl1, const unsigned short* __restrict__ xr1,
    const float* __restrict__ attB,
    float* __restrict__ acc, int fin_mode,
    const float* __restrict__ bA, const float* __restrict__ bB,
    unsigned short* __restrict__ zout)
{
    if ((int)blockIdx.x < ngemm) {
        int b = blockIdx.x;
        int xcd = b & 7, q8 = ngemm >> 3, r8 = ngemm & 7;
        int work = (xcd < r8 ? xcd * (q8 + 1) : r8 * (q8 + 1) + (xcd - r8) * q8) + (b >> 3);
        const int gx = N / 128, gy = (M + 127) / 128;
        int bx = work % gx; int t2 = work / gx; int by = t2 % gy; int bz = t2 / gy;
        const TA* A = bz == 0 ? A0 : bz == 1 ? A1 : bz == 2 ? A2 : A3;
        const unsigned short* Bh = bz == 0 ? B0h : bz == 1 ? B1h : bz == 2 ? B2h : B3h;
        const unsigned short* Bl = bz == 0 ? B0l : bz == 1 ? B1l : bz == 2 ? B2l : B3l;
        unsigned short* C = bz == 0 ? C0 : bz == 1 ? C1 : bz == 2 ? C2 : C3;
        gemm_body<TA, A_EXACT>(A, Bh, Bl, C, bx, by, M, K, N);
    } else {
        int dst = (int)(((blockIdx.x - ngemm) * (size_t)blockDim.x + threadIdx.x) >> 6);
        int lane = threadIdx.x & 63;
        if (dst >= NN) return;
        aggr4d_body(dst, lane, rp0, sr0, xl0, xr0, attA, rp1, sr1, xl1, xr1, attB,
                    acc, fin_mode, bA, bB, zout);
    }
}

// ================= pool_reduce: segmented sum over sorted batch (no atomics) ========
__global__ __launch_bounds__(512) void pool_reduce(
    const float* __restrict__ acc, const int* __restrict__ batch,
    float* __restrict__ pool)
{
    int b = blockIdx.x;
    int t = threadIdx.x & (CD - 1);
    int q = threadIdx.x >> 7;
    int lo, hi;
    { int l = 0, r = NN; while (l < r) { int m = (l + r) >> 1; if (batch[m] < b) l = m + 1; else r = m; } lo = l; }
    { int l = lo, r = NN; while (l < r) { int m = (l + r) >> 1; if (batch[m] <= b) l = m + 1; else r = m; } hi = l; }
    float s = 0.f;
    for (int nrow = lo + q; nrow < hi; nrow += 4)
        s += acc[(size_t)nrow * CD + t];
    __shared__ float red[4][CD];
    red[q][t] = s;
    __syncthreads();
    if (q == 0)
        pool[(size_t)b * CD + t] = red[0][t] + red[1][t] + red[2][t] + red[3][t];
}

// both pools in one launch (2*BG blocks)
__global__ __launch_bounds__(512) void pool_reduce2(
    const float* __restrict__ accA, const int* __restrict__ batchA, float* __restrict__ poolA,
    const float* __restrict__ accB, const int* __restrict__ batchB, float* __restrict__ poolB)
{
    int g = blockIdx.x;
    const float* acc = (g < BG) ? accA : accB;
    const int* batch = (g < BG) ? batchA : batchB;
    float* pool = (g < BG) ? poolA : poolB;
    int b = (g < BG) ? g : g - BG;
    int t = threadIdx.x & (CD - 1);
    int q = threadIdx.x >> 7;
    int lo, hi;
    { int l = 0, r = NN; while (l < r) { int m = (l + r) >> 1; if (batch[m] < b) l = m + 1; else r = m; } lo = l; }
    { int l = lo, r = NN; while (l < r) { int m = (l + r) >> 1; if (batch[m] <= b) l = m + 1; else r = m; } hi = l; }
    float s = 0.f;
    for (int nrow = lo + q; nrow < hi; nrow += 4)
        s += acc[(size_t)nrow * CD + t];
    __shared__ float red[4][CD];
    red[q][t] = s;
    __syncthreads();
    if (q == 0)
        pool[(size_t)b * CD + t] = red[0][t] + red[1][t] + red[2][t] + red[3][t];
}

// ================= head =================
__global__ __launch_bounds__(128) void head_kernel(
    const float* __restrict__ pool_i, const float* __restrict__ pool_j,
    const float* __restrict__ W_out, const float* __restrict__ b_out,
    const float* __restrict__ W_i, const float* __restrict__ b_i,
    const float* __restrict__ W_j, const float* __restrict__ b_j,
    float* __restrict__ out)
{
    int b = blockIdx.x;
    int t = threadIdx.x;
    __shared__ float pi[CD], pj[CD];
    pi[t] = tanhf(pool_i[(size_t)b * CD + t]);
    pj[t] = tanhf(pool_j[(size_t)b * CD + t]);
    __syncthreads();
    if (t < INNERD) {
        float a = b_i[t];
        for (int c = 0; c < CD; ++c) a += pi[c] * W_i[c * INNERD + t];
        out[BG + (size_t)b * INNERD + t] = a;
    } else {
        int k = t - INNERD;
        float a = b_j[k];
        for (int c = 0; c < CD; ++c) a += pj[c] * W_j[c * INNERD + k];
        out[BG + BG * INNERD + (size_t)b * INNERD + k] = a;
    }
    if (t == 0) {
        float a = b_out[0];
        for (int c = 0; c < CD; ++c) a += (pi[c] + pj[c]) * W_out[c];
        out[b] = 1.f / (1.f + expf(-a));
    }
}

// ================= host-side drivers =================
struct Ws {
    unsigned short *xl, *xr, *xl2, *xr2, *xl3, *xr3, *xl4, *xr4, *z_i, *z_j;
    float *acc, *acc2;
    int *rowptr[4];
    unsigned short *srcs[4];
    int *cnt, *cursor;
    float *pool_i, *pool_j;
    unsigned short *wt0l_h, *wt0l_l, *wt0r_h, *wt0r_l;
    unsigned short *wt1l_h, *wt1l_l, *wt1r_h, *wt1r_l;
};

static void build_csr(const int* ei, int* rowptr, unsigned short* srcs,
                      int* cnt, int* cursor, hipStream_t stream) {
    hipMemsetAsync(cnt, 0, NN * sizeof(int), stream);
    csr_hist<<<(EE + 255) / 256, 256, 0, stream>>>(ei, cnt);
    csr_scan<<<1, 1024, 0, stream>>>(cnt, rowptr, cursor);
    csr_scatter16<<<(ETOT + 255) / 256, 256, 0, stream>>>(ei, cursor, srcs);
}

// ---- MERGED group pass (fat_m fallback) ----
template <typename TA, bool A_EXACT>
static void run_group_fat_m(const TA* srcA[2], const TA* dstA[2],
                            const int* rp[2], const unsigned short* sr[2],
                            const int rids[2], int K,
                            const unsigned short* WTl_h, const unsigned short* WTl_l,
                            const unsigned short* WTr_h, const unsigned short* WTr_l,
                            const float* att, const float* bias, int fin_mode,
                            unsigned short* zout, const int* batch, float* pool,
                            const Ws& w, hipStream_t stream)
{
    dim3 gg(HHD / 128, (NN + 127) / 128, 4);
    size_t off0 = (size_t)rids[0] * HHD * K;
    size_t off1 = (size_t)rids[1] * HHD * K;
    gemm_mfma_t4<TA, A_EXACT><<<gg, 256, 0, stream>>>(
        srcA[0], dstA[0], srcA[1], dstA[1],
        WTl_h + off0, WTl_l + off0, WTr_h + off0, WTr_l + off0,
        WTl_h + off1, WTl_l + off1, WTr_h + off1, WTr_l + off1,
        w.xl, w.xr, w.xl2, w.xr2, NN, K, HHD);
    fused_aggr4d<<<NN / 4, 256, 0, stream>>>(
        rp[0], sr[0], w.xl, w.xr, att + (size_t)rids[0] * HHD,
        rp[1], sr[1], w.xl2, w.xr2, att + (size_t)rids[1] * HHD,
        w.acc, fin_mode,
        bias + (size_t)rids[0] * HHD, bias + (size_t)rids[1] * HHD,
        zout, batch, pool);
}

// ---- fat_t group pass (fallback) ----
template <typename TA, bool A_EXACT>
static void run_group_fat_t(const TA* srcA[2], const TA* dstA[2],
                            const int* rp[2], const unsigned short* sr[2],
                            const int rids[2], int K,
                            const unsigned short* WTl_h, const unsigned short* WTl_l,
                            const unsigned short* WTr_h, const unsigned short* WTr_l,
                            const float* att, const float* bias, int fin_mode,
                            unsigned short* zout, const int* batch, float* pool,
                            const Ws& w, hipStream_t stream)
{
    dim3 gg(HHD / 128, (NN + 127) / 128, 2);
    const int ablocks = NN / 4;
    for (int q = 0; q < 2; ++q) {
        int r = rids[q];
        size_t off = (size_t)r * HHD * K;
        gemm_mfma_t<TA, A_EXACT><<<gg, 256, 0, stream>>>(
            srcA[q], dstA[q],
            WTl_h + off, WTl_l + off, WTr_h + off, WTr_l + off,
            w.xl, w.xr, NN, K, HHD);
        int fm = (q == 1) ? fin_mode : 0;
        fused_aggr4<<<ablocks, 256, 0, stream>>>(
            rp[q], sr[q], w.xl, w.xr,
            att + (size_t)r * HHD,
            w.acc, q > 0 ? 1 : 0, fm,
            bias + (size_t)rids[0] * HHD, bias + (size_t)rids[1] * HHD,
            zout, batch, pool);
    }
}

// ---- OLD FAT group pass (fallback) ----
template <typename TA, bool A_EXACT>
static void run_group_fat(const TA* srcA[2], const TA* dstA[2],
                          const int* rp[2], const unsigned short* sr[2],
                          const int rids[2], int K,
                          const float* Wl, const float* Wr, const float* att,
                          const float* bias, int fin_mode,
                          unsigned short* zout, const int* batch, float* pool,
                          const Ws& w, hipStream_t stream)
{
    dim3 gg(HHD / 64, (NN + 63) / 64, 2);
    const int ablocks = NN / 4;
    for (int q = 0; q < 2; ++q) {
        int r = rids[q];
        gemm_mfma<TA, A_EXACT><<<gg, 256, 0, stream>>>(
            srcA[q], dstA[q],
            Wl + (size_t)r * K * HHD, Wr + (size_t)r * K * HHD, HHD,
            w.xl, w.xr, NN, K, HHD);
        int fm = (q == 1) ? fin_mode : 0;
        fused_aggr4<<<ablocks, 256, 0, stream>>>(
            rp[q], sr[q], w.xl, w.xr,
            att + (size_t)r * HHD,
            w.acc, q > 0 ? 1 : 0, fm,
            bias + (size_t)rids[0] * HHD, bias + (size_t)rids[1] * HHD,
            zout, batch, pool);
    }
}

// ---- THIN group pass (deep fallback) ----
template <typename TA, bool A_EXACT>
static void run_group_thin(const TA* srcA[2], const TA* dstA[2],
                           const int* eis[2], const int rids[2], int K,
                           const float* Wl, const float* Wr, const float* att,
                           const float* bias, int fin_mode,
                           unsigned short* zout, const int* batch, float* pool,
                           const Ws& w, hipStream_t stream)
{
    dim3 gg(2, (NN + 63) / 64, 2);
    const int ablocks = NN / 4;
    for (int q = 0; q < 2; ++q) {
        int r = rids[q];
        build_csr(eis[q], w.rowptr[0], w.srcs[0], w.cnt, w.cursor, stream);
        for (int h = 0; h < HH_; ++h) {
            const float* WlS = Wl + (size_t)r * K * HHD + h * CD;
            const float* WrS = Wr + (size_t)r * K * HHD + h * CD;
            gemm_mfma<TA, A_EXACT><<<gg, 256, 0, stream>>>(
                srcA[q], dstA[q], WlS, WrS, HHD, w.xl, w.xr, NN, K, CD);
            int pass = q * HH_ + h;
            int fm = (pass == 2 * HH_ - 1) ? fin_mode : 0;
            fused_aggr1<<<ablocks, 256, 0, stream>>>(
                w.rowptr[0], w.srcs[0], w.xl, w.xr,
                att + (size_t)r * HHD + h * CD,
                w.acc, pass > 0 ? 1 : 0, fm,
                bias + (size_t)rids[0] * HHD, bias + (size_t)rids[1] * HHD,
                zout, batch, pool);
        }
    }
}

extern "C" void kernel_launch(void* const* d_in, const int* in_sizes, int n_in,
                              void* d_out, int out_size, void* d_ws, size_t ws_size,
                              hipStream_t stream)
{
    const float* x_i   = (const float*)d_in[0];
    const float* x_j   = (const float*)d_in[1];
    const int* ei_ii   = (const int*)d_in[2];
    const int* ei_jj   = (const int*)d_in[3];
    const int* ei_ij   = (const int*)d_in[4];
    const int* ei_ji   = (const int*)d_in[5];
    const int* batch_i = (const int*)d_in[6];
    const int* batch_j = (const int*)d_in[7];
    const float* Wl0   = (const float*)d_in[8];
    const float* Wr0   = (const float*)d_in[9];
    const float* att0  = (const float*)d_in[10];
    const float* b0    = (const float*)d_in[11];
    const float* Wl1   = (const float*)d_in[12];
    const float* Wr1   = (const float*)d_in[13];
    const float* att1  = (const float*)d_in[14];
    const float* b1    = (const float*)d_in[15];
    const float* W_out = (const float*)d_in[16];
    const float* b_out = (const float*)d_in[17];
    const float* W_i   = (const float*)d_in[18];
    const float* b_i   = (const float*)d_in[19];
    const float* W_j   = (const float*)d_in[20];
    const float* b_j   = (const float*)d_in[21];
    float* out = (float*)d_out;

    const size_t FAT2_BYTES = (size_t)NN * HHD * 2 * 2 + (size_t)NN * CD * 4
                            + (size_t)NN * CD * 2 * 2 + 4 * (size_t)ETOT * 2
                            + 4 * (size_t)(NN + 4) * 4 + 4 * (size_t)NN * 4 * 2
                            + (size_t)BG * CD * 4 * 2;
    const size_t FAT1_BYTES = (size_t)NN * HHD * 2 * 2 + (size_t)NN * CD * 4
                            + (size_t)NN * CD * 2 * 2 + (size_t)ETOT * 2
                            + (size_t)(NN + 4) * 4 + (size_t)NN * 4 * 2
                            + (size_t)BG * CD * 4 * 2;
    const size_t WT0_ONE = (size_t)4 * 512 * 512 * 2;
    const size_t WT1_ONE = (size_t)4 * 512 * 128 * 2;
    const size_t WT_BYTES = 4 * WT0_ONE + 4 * WT1_ONE;
    const size_t X2_BYTES = 2 * (size_t)NN * HHD * 2;
    const size_t ACC2_BYTES = (size_t)NN * CD * 4;

    const int ncsr = (ws_size >= FAT2_BYTES) ? 4 : 1;
    const bool fat = (ws_size >= FAT1_BYTES);
    const bool fat_t = (ws_size >= FAT2_BYTES + WT_BYTES);
    const bool fat_m = (ws_size >= FAT2_BYTES + WT_BYTES + X2_BYTES);
    const bool fat_f = (ws_size >= FAT2_BYTES + WT_BYTES + 3 * X2_BYTES);
    const bool fat_g = (ws_size >= FAT2_BYTES + WT_BYTES + 3 * X2_BYTES + ACC2_BYTES);

    Ws w;
    char* p = (char*)d_ws;
    size_t xbytes = fat ? (size_t)NN * HHD * 2 : (size_t)NN * CD * 2;
    w.xl     = (unsigned short*)p; p += xbytes;
    w.xr     = (unsigned short*)p; p += xbytes;
    w.acc    = (float*)p;          p += (size_t)NN * CD * 4;
    w.z_i    = (unsigned short*)p; p += (size_t)NN * CD * 2;
    w.z_j    = (unsigned short*)p; p += (size_t)NN * CD * 2;
    {
        int* rowptr_all = (int*)p;            p += (size_t)ncsr * (NN + 4) * 4;
        unsigned short* srcs_all = (unsigned short*)p; p += (size_t)ncsr * ETOT * 2;
        for (int r = 0; r < 4; ++r) {
            int rr = (r < ncsr) ? r : 0;
            w.rowptr[r] = rowptr_all + (size_t)rr * (NN + 4);
            w.srcs[r]   = srcs_all + (size_t)rr * ETOT;
        }
    }
    w.cnt    = (int*)p;            p += (size_t)ncsr * NN * 4;
    w.cursor = (int*)p;            p += (size_t)ncsr * NN * 4;
    w.pool_i = (float*)p;          p += (size_t)BG * CD * 4;
    w.pool_j = (float*)p;          p += (size_t)BG * CD * 4;
    if (fat_t) {
        w.wt0l_h = (unsigned short*)p; p += WT0_ONE;
        w.wt0l_l = (unsigned short*)p; p += WT0_ONE;
        w.wt0r_h = (unsigned short*)p; p += WT0_ONE;
        w.wt0r_l = (unsigned short*)p; p += WT0_ONE;
        w.wt1l_h = (unsigned short*)p; p += WT1_ONE;
        w.wt1l_l = (unsigned short*)p; p += WT1_ONE;
        w.wt1r_h = (unsigned short*)p; p += WT1_ONE;
        w.wt1r_l = (unsigned short*)p; p += WT1_ONE;
    }
    if (fat_m) {
        w.xl2 = (unsigned short*)p; p += (size_t)NN * HHD * 2;
        w.xr2 = (unsigned short*)p; p += (size_t)NN * HHD * 2;
    }
    if (fat_f) {
        w.xl3 = (unsigned short*)p; p += (size_t)NN * HHD * 2;
        w.xr3 = (unsigned short*)p; p += (size_t)NN * HHD * 2;
        w.xl4 = (unsigned short*)p; p += (size_t)NN * HHD * 2;
        w.xr4 = (unsigned short*)p; p += (size_t)NN * HHD * 2;
    }
    if (fat_g) {
        w.acc2 = (float*)p; p += ACC2_BYTES;
    }

    hipMemsetAsync(w.pool_i, 0, (size_t)BG * CD * sizeof(float), stream);
    hipMemsetAsync(w.pool_j, 0, (size_t)BG * CD * sizeof(float), stream);

    const int* eis_all[4] = { ei_ii, ei_jj, ei_ij, ei_ji };
    const float* srcA0_i[2] = { x_i, x_j };  const float* dstA0_i[2] = { x_i, x_i };
    const float* srcA0_j[2] = { x_j, x_i };  const float* dstA0_j[2] = { x_j, x_j };
    const int rids_i[2] = { 0, 3 };
    const int rids_j[2] = { 1, 2 };
    const unsigned short* srcA1_i[2] = { w.z_i, w.z_j };
    const unsigned short* dstA1_i[2] = { w.z_i, w.z_i };
    const unsigned short* srcA1_j[2] = { w.z_j, w.z_i };
    const unsigned short* dstA1_j[2] = { w.z_j, w.z_j };

    if (fat_t) {
        // merged CSR build for all 4 relations
        hipMemsetAsync(w.cnt, 0, 4 * NN * sizeof(int), stream);
        csr_hist4<<<(4 * EE + 255) / 256, 256, 0, stream>>>(
            ei_ii, ei_jj, ei_ij, ei_ji, w.cnt);
        csr_scan4<<<4, 1024, 0, stream>>>(w.cnt, w.rowptr[0], w.cursor);
        csr_scatter4<<<(4 * ETOT + 255) / 256, 256, 0, stream>>>(
            ei_ii, ei_jj, ei_ij, ei_ji, w.cursor, w.srcs[0]);
        wsplit_t<<<4 * (FD / 64) * 8, 256, 0, stream>>>(Wl0, w.wt0l_h, w.wt0l_l, FD);
        wsplit_t<<<4 * (FD / 64) * 8, 256, 0, stream>>>(Wr0, w.wt0r_h, w.wt0r_l, FD);
        wsplit_t<<<4 * (CD / 64) * 8, 256, 0, stream>>>(Wl1, w.wt1l_h, w.wt1l_l, CD);
        wsplit_t<<<4 * (CD / 64) * 8, 256, 0, stream>>>(Wr1, w.wt1r_h, w.wt1r_l, CD);

        const int* rp_i[2] = { w.rowptr[0], w.rowptr[3] };
        const unsigned short* sr_i[2] = { w.srcs[0], w.srcs[3] };
        const int* rp_j[2] = { w.rowptr[1], w.rowptr[2] };
        const unsigned short* sr_j[2] = { w.srcs[1], w.srcs[2] };

        if (fat_g) {
            const size_t o0 = (size_t)0 * HHD * FD, o3 = (size_t)3 * HHD * FD;
            const size_t o1 = (size_t)1 * HHD * FD, o2 = (size_t)2 * HHD * FD;
            const size_t p0 = (size_t)0 * HHD * CD, p1 = (size_t)1 * HHD * CD;
            const size_t p2 = (size_t)2 * HHD * CD, p3 = (size_t)3 * HHD * CD;
            // A) GEMM0_i (z=4) -> xl,xr (rel0), xl2,xr2 (rel3)
            dim3 gg(HHD / 128, (NN + 127) / 128, 4);
            gemm_mfma_t4<float, false><<<gg, 256, 0, stream>>>(
                x_i, x_i, x_j, x_i,
                w.wt0l_h + o0, w.wt0l_l + o0, w.wt0r_h + o0, w.wt0r_l + o0,
                w.wt0l_h + o3, w.wt0l_l + o3, w.wt0r_h + o3, w.wt0r_l + o3,
                w.xl, w.xr, w.xl2, w.xr2, NN, FD, HHD);
            // B) FUSED: GEMM0_j -> xl3..xr4  ||  aggr0_i -> z_i
            const int ngemm0 = (HHD / 128) * ((NN + 127) / 128) * 4;   // 2512
            gemm_aggr_fused<float, false><<<ngemm0 + NN / 4, 256, 0, stream>>>(
                ngemm0,
                x_j, x_j, x_i, x_j,
                w.wt0l_h + o1, w.wt0l_l + o1, w.wt0r_h + o1, w.wt0r_l + o1,
                w.wt0l_h + o2, w.wt0l_l + o2, w.wt0r_h + o2, w.wt0r_l + o2,
                w.xl3, w.xr3, w.xl4, w.xr4, NN, FD, HHD,
                w.rowptr[0], w.srcs[0], w.xl, w.xr, att0 + (size_t)0 * HHD,
                w.rowptr[3], w.srcs[3], w.xl2, w.xr2, att0 + (size_t)3 * HHD,
                w.acc, 1, b0 + (size_t)0 * HHD, b0 + (size_t)3 * HHD, w.z_i);
            // C) FUSED: z_i-only L1 GEMM slices -> xl,xr,xr2,xl2  ||  aggr0_j -> z_j
            //    slices: zi@Wl1[0]->xl (rel0 src), zi@Wr1[0]->xr (rel0 dst),
            //            zi@Wr1[3]->xr2 (rel3 dst), zi@Wl1[2]->xl2 (rel2 src)
            gemm_aggr_fused<unsigned short, true><<<ngemm0 + NN / 4, 256, 0, stream>>>(
                ngemm0,
                w.z_i, w.z_i, w.z_i, w.z_i,
                w.wt1l_h + p0, w.wt1l_l + p0, w.wt1r_h + p0, w.wt1r_l + p0,
                w.wt1r_h + p3, w.wt1r_l + p3, w.wt1l_h + p2, w.wt1l_l + p2,
                w.xl, w.xr, w.xr2, w.xl2, NN, CD, HHD,
                w.rowptr[1], w.srcs[1], w.xl3, w.xr3, att0 + (size_t)1 * HHD,
                w.rowptr[2], w.srcs[2], w.xl4, w.xr4, att0 + (size_t)2 * HHD,
                w.acc, 1, b0 + (size_t)1 * HHD, b0 + (size_t)2 * HHD, w.z_j);
            // D) z_j-only L1 GEMM slices (z=4):
            //    zj@Wl1[3]->xl4 (rel3 src), zj@Wl1[1]->xl3 (rel1 src),
            //    zj@Wr1[1]->xr3 (rel1 dst), zj@Wr1[2]->xr4 (rel2 dst)
            gemm_mfma_t4<unsigned short, true><<<gg, 256, 0, stream>>>(
                w.z_j, w.z_j, w.z_j, w.z_j,
                w.wt1l_h + p3, w.wt1l_l + p3, w.wt1l_h + p1, w.wt1l_l + p1,
                w.wt1r_h + p1, w.wt1r_l + p1, w.wt1r_h + p2, w.wt1r_l + p2,
                w.xl4, w.xl3, w.xr3, w.xr4, NN, CD, HHD);
            // E) PAIRED aggr1_i (->acc) || aggr1_j (->acc2) in one dispatch
            fused_aggr4d_pair<<<2 * (NN / 4), 256, 0, stream>>>(
                w.rowptr[0], w.srcs[0], w.xl, w.xr, att1 + (size_t)0 * HHD,
                w.rowptr[3], w.srcs[3], w.xl4, w.xr2, att1 + (size_t)3 * HHD,
                w.acc, b1 + (size_t)0 * HHD, b1 + (size_t)3 * HHD,
                w.rowptr[1], w.srcs[1], w.xl3, w.xr3, att1 + (size_t)1 * HHD,
                w.rowptr[2], w.srcs[2], w.xl2, w.xr4, att1 + (size_t)2 * HHD,
                w.acc2, b1 + (size_t)1 * HHD, b1 + (size_t)2 * HHD);
            // F) both pool reductions in one launch
            pool_reduce2<<<2 * BG, 512, 0, stream>>>(
                w.acc, batch_i, w.pool_i, w.acc2, batch_j, w.pool_j);
        } else if (fat_f) {
            const size_t o0 = (size_t)0 * HHD * FD, o3 = (size_t)3 * HHD * FD;
            const size_t o1 = (size_t)1 * HHD * FD, o2 = (size_t)2 * HHD * FD;
            dim3 gg(HHD / 128, (NN + 127) / 128, 4);
            gemm_mfma_t4<float, false><<<gg, 256, 0, stream>>>(
                x_i, x_i, x_j, x_i,
                w.wt0l_h + o0, w.wt0l_l + o0, w.wt0r_h + o0, w.wt0r_l + o0,
                w.wt0l_h + o3, w.wt0l_l + o3, w.wt0r_h + o3, w.wt0r_l + o3,
                w.xl, w.xr, w.xl2, w.xr2, NN, FD, HHD);
            const int ngemm = (HHD / 128) * ((NN + 127) / 128) * 4;
            gemm_aggr_fused<float, false><<<ngemm + NN / 4, 256, 0, stream>>>(
                ngemm,
                x_j, x_j, x_i, x_j,
                w.wt0l_h + o1, w.wt0l_l + o1, w.wt0r_h + o1, w.wt0r_l + o1,
                w.wt0l_h + o2, w.wt0l_l + o2, w.wt0r_h + o2, w.wt0r_l + o2,
                w.xl3, w.xr3, w.xl4, w.xr4, NN, FD, HHD,
                w.rowptr[0], w.srcs[0], w.xl, w.xr, att0 + (size_t)0 * HHD,
                w.rowptr[3], w.srcs[3], w.xl2, w.xr2, att0 + (size_t)3 * HHD,
                w.acc, 1, b0 + (size_t)0 * HHD, b0 + (size_t)3 * HHD, w.z_i);
            fused_aggr4d<<<NN / 4, 256, 0, stream>>>(
                w.rowptr[1], w.srcs[1], w.xl3, w.xr3, att0 + (size_t)1 * HHD,
                w.rowptr[2], w.srcs[2], w.xl4, w.xr4, att0 + (size_t)2 * HHD,
                w.acc, 1, b0 + (size_t)1 * HHD, b0 + (size_t)2 * HHD,
                w.z_j, nullptr, nullptr);
            dim3 g8(HHD / 128, (NN + 127) / 128, 8);
            gemm_mfma_L1x8<<<g8, 256, 0, stream>>>(
                w.z_i, w.z_j, w.wt1l_h, w.wt1l_l, w.wt1r_h, w.wt1r_l,
                w.xl, w.xr, w.xl2, w.xr2, w.xl3, w.xr3, w.xl4, w.xr4,
                NN, CD, HHD);
            fused_aggr4d<<<NN / 4, 256, 0, stream>>>(
                w.rowptr[0], w.srcs[0], w.xl, w.xr, att1 + (size_t)0 * HHD,
                w.rowptr[3], w.srcs[3], w.xl2, w.xr2, att1 + (size_t)3 * HHD,
                w.acc, 2, b1 + (size_t)0 * HHD, b1 + (size_t)3 * HHD,
                nullptr, nullptr, nullptr);
            pool_reduce<<<BG, 512, 0, stream>>>(w.acc, batch_i, w.pool_i);
            fused_aggr4d<<<NN / 4, 256, 0, stream>>>(
                w.rowptr[1], w.srcs[1], w.xl3, w.xr3, att1 + (size_t)1 * HHD,
                w.rowptr[2], w.srcs[2], w.xl4, w.xr4, att1 + (size_t)2 * HHD,
                w.acc, 2, b1 + (size_t)1 * HHD, b1 + (size_t)2 * HHD,
                nullptr, nullptr, nullptr);
            pool_reduce<<<BG, 512, 0, stream>>>(w.acc, batch_j, w.pool_j);
        } else if (fat_m) {
            run_group_fat_m<float, false>(srcA0_i, dstA0_i, rp_i, sr_i, rids_i, FD,
                                          w.wt0l_h, w.wt0l_l, w.wt0r_h, w.wt0r_l,
                                          att0, b0, 1, w.z_i, nullptr, nullptr, w, stream);
            run_group_fat_m<float, false>(srcA0_j, dstA0_j, rp_j, sr_j, rids_j, FD,
                                          w.wt0l_h, w.wt0l_l, w.wt0r_h, w.wt0r_l,
                                          att0, b0, 1, w.z_j, nullptr, nullptr, w, stream);
            run_group_fat_m<unsigned short, true>(srcA1_i, dstA1_i, rp_i, sr_i, rids_i, CD,
                                                  w.wt1l_h, w.wt1l_l, w.wt1r_h, w.wt1r_l,
                                                  att1, b1, 2, nullptr, batch_i, w.pool_i, w, stream);
            pool_reduce<<<BG, 512, 0, stream>>>(w.acc, batch_i, w.pool_i);
            run_group_fat_m<unsigned short, true>(srcA1_j, dstA1_j, rp_j, sr_j, rids_j, CD,
                                                  w.wt1l_h, w.wt1l_l, w.wt1r_h, w.wt1r_l,
                                                  att1, b1, 2, nullptr, batch_j, w.pool_j, w, stream);
            pool_reduce<<<BG, 512, 0, stream>>>(w.acc, batch_j, w.pool_j);
        } else {
            run_group_fat_t<float, false>(srcA0_i, dstA0_i, rp_i, sr_i, rids_i, FD,
                                          w.wt0l_h, w.wt0l_l, w.wt0r_h, w.wt0r_l,
                                          att0, b0, 1, w.z_i, nullptr, nullptr, w, stream);
            run_group_fat_t<float, false>(srcA0_j, dstA0_j, rp_j, sr_j, rids_j, FD,
                                          w.wt0l_h, w.wt0l_l, w.wt0r_h, w.wt0r_l,
                                          att0, b0, 1, w.z_j, nullptr, nullptr, w, stream);
            run_group_fat_t<unsigned short, true>(srcA1_i, dstA1_i, rp_i, sr_i, rids_i, CD,
                                                  w.wt1l_h, w.wt1l_l, w.wt1r_h, w.wt1r_l,
                                                  att1, b1, 2, nullptr, batch_i, w.pool_i, w, stream);
            pool_reduce<<<BG, 512, 0, stream>>>(w.acc, batch_i, w.pool_i);
            run_group_fat_t<unsigned short, true>(srcA1_j, dstA1_j, rp_j, sr_j, rids_j, CD,
                                                  w.wt1l_h, w.wt1l_l, w.wt1r_h, w.wt1r_l,
                                                  att1, b1, 2, nullptr, batch_j, w.pool_j, w, stream);
            pool_reduce<<<BG, 512, 0, stream>>>(w.acc, batch_j, w.pool_j);
        }
    } else if (fat) {
        if (ncsr == 4) {
            for (int r = 0; r < 4; ++r)
                build_csr(eis_all[r], w.rowptr[r], w.srcs[r], w.cnt, w.cursor, stream);
            const int* rp_i[2] = { w.rowptr[0], w.rowptr[3] };
            const unsigned short* sr_i[2] = { w.srcs[0], w.srcs[3] };
            const int* rp_j[2] = { w.rowptr[1], w.rowptr[2] };
            const unsigned short* sr_j[2] = { w.srcs[1], w.srcs[2] };
            run_group_fat<float, false>(srcA0_i, dstA0_i, rp_i, sr_i, rids_i, FD,
                                        Wl0, Wr0, att0, b0, 1, w.z_i, nullptr, nullptr, w, stream);
            run_group_fat<float, false>(srcA0_j, dstA0_j, rp_j, sr_j, rids_j, FD,
                                        Wl0, Wr0, att0, b0, 1, w.z_j, nullptr, nullptr, w, stream);
            run_group_fat<unsigned short, true>(srcA1_i, dstA1_i, rp_i, sr_i, rids_i, CD,
                                                Wl1, Wr1, att1, b1, 2, nullptr, batch_i, w.pool_i, w, stream);
            pool_reduce<<<BG, 512, 0, stream>>>(w.acc, batch_i, w.pool_i);
            run_group_fat<unsigned short, true>(srcA1_j, dstA1_j, rp_j, sr_j, rids_j, CD,
                                                Wl1, Wr1, att1, b1, 2, nullptr, batch_j, w.pool_j, w, stream);
            pool_reduce<<<BG, 512, 0, stream>>>(w.acc, batch_j, w.pool_j);
        } else {
            for (int pass = 0; pass < 4; ++pass) {
                const int* rids = (pass & 1) ? rids_j : rids_i;
                for (int q = 0; q < 2; ++q) {
                    int r = rids[q];
                    build_csr(eis_all[r], w.rowptr[0], w.srcs[0], w.cnt, w.cursor, stream);
                    dim3 gg(HHD / 64, (NN + 63) / 64, 2);
                    if (pass < 2) {
                        const float* sa = (pass == 0) ? srcA0_i[q] : srcA0_j[q];
                        const float* da = (pass == 0) ? dstA0_i[q] : dstA0_j[q];
                        gemm_mfma<float, false><<<gg, 256, 0, stream>>>(
                            sa, da, Wl0 + (size_t)r * FD * HHD, Wr0 + (size_t)r * FD * HHD,
                            HHD, w.xl, w.xr, NN, FD, HHD);
                        fused_aggr4<<<NN / 4, 256, 0, stream>>>(
                            w.rowptr[0], w.srcs[0], w.xl, w.xr, att0 + (size_t)r * HHD,
                            w.acc, q, (q == 1) ? 1 : 0,
                            b0 + (size_t)rids[0] * HHD, b0 + (size_t)rids[1] * HHD,
                            (pass == 0) ? w.z_i : w.z_j, nullptr, nullptr);
                    } else {
                        const unsigned short* sa = (pass == 2) ? srcA1_i[q] : srcA1_j[q];
                        const unsigned short* da = (pass == 2) ? dstA1_i[q] : dstA1_j[q];
                        gemm_mfma<unsigned short, true><<<gg, 256, 0, stream>>>(
                            sa, da, Wl1 + (size_t)r * CD * HHD, Wr1 + (size_t)r * CD * HHD,
                            HHD, w.xl, w.xr, NN, CD, HHD);
                        fused_aggr4<<<NN / 4, 256, 0, stream>>>(
                            w.rowptr[0], w.srcs[0], w.xl, w.xr, att1 + (size_t)r * HHD,
                            w.acc, q, (q == 1) ? 2 : 0,
                            b1 + (size_t)rids[0] * HHD, b1 + (size_t)rids[1] * HHD,
                            nullptr, (pass == 2) ? batch_i : batch_j,
                            (pass == 2) ? w.pool_i : w.pool_j);
                    }
                }
                if (pass == 2)
                    pool_reduce<<<BG, 512, 0, stream>>>(w.acc, batch_i, w.pool_i);
                else if (pass == 3)
                    pool_reduce<<<BG, 512, 0, stream>>>(w.acc, batch_j, w.pool_j);
            }
        }
    } else {
        const int* eis_i[2] = { ei_ii, ei_ji };
        const int* eis_j[2] = { ei_jj, ei_ij };
        run_group_thin<float, false>(srcA0_i, dstA0_i, eis_i, rids_i, FD, Wl0, Wr0, att0, b0,
                                     1, w.z_i, nullptr, nullptr, w, stream);
        run_group_thin<float, false>(srcA0_j, dstA0_j, eis_j, rids_j, FD, Wl0, Wr0, att0, b0,
                                     1, w.z_j, nullptr, nullptr, w, stream);
        run_group_thin<unsigned short, true>(srcA1_i, dstA1_i, eis_i, rids_i, CD, Wl1, Wr1, att1, b1,
                                             2, nullptr, batch_i, w.pool_i, w, stream);
        run_group_thin<unsigned short, true>(srcA1_j, dstA1_j, eis_j, rids_j, CD, Wl1, Wr1, att1, b1,
                                             2, nullptr, batch_j, w.pool_j, w, stream);
    }

    head_kernel<<<BG, 128, 0, stream>>>(w.pool_i, w.pool_j, W_out, b_out,
                                        W_i, b_i, W_j, b_j, out);
}